// Round 12
// baseline (801.821 us; speedup 1.0000x reference)
//
#include <hip/hip_runtime.h>
#include <hip/hip_bf16.h>
#include <math.h>

#define H_ 1024
#define NH_ 16
#define HD_ 64
#define I_ 4096
#define E_ 8
#define B_ 2
#define S_ 2048
#define T_ 4096

#define MAXSLOTS 9216   // 2*T + 8*128 pad
#define MAXTILES 72     // MAXSLOTS/128

typedef __attribute__((ext_vector_type(8))) short short8v;
typedef __attribute__((ext_vector_type(4))) float f32x4;

#define GLOAD16(g, l) __builtin_amdgcn_global_load_lds((const __attribute__((address_space(1))) void*)(g), (__attribute__((address_space(3))) void*)(l), 16, 0, 0)

static __device__ inline unsigned short f2bf(float x) {
    __hip_bfloat16 h = __float2bfloat16(x);
    unsigned short u;
    __builtin_memcpy(&u, &h, 2);
    return u;
}
static __device__ inline float bf2f(unsigned short u) {
    __hip_bfloat16 h;
    __builtin_memcpy(&h, &u, 2);
    return __bfloat162float(h);
}

// exact-gelu via A&S 7.1.26 erf approximation (max abs err 1.5e-7 << bf16 rounding)
static __device__ inline float gelu_fast(float x) {
    float z  = x * 0.70710678118654752f;
    float az = fabsf(z);
    float t  = __builtin_amdgcn_rcpf(fmaf(0.3275911f, az, 1.f));
    float p  = fmaf(1.061405429f, t, -1.453152027f);
    p = fmaf(p, t, 1.421413741f);
    p = fmaf(p, t, -0.284496736f);
    p = fmaf(p, t, 0.254829592f);
    p = p * t;
    float e = __expf(-az*az);
    float er = 1.f - p*e;
    er = (z < 0.f) ? -er : er;
    return 0.5f * x * (1.f + er);
}

// ---------------- zero ----------------
__global__ void zero_kernel(float* __restrict__ p, int n) {
    int i = blockIdx.x * blockDim.x + threadIdx.x;
    if (i < n) p[i] = 0.f;
}

// ---------------- fp32 -> bf16 hi/lo split (elementwise) ----------------
__global__ __launch_bounds__(256) void split_bf16(
    const float* __restrict__ in, __hip_bfloat16* __restrict__ hi,
    __hip_bfloat16* __restrict__ lo, int n4)
{
    int i = blockIdx.x * blockDim.x + threadIdx.x;
    if (i >= n4) return;
    float4 v = ((const float4*)in)[i];
    unsigned short h0 = f2bf(v.x), h1 = f2bf(v.y), h2 = f2bf(v.z), h3 = f2bf(v.w);
    unsigned short l0 = f2bf(v.x - bf2f(h0)), l1 = f2bf(v.y - bf2f(h1));
    unsigned short l2 = f2bf(v.z - bf2f(h2)), l3 = f2bf(v.w - bf2f(h3));
    uint2 ph = make_uint2((unsigned)h0 | ((unsigned)h1 << 16), (unsigned)h2 | ((unsigned)h3 << 16));
    uint2 pl = make_uint2((unsigned)l0 | ((unsigned)l1 << 16), (unsigned)l2 | ((unsigned)l3 << 16));
    *(uint2*)((char*)hi + (size_t)i*8) = ph;
    *(uint2*)((char*)lo + (size_t)i*8) = pl;
}

// ---------------- merged transpose+split for the 4 projection weights ----------------
__global__ __launch_bounds__(256) void transpose_split_w4(
    const float* __restrict__ Wq, const float* __restrict__ Wk,
    const float* __restrict__ Wv, const float* __restrict__ Wd,
    __hip_bfloat16* __restrict__ wqkv_h, __hip_bfloat16* __restrict__ wqkv_l,
    __hip_bfloat16* __restrict__ wd_h, __hip_bfloat16* __restrict__ wd_l)
{
    __shared__ float t[64][65];
    const int z = blockIdx.z;
    const float* in = (z==0) ? Wq : (z==1) ? Wk : (z==2) ? Wv : Wd;
    __hip_bfloat16* oh = (z<3) ? (wqkv_h + (size_t)z*1024*1024) : wd_h;
    __hip_bfloat16* ol = (z<3) ? (wqkv_l + (size_t)z*1024*1024) : wd_l;
    int k0 = blockIdx.y*64, n0 = blockIdx.x*64;
    int tid = threadIdx.x;
    #pragma unroll
    for (int it=0; it<4; ++it) {
        int lin = it*256 + tid;
        int r = lin >> 4, c4 = (lin & 15) << 2;
        float4 v = *(const float4*)&in[(size_t)(k0+r)*1024 + n0 + c4];
        t[r][c4] = v.x; t[r][c4+1] = v.y; t[r][c4+2] = v.z; t[r][c4+3] = v.w;
    }
    __syncthreads();
    #pragma unroll
    for (int it=0; it<4; ++it) {
        int lin = it*256 + tid;
        int r = lin >> 4, c4 = (lin & 15) << 2;
        float v0 = t[c4][r], v1 = t[c4+1][r], v2 = t[c4+2][r], v3 = t[c4+3][r];
        ushort4 hh, ll;
        hh.x = f2bf(v0); hh.y = f2bf(v1); hh.z = f2bf(v2); hh.w = f2bf(v3);
        ll.x = f2bf(v0 - bf2f(hh.x)); ll.y = f2bf(v1 - bf2f(hh.y));
        ll.z = f2bf(v2 - bf2f(hh.z)); ll.w = f2bf(v3 - bf2f(hh.w));
        size_t o = (size_t)(n0+r)*1024 + k0 + c4;
        *(ushort4*)&oh[o] = hh;
        *(ushort4*)&ol[o] = ll;
    }
}

// ---------------- transpose + f32->bf16: in [K][N] -> out [N][K] (vectorized) ----------------
__global__ __launch_bounds__(256) void transpose_bf16(
    const float* __restrict__ in, __hip_bfloat16* __restrict__ outp, int K, int N)
{
    __shared__ float t[64][65];
    size_t eoff = (size_t)blockIdx.z * (size_t)K * (size_t)N;
    int k0 = blockIdx.y*64, n0 = blockIdx.x*64;
    int tid = threadIdx.x;
    #pragma unroll
    for (int it=0; it<4; ++it) {
        int lin = it*256 + tid;
        int r = lin >> 4, c4 = (lin & 15) << 2;
        float4 v = *(const float4*)&in[eoff + (size_t)(k0+r)*N + n0 + c4];
        t[r][c4] = v.x; t[r][c4+1] = v.y; t[r][c4+2] = v.z; t[r][c4+3] = v.w;
    }
    __syncthreads();
    #pragma unroll
    for (int it=0; it<4; ++it) {
        int lin = it*256 + tid;
        int r = lin >> 4, c4 = (lin & 15) << 2;
        ushort4 o;
        o.x = f2bf(t[c4][r]);   o.y = f2bf(t[c4+1][r]);
        o.z = f2bf(t[c4+2][r]); o.w = f2bf(t[c4+3][r]);
        *(ushort4*)&outp[eoff + (size_t)(n0+r)*K + k0 + c4] = o;
    }
}

// ---------------- bf16x3 GEMM: C = A@B (+bias), fp32-accurate, XCD-swizzled 1D grid ----------------
template<bool BIAS>
__global__ __launch_bounds__(256, 2) void gemm_bf16x3(
    const __hip_bfloat16* __restrict__ Ah, const __hip_bfloat16* __restrict__ Al,
    const __hip_bfloat16* __restrict__ Bh, const __hip_bfloat16* __restrict__ Bl,
    float* __restrict__ C, const float* __restrict__ bias, int N, int K, int nbx)
{
    const int tid = threadIdx.x;
    const int w = tid >> 6, lane = tid & 63;
    const int wg = blockIdx.x;
    const int xcd = wg & 7, ix = wg >> 3;
    const int byc = (int)(gridDim.x >> 3) / nbx;
    const int by = xcd*byc + ix / nbx;
    const int bx = ix % nbx;

    __shared__ __align__(16) char smem[65536];
    const int AH = 0, AL = 16384, BH = 32768, BL = 49152;

    const int laneg = lane >> 3;
    const int k2sw = ((lane & 7) ^ laneg) << 4;
    const int l15 = lane & 15, l4 = lane >> 4;
    const int wr = w >> 1, wc = w & 1;

    f32x4 acc[4][4];
    #pragma unroll
    for (int m=0;m<4;m++)
        #pragma unroll
        for (int n=0;n<4;n++) acc[m][n] = (f32x4){0.f,0.f,0.f,0.f};

    for (int k0 = 0; k0 < K; k0 += 64) {
        __syncthreads();
        #pragma unroll
        for (int qq=0;qq<4;qq++) {
            int arow = by*128 + (w*4+qq)*8 + laneg;
            int brow = bx*128 + (w*4+qq)*8 + laneg;
            size_t aoff = ((size_t)arow*K + k0)*2 + k2sw;
            size_t boff = ((size_t)brow*K + k0)*2 + k2sw;
            GLOAD16((const char*)Ah + aoff, smem + AH + (w*4+qq)*1024);
            GLOAD16((const char*)Al + aoff, smem + AL + (w*4+qq)*1024);
            GLOAD16((const char*)Bh + boff, smem + BH + (w*4+qq)*1024);
            GLOAD16((const char*)Bl + boff, smem + BL + (w*4+qq)*1024);
        }
        __syncthreads();

        short8v ahf[4][2], alf[4][2], bhf[4][2], blf[4][2];
        #pragma unroll
        for (int m=0;m<4;m++) {
            int row = wr*64 + m*16 + l15;
            int rb = row << 7, rsw = (row & 7) << 4;
            #pragma unroll
            for (int s=0;s<2;s++) {
                int off = rb + ((s*64 + (l4<<4)) ^ rsw);
                ahf[m][s] = *(const short8v*)(smem + AH + off);
                alf[m][s] = *(const short8v*)(smem + AL + off);
            }
        }
        #pragma unroll
        for (int n=0;n<4;n++) {
            int row = wc*64 + n*16 + l15;
            int rb = row << 7, rsw = (row & 7) << 4;
            #pragma unroll
            for (int s=0;s<2;s++) {
                int off = rb + ((s*64 + (l4<<4)) ^ rsw);
                bhf[n][s] = *(const short8v*)(smem + BH + off);
                blf[n][s] = *(const short8v*)(smem + BL + off);
            }
        }
        #pragma unroll
        for (int m=0;m<4;m++)
            #pragma unroll
            for (int n=0;n<4;n++)
                #pragma unroll
                for (int s=0;s<2;s++) {
                    acc[m][n] = __builtin_amdgcn_mfma_f32_16x16x32_bf16(ahf[m][s], bhf[n][s], acc[m][n], 0, 0, 0);
                    acc[m][n] = __builtin_amdgcn_mfma_f32_16x16x32_bf16(ahf[m][s], blf[n][s], acc[m][n], 0, 0, 0);
                    acc[m][n] = __builtin_amdgcn_mfma_f32_16x16x32_bf16(alf[m][s], bhf[n][s], acc[m][n], 0, 0, 0);
                }
    }

    #pragma unroll
    for (int m=0;m<4;m++)
        #pragma unroll
        for (int j=0;j<4;j++) {
            int orow = by*128 + wr*64 + m*16 + l4*4 + j;
            #pragma unroll
            for (int n=0;n<4;n++) {
                int ocol = bx*128 + wc*64 + n*16 + l15;
                float v = acc[m][n][j];
                if (BIAS) v += bias[ocol];
                C[(size_t)orow*N + ocol] = v;
            }
        }
}

// ---------------- MFMA MoE GEMM ----------------
// MODE 2: y1 = gelu(gather(hs_b) @ W1t^T) -> bf16
// MODE 3: moe_out[tok] += w * (y1 @ W2t^T) -> f32 atomic
// FULL (!PE): 1D grid, XCD-swizzled, bx-MAJOR within XCD: concurrent blocks share
// one W-slice (1MB) and cycle the XCD's A-tiles (~1.3MB) -> both stay L2-resident.
template<int MODE, bool PE>
__global__ __launch_bounds__(256) void moe_mfma(
    const __hip_bfloat16* __restrict__ A,
    const __hip_bfloat16* __restrict__ Bt,
    __hip_bfloat16* __restrict__ y1,
    float* __restrict__ moe_out,
    const int* __restrict__ slot_token,
    const float* __restrict__ slot_w,
    const int* __restrict__ tile_expert,
    const int* __restrict__ cnt_ptr,
    const int* __restrict__ base_ptr,
    int N, int K, int nbx)
{
    const int tid = threadIdx.x;
    const int w = tid >> 6, lane = tid & 63;

    int bx, slot0, y1row0;
    const __hip_bfloat16* Bp;
    if (PE) {
        bx = blockIdx.x;
        int tloc = blockIdx.y;
        if ((tloc << 7) >= *cnt_ptr) return;
        slot0 = *base_ptr + (tloc << 7);
        y1row0 = tloc << 7;
        Bp = Bt;
    } else {
        const int wg = blockIdx.x;
        const int xcd = wg & 7, ix = wg >> 3;
        const int byc = (int)(gridDim.x >> 3) / nbx;   // tiles per XCD
        int gt = xcd*byc + ix % byc;                   // bx-major: tile varies fastest
        bx = ix / byc;
        if (gt >= *cnt_ptr) return;
        int e = tile_expert[gt];
        Bp = Bt + (size_t)e * (size_t)K * (size_t)N;
        slot0 = gt << 7;
        y1row0 = gt << 7;
    }

    __shared__ __align__(16) char smem[32768];

    const int laneg = lane >> 3;
    const int k2sw = ((lane & 7) ^ laneg) << 4;

    int tokq[4];
    if (MODE == 2) {
        #pragma unroll
        for (int qq=0;qq<4;qq++) {
            int t0 = slot_token[slot0 + (w*4+qq)*8 + laneg];
            tokq[qq] = t0 < 0 ? 0 : t0;
        }
    }

    f32x4 acc[4][4];
    #pragma unroll
    for (int m=0;m<4;m++)
        #pragma unroll
        for (int n=0;n<4;n++) acc[m][n] = (f32x4){0.f,0.f,0.f,0.f};

    const int l15 = lane & 15;
    const int l4  = lane >> 4;
    const int wr = w >> 1, wc = w & 1;

    for (int k0 = 0; k0 < K; k0 += 64) {
        __syncthreads();
        #pragma unroll
        for (int qq=0;qq<4;qq++) {
            const char* ga;
            if (MODE == 2) {
                ga = (const char*)A + (((size_t)tokq[qq])*K + k0)*2 + k2sw;
            } else {
                int row = y1row0 + (w*4+qq)*8 + laneg;
                ga = (const char*)A + ((size_t)row*K + k0)*2 + k2sw;
            }
            GLOAD16(ga, smem + (w*4+qq)*1024);
        }
        #pragma unroll
        for (int qq=0;qq<4;qq++) {
            int row = bx*128 + (w*4+qq)*8 + laneg;
            const char* gb = (const char*)Bp + ((size_t)row*K + k0)*2 + k2sw;
            GLOAD16(gb, smem + 16384 + (w*4+qq)*1024);
        }
        __syncthreads();

        short8v a_frag[4][2], b_frag[4][2];
        #pragma unroll
        for (int m=0;m<4;m++) {
            int row = wr*64 + m*16 + l15;
            int rb = row << 7;
            #pragma unroll
            for (int s=0;s<2;s++) {
                int off = rb + ((s*64 + (l4<<4)) ^ ((row&7)<<4));
                a_frag[m][s] = *(const short8v*)(smem + off);
            }
        }
        #pragma unroll
        for (int n=0;n<4;n++) {
            int row = wc*64 + n*16 + l15;
            int rb = row << 7;
            #pragma unroll
            for (int s=0;s<2;s++) {
                int off = rb + ((s*64 + (l4<<4)) ^ ((row&7)<<4));
                b_frag[n][s] = *(const short8v*)(smem + 16384 + off);
            }
        }
        #pragma unroll
        for (int m=0;m<4;m++)
            #pragma unroll
            for (int n=0;n<4;n++) {
                acc[m][n] = __builtin_amdgcn_mfma_f32_16x16x32_bf16(a_frag[m][0], b_frag[n][0], acc[m][n], 0, 0, 0);
                acc[m][n] = __builtin_amdgcn_mfma_f32_16x16x32_bf16(a_frag[m][1], b_frag[n][1], acc[m][n], 0, 0, 0);
            }
    }

    #pragma unroll
    for (int m=0;m<4;m++) {
        #pragma unroll
        for (int j=0;j<4;j++) {
            int orow = wr*64 + m*16 + l4*4 + j;
            if (MODE == 3) {
                int slot = slot0 + orow;
                int tok = slot_token[slot];
                if (tok < 0) continue;
                float sw = slot_w[slot];
                #pragma unroll
                for (int n=0;n<4;n++) {
                    int ocol = bx*128 + wc*64 + n*16 + l15;
                    atomicAdd(&moe_out[(size_t)tok*H_ + ocol], sw * acc[m][n][j]);
                }
            } else {
                #pragma unroll
                for (int n=0;n<4;n++) {
                    int ocol = bx*128 + wc*64 + n*16 + l15;
                    float g = gelu_fast(acc[m][n][j]);
                    y1[(size_t)(y1row0 + orow)*N + ocol] = __float2bfloat16(g);
                }
            }
        }
    }
}

// ---------------- RoPE + split: fp32 qkv[t][3072] -> rotated bf16 hi/lo, head-major ----------------
__global__ void rope_split_kernel(
    const float* __restrict__ qkv,
    __hip_bfloat16* __restrict__ qh, __hip_bfloat16* __restrict__ ql,
    __hip_bfloat16* __restrict__ kh, __hip_bfloat16* __restrict__ kl)
{
    int idx = blockIdx.x * blockDim.x + threadIdx.x;  // T*NH*32
    int i = idx & 31;
    int n = (idx >> 5) & (NH_-1);
    int t = idx >> 9;
    int b = t >> 11;
    int pos = t & (S_ - 1);
    float inv = exp2f((float)i * (-13.287712379549449f / 32.f));
    float ang = (float)pos * inv;
    float c = cosf(ang), s = sinf(ang);
    size_t base = (size_t)t*3072 + (size_t)n*64;
    size_t obase = ((size_t)(b*NH_ + n)*S_ + pos)*64;

    float q1 = qkv[base+i], q2 = qkv[base+i+32];
    float qo1 = (q1*c - q2*s)*0.125f;
    float qo2 = (q2*c + q1*s)*0.125f;
    unsigned short h1 = f2bf(qo1), h2 = f2bf(qo2);
    qh[obase+i]    = *(__hip_bfloat16*)&h1;
    qh[obase+i+32] = *(__hip_bfloat16*)&h2;
    unsigned short lo1 = f2bf(qo1 - bf2f(h1)), lo2 = f2bf(qo2 - bf2f(h2));
    ql[obase+i]    = *(__hip_bfloat16*)&lo1;
    ql[obase+i+32] = *(__hip_bfloat16*)&lo2;

    float k1 = qkv[base+1024+i], k2 = qkv[base+1024+i+32];
    float ko1 = k1*c - k2*s;
    float ko2 = k2*c + k1*s;
    unsigned short kh1 = f2bf(ko1), kh2 = f2bf(ko2);
    kh[obase+i]    = *(__hip_bfloat16*)&kh1;
    kh[obase+i+32] = *(__hip_bfloat16*)&kh2;
    unsigned short kl1 = f2bf(ko1 - bf2f(kh1)), kl2 = f2bf(ko2 - bf2f(kh2));
    kl[obase+i]    = *(__hip_bfloat16*)&kl1;
    kl[obase+i+32] = *(__hip_bfloat16*)&kl2;
}

// ---------------- V transpose + split ----------------
__global__ __launch_bounds__(256) void vsplit_t_kernel(
    const float* __restrict__ qkv,
    __hip_bfloat16* __restrict__ vth, __hip_bfloat16* __restrict__ vtl)
{
    __shared__ float t[64][65];
    const int s0 = blockIdx.x*64;
    const int hn = blockIdx.y;
    const int b  = blockIdx.z;
    const int tid = threadIdx.x;
    #pragma unroll
    for (int it=0; it<4; ++it) {
        int lin = it*256 + tid;
        int r = lin >> 4, c4 = (lin & 15) << 2;
        float4 vv = *(const float4*)&qkv[(size_t)(b*S_ + s0 + r)*3072 + 2048 + hn*64 + c4];
        t[r][c4] = vv.x; t[r][c4+1] = vv.y; t[r][c4+2] = vv.z; t[r][c4+3] = vv.w;
    }
    __syncthreads();
    size_t obase = (size_t)(b*NH_ + hn)*64*S_;
    #pragma unroll
    for (int it=0; it<4; ++it) {
        int lin = it*256 + tid;
        int d = lin >> 4, c4 = (lin & 15) << 2;
        float v0 = t[c4][d], v1 = t[c4+1][d], v2 = t[c4+2][d], v3 = t[c4+3][d];
        ushort4 hh, ll;
        hh.x = f2bf(v0); hh.y = f2bf(v1); hh.z = f2bf(v2); hh.w = f2bf(v3);
        ll.x = f2bf(v0 - bf2f(hh.x)); ll.y = f2bf(v1 - bf2f(hh.y));
        ll.z = f2bf(v2 - bf2f(hh.z)); ll.w = f2bf(v3 - bf2f(hh.w));
        size_t o = obase + (size_t)d*S_ + s0 + c4;
        *(ushort4*)&vth[o] = hh;
        *(ushort4*)&vtl[o] = ll;
    }
}

// ---------------- MFMA attention: bf16x3, XCD-swizzled, NO max-tracking softmax ----------------
__global__ __launch_bounds__(256, 3) void attn_mfma(
    const __hip_bfloat16* __restrict__ qh, const __hip_bfloat16* __restrict__ ql,
    const __hip_bfloat16* __restrict__ kh, const __hip_bfloat16* __restrict__ kl,
    const __hip_bfloat16* __restrict__ vth, const __hip_bfloat16* __restrict__ vtl,
    __hip_bfloat16* __restrict__ ctx_hi, __hip_bfloat16* __restrict__ ctx_lo)
{
    const int wg = blockIdx.x;
    const int xcd = wg & 7;
    const int ix = wg >> 3;
    const int head = xcd*4 + (ix >> 5);
    const int qt = ix & 31;
    const int b = head >> 4, hn = head & 15;

    const int tid = threadIdx.x;
    const int w = tid >> 6, lane = tid & 63;
    const int l15 = lane & 15, l4 = lane >> 4;
    const int laneg = lane >> 3;
    const int k2sw = ((lane & 7) ^ laneg) << 4;

    __shared__ __align__(16) char smem[49152];
    const int KHo = 0, KLo = 8192, VHo = 16384, VLo = 24576, PHo = 32768, PLo = 40960;

    const size_t kbase = (size_t)head*S_*64;
    const size_t vbase = (size_t)head*64*S_;

    #pragma unroll
    for (int qq=0;qq<2;qq++) {
        int c = w*2 + qq;
        int row = qt*64 + c*8 + laneg;
        size_t off = (kbase + (size_t)row*64)*2 + k2sw;
        GLOAD16((const char*)qh + off, smem + PHo + c*1024);
        GLOAD16((const char*)ql + off, smem + PLo + c*1024);
    }
    __syncthreads();
    short8v qhf[2], qlf[2];
    {
        int row = w*16 + l15;
        int rsw = (row & 7) << 4;
        #pragma unroll
        for (int s=0;s<2;s++) {
            int off = row*128 + ((s*64 + l4*16) ^ rsw);
            qhf[s] = *(const short8v*)(smem + PHo + off);
            qlf[s] = *(const short8v*)(smem + PLo + off);
        }
    }

    f32x4 acc[4];
    #pragma unroll
    for (int db=0;db<4;db++) acc[db] = (f32x4){0.f,0.f,0.f,0.f};
    float lrun[4] = {0.f, 0.f, 0.f, 0.f};

    for (int kt=0; kt<S_/64; ++kt) {
        __syncthreads();
        #pragma unroll
        for (int qq=0;qq<2;qq++) {
            int c = w*2 + qq;
            int r8 = c*8 + laneg;
            size_t koff = (kbase + (size_t)(kt*64 + r8)*64)*2 + k2sw;
            GLOAD16((const char*)kh + koff, smem + KHo + c*1024);
            GLOAD16((const char*)kl + koff, smem + KLo + c*1024);
            size_t voff = (vbase + (size_t)r8*S_ + kt*64)*2 + k2sw;
            GLOAD16((const char*)vth + voff, smem + VHo + c*1024);
            GLOAD16((const char*)vtl + voff, smem + VLo + c*1024);
        }
        __syncthreads();

        f32x4 s_acc[4];
        #pragma unroll
        for (int cb=0;cb<4;cb++) {
            s_acc[cb] = (f32x4){0.f,0.f,0.f,0.f};
            int row = cb*16 + l15;
            int rsw = (row & 7) << 4;
            #pragma unroll
            for (int s=0;s<2;s++) {
                int off = row*128 + ((s*64 + l4*16) ^ rsw);
                short8v khf = *(const short8v*)(smem + KHo + off);
                short8v klf = *(const short8v*)(smem + KLo + off);
                s_acc[cb] = __builtin_amdgcn_mfma_f32_16x16x32_bf16(qhf[s], khf, s_acc[cb], 0, 0, 0);
                s_acc[cb] = __builtin_amdgcn_mfma_f32_16x16x32_bf16(qhf[s], klf, s_acc[cb], 0, 0, 0);
                s_acc[cb] = __builtin_amdgcn_mfma_f32_16x16x32_bf16(qlf[s], khf, s_acc[cb], 0, 0, 0);
            }
        }

        #pragma unroll
        for (int cb=0;cb<4;cb++)
            #pragma unroll
            for (int j=0;j<4;j++) {
                float p = __expf(s_acc[cb][j]);
                lrun[j] += p;
                int prow = w*16 + l4*4 + j;
                unsigned short hh = f2bf(p);
                unsigned short ll = f2bf(p - bf2f(hh));
                int off = prow*128 + (((cb*16 + l15)*2) ^ ((prow&7)<<4));
                *(unsigned short*)(smem + PHo + off) = hh;
                *(unsigned short*)(smem + PLo + off) = ll;
            }
        asm volatile("s_waitcnt lgkmcnt(0)" ::: "memory");
        __builtin_amdgcn_sched_barrier(0);

        short8v pah[2], pal[2];
        {
            int row = w*16 + l15;
            int rsw = (row & 7) << 4;
            #pragma unroll
            for (int s=0;s<2;s++) {
                int off = row*128 + ((s*64 + l4*16) ^ rsw);
                pah[s] = *(const short8v*)(smem + PHo + off);
                pal[s] = *(const short8v*)(smem + PLo + off);
            }
        }
        #pragma unroll
        for (int db=0;db<4;db++) {
            int row = db*16 + l15;
            int rsw = (row & 7) << 4;
            #pragma unroll
            for (int s=0;s<2;s++) {
                int off = row*128 + ((s*64 + l4*16) ^ rsw);
                short8v vhf = *(const short8v*)(smem + VHo + off);
                short8v vlf = *(const short8v*)(smem + VLo + off);
                acc[db] = __builtin_amdgcn_mfma_f32_16x16x32_bf16(pah[s], vhf, acc[db], 0, 0, 0);
                acc[db] = __builtin_amdgcn_mfma_f32_16x16x32_bf16(pah[s], vlf, acc[db], 0, 0, 0);
                acc[db] = __builtin_amdgcn_mfma_f32_16x16x32_bf16(pal[s], vhf, acc[db], 0, 0, 0);
            }
        }
    }

    #pragma unroll
    for (int j=0;j<4;j++) {
        float s = lrun[j];
        #pragma unroll
        for (int m=8;m;m>>=1) s += __shfl_xor(s, m);
        lrun[j] = s;
    }

    #pragma unroll
    for (int db=0;db<4;db++)
        #pragma unroll
        for (int j=0;j<4;j++) {
            int qrow = qt*64 + w*16 + l4*4 + j;
            float o = acc[db][j] / lrun[j];
            unsigned short hh = f2bf(o);
            unsigned short ll = f2bf(o - bf2f(hh));
            size_t oidx = (size_t)(b*S_ + qrow)*H_ + hn*64 + db*16 + l15;
            ctx_hi[oidx] = *(__hip_bfloat16*)&hh;
            ctx_lo[oidx] = *(__hip_bfloat16*)&ll;
        }
}

// ---------------- layernorm (residual fused, optional bf16 out) ----------------
__global__ __launch_bounds__(256) void ln_kernel(
    const float* __restrict__ a, const float* __restrict__ res,
    const float* __restrict__ g, const float* __restrict__ beta,
    float* __restrict__ out, __hip_bfloat16* __restrict__ outb)
{
    int row = blockIdx.x, tid = threadIdx.x;
    const float4 va = ((const float4*)(a + (size_t)row*H_))[tid];
    const float4 vr = ((const float4*)(res + (size_t)row*H_))[tid];
    float x0=va.x+vr.x, x1=va.y+vr.y, x2=va.z+vr.z, x3=va.w+vr.w;
    float s  = x0+x1+x2+x3;
    float ss = x0*x0 + x1*x1 + x2*x2 + x3*x3;
    #pragma unroll
    for (int off=32; off; off>>=1) { s += __shfl_xor(s, off); ss += __shfl_xor(ss, off); }
    __shared__ float red[8];
    if ((tid&63)==0) { red[tid>>6]=s; red[4+(tid>>6)]=ss; }
    __syncthreads();
    if (tid==0) { red[0]=red[0]+red[1]+red[2]+red[3]; red[4]=red[4]+red[5]+red[6]+red[7]; }
    __syncthreads();
    float mu  = red[0] * (1.f/H_);
    float var = red[4] * (1.f/H_) - mu*mu;
    float rs = rsqrtf(fmaxf(var, 0.f) + 1e-12f);
    const float4 vg = ((const float4*)g)[tid];
    const float4 vb = ((const float4*)beta)[tid];
    float4 vo;
    vo.x = (x0-mu)*rs*vg.x + vb.x;
    vo.y = (x1-mu)*rs*vg.y + vb.y;
    vo.z = (x2-mu)*rs*vg.z + vb.z;
    vo.w = (x3-mu)*rs*vg.w + vb.w;
    ((float4*)(out + (size_t)row*H_))[tid] = vo;
    if (outb) {
        unsigned int p0 = (unsigned)f2bf(vo.x) | ((unsigned)f2bf(vo.y) << 16);
        unsigned int p1 = (unsigned)f2bf(vo.z) | ((unsigned)f2bf(vo.w) << 16);
        ((uint2*)(outb + (size_t)row*H_))[tid] = make_uint2(p0, p1);
    }
}

// ---------------- router: 64 blocks x 64 tokens, register-accumulated stats ----------------
__global__ __launch_bounds__(256) void router_kernel(
    const float* __restrict__ hs, const float* __restrict__ Wg,
    int* __restrict__ tok_e, float* __restrict__ tok_w,
    int* __restrict__ counts, float* __restrict__ P_sum)
{
    const int w = threadIdx.x >> 6, lane = threadIdx.x & 63;
    float psum[E_];
    int cnt[E_];
    #pragma unroll
    for (int e=0;e<E_;e++){ psum[e]=0.f; cnt[e]=0; }

    for (int it=0; it<16; ++it) {
        int t = blockIdx.x*64 + it*4 + w;
        const float* row = hs + (size_t)t * H_;
        float acc[E_];
        #pragma unroll
        for (int e=0;e<E_;e++) acc[e]=0.f;
        for (int i16=0; i16<16; ++i16) {
            int i = i16*64 + lane;
            float xv = row[i];
            const float* wg = Wg + (size_t)i*E_;
            #pragma unroll
            for (int e=0;e<E_;e++) acc[e] = fmaf(xv, wg[e], acc[e]);
        }
        #pragma unroll
        for (int e=0;e<E_;e++) {
            float vv = acc[e];
            #pragma unroll
            for (int off=32; off; off>>=1) vv += __shfl_xor(vv, off);
            acc[e] = vv;
        }
        float mx = acc[0];
        #pragma unroll
        for (int e=1;e<E_;e++) mx = fmaxf(mx, acc[e]);
        float p[E_], se=0.f;
        #pragma unroll
        for (int e=0;e<E_;e++){ p[e] = __expf(acc[e]-mx); se += p[e]; }
        float isv = 1.f/se;
        #pragma unroll
        for (int e=0;e<E_;e++){ p[e]*=isv; psum[e] += p[e]; }
        int e1=0;
        #pragma unroll
        for (int e=1;e<E_;e++) if (p[e] > p[e1]) e1=e;
        int e2 = (e1==0)?1:0;
        #pragma unroll
        for (int e=0;e<E_;e++) if (e!=e1 && p[e] > p[e2]) e2=e;
        #pragma unroll
        for (int e=0;e<E_;e++) cnt[e] += (e==e1?1:0) + (e==e2?1:0);
        if (lane==0) {
            float w1=p[e1], w2=p[e2], si=1.f/(w1+w2);
            tok_e[t*2]=e1; tok_e[t*2+1]=e2;
            tok_w[t*2]=w1*si; tok_w[t*2+1]=w2*si;
        }
    }
    if (lane==0) {
        #pragma unroll
        for (int e=0;e<E_;e++) {
            atomicAdd(&P_sum[e], psum[e]);
            atomicAdd(&counts[e], cnt[e]);
        }
    }
}

__global__ void router_finalize(
    const int* __restrict__ counts, const float* __restrict__ P_sum,
    int* __restrict__ base, int* __restrict__ cursor,
    int* __restrict__ cnt_pad, int* __restrict__ ntiles,
    int* __restrict__ slot_token, int* __restrict__ tile_expert,
    float* __restrict__ aux_out)
{
    __shared__ int sbase[E_+1];
    if (threadIdx.x == 0) {
        int bacc = 0;
        float aux = 0.f;
        for (int e=0;e<E_;e++) {
            sbase[e] = bacc; base[e] = bacc;
            int cp = (counts[e] + 127) & ~127;
            cnt_pad[e] = cp;
            bacc += cp;
            cursor[e] = 0;
            aux += ((float)counts[e]/(float)T_) * (P_sum[e]/(float)T_);
        }
        sbase[E_] = bacc;
        *ntiles = bacc >> 7;
        *aux_out = (float)E_ * aux;
    }
    __syncthreads();
    for (int sIdx = (int)threadIdx.x; sIdx < MAXSLOTS; sIdx += (int)blockDim.x)
        slot_token[sIdx] = -1;
    for (int tt = (int)threadIdx.x; tt < MAXTILES; tt += (int)blockDim.x) {
        int s = tt*128;
        int e = E_-1;
        for (int qe=0; qe<E_; ++qe) if (s < sbase[qe+1]) { e = qe; break; }
        tile_expert[tt] = e;
    }
}

__global__ void scatter_slots(
    const int* __restrict__ tok_e, const float* __restrict__ tok_w,
    const int* __restrict__ base, int* __restrict__ cursor,
    int* __restrict__ slot_token, float* __restrict__ slot_w)
{
    int t = blockIdx.x*blockDim.x + threadIdx.x;
    if (t >= T_) return;
    #pragma unroll
    for (int j=0;j<2;j++) {
        int e = tok_e[t*2+j];
        int pos = atomicAdd(&cursor[e], 1);
        int s = base[e] + pos;
        slot_token[s] = t;
        slot_w[s] = tok_w[t*2+j];
    }
}

extern "C" void kernel_launch(void* const* d_in, const int* in_sizes, int n_in,
                              void* d_out, int out_size, void* d_ws, size_t ws_size,
                              hipStream_t stream)
{
    const float* x    = (const float*)d_in[0];
    const float* Wq   = (const float*)d_in[1];
    const float* Wk   = (const float*)d_in[2];
    const float* Wv   = (const float*)d_in[3];
    const float* Wd   = (const float*)d_in[4];
    const float* bd   = (const float*)d_in[5];
    const float* ln1g = (const float*)d_in[6];
    const float* ln1b = (const float*)d_in[7];
    const float* Wg   = (const float*)d_in[8];
    const float* W1   = (const float*)d_in[9];
    const float* W2   = (const float*)d_in[10];
    const float* ln2g = (const float*)d_in[11];
    const float* ln2b = (const float*)d_in[12];
    float* out = (float*)d_out;

    float* f0 = (float*)d_ws;
    const size_t M1 = 1u << 20;
    float* qkv      = f0;
    float* attn_out = f0 + 12*M1;
    float* hs       = f0;
    float* moe_out  = f0 + 4*M1;
    __hip_bfloat16* hs_b = (__hip_bfloat16*)(f0 + 16*M1);

    float* misc = f0 + 18*M1;
    int*   misc_i = (int*)misc;
    int*   tok_e   = misc_i;
    float* tok_w   = misc + 8192;
    int*   slot_tok= misc_i + 16384;
    float* slot_w  = misc + 25600;
    int*   counts  = misc_i + 34816;
    float* P_sum   = misc + 34824;
    int*   cursor  = misc_i + 34832;
    int*   basep   = misc_i + 34840;
    int*   cnt_pad = misc_i + 34848;
    int*   ntiles  = misc_i + 34856;
    int*   tile_ex = misc_i + 34857;

    float* off_p = f0 + 18*M1 + 65536;
    __hip_bfloat16* xa_hi = (__hip_bfloat16*)(off_p);
    __hip_bfloat16* xa_lo = (__hip_bfloat16*)(off_p + 2*M1);
    __hip_bfloat16* at_qh = (__hip_bfloat16*)(off_p + 4*M1);
    __hip_bfloat16* at_ql = (__hip_bfloat16*)(off_p + 6*M1);
    __hip_bfloat16* at_kh = (__hip_bfloat16*)(off_p + 8*M1);
    __hip_bfloat16* at_kl = (__hip_bfloat16*)(off_p + 10*M1);
    __hip_bfloat16* at_vh = (__hip_bfloat16*)(off_p + 12*M1);
    __hip_bfloat16* at_vl = (__hip_bfloat16*)(off_p + 14*M1);
    __hip_bfloat16* wqkv_h = (__hip_bfloat16*)(off_p + 16*M1);
    __hip_bfloat16* wqkv_l = (__hip_bfloat16*)(off_p + 16*M1 + 3*(M1/2));
    __hip_bfloat16* wd_h = (__hip_bfloat16*)(off_p + 19*M1);
    __hip_bfloat16* wd_l = (__hip_bfloat16*)(off_p + 19*M1 + M1/2);

    float* wreg = off_p + 4*M1;
    const bool FULL = ws_size >= (size_t)300*1024*1024;

    dim3 blk(256);

    split_bf16<<<(T_*H_/4)/256, blk, 0, stream>>>(x, xa_hi, xa_lo, T_*H_/4);
    transpose_split_w4<<<dim3(16,16,4), blk, 0, stream>>>(Wq, Wk, Wv, Wd, wqkv_h, wqkv_l, wd_h, wd_l);

    gemm_bf16x3<false><<<dim3(768), blk, 0, stream>>>(xa_hi, xa_lo, wqkv_h, wqkv_l, qkv, nullptr, 3072, H_, 24);

    rope_split_kernel<<<(T_*NH_*32)/256, blk, 0, stream>>>(qkv, at_qh, at_ql, at_kh, at_kl);
    vsplit_t_kernel<<<dim3(S_/64, NH_, B_), blk, 0, stream>>>(qkv, at_vh, at_vl);

    attn_mfma<<<dim3(B_*NH_*(S_/64)), blk, 0, stream>>>(at_qh, at_ql, at_kh, at_kl, at_vh, at_vl, xa_hi, xa_lo);

    gemm_bf16x3<true><<<dim3(256), blk, 0, stream>>>(xa_hi, xa_lo, wd_h, wd_l, attn_out, bd, H_, H_, 8);

    zero_kernel<<<(T_*H_)/256, blk, 0, stream>>>(moe_out, T_*H_);
    zero_kernel<<<1, blk, 0, stream>>>(misc + 34816, 16);

    ln_kernel<<<T_, blk, 0, stream>>>(attn_out, x, ln1g, ln1b, hs, hs_b);

    router_kernel<<<T_/64, blk, 0, stream>>>(hs, Wg, tok_e, tok_w, counts, P_sum);
    router_finalize<<<1, blk, 0, stream>>>(counts, P_sum, basep, cursor, cnt_pad, ntiles,
                                           slot_tok, tile_ex, out + (size_t)T_*H_);
    scatter_slots<<<T_/256, blk, 0, stream>>>(tok_e, tok_w, basep, cursor, slot_tok, slot_w);

    if (FULL) {
        __hip_bfloat16* W1t = (__hip_bfloat16*)wreg;
        __hip_bfloat16* W2t = (__hip_bfloat16*)(wreg + 16*M1);
        __hip_bfloat16* y1  = (__hip_bfloat16*)(wreg + 32*M1);
        transpose_bf16<<<dim3(I_/64, H_/64, E_), blk, 0, stream>>>(W1, W1t, H_, I_);
        transpose_bf16<<<dim3(H_/64, I_/64, E_), blk, 0, stream>>>(W2, W2t, I_, H_);
        moe_mfma<2,false><<<dim3(MAXTILES*32), blk, 0, stream>>>(
            hs_b, W1t, y1, nullptr, slot_tok, slot_w, tile_ex, ntiles, nullptr, I_, H_, 32);
        moe_mfma<3,false><<<dim3(MAXTILES*8), blk, 0, stream>>>(
            y1, W2t, nullptr, moe_out, slot_tok, slot_w, tile_ex, ntiles, nullptr, H_, I_, 8);
    } else {
        __hip_bfloat16* w1t = (__hip_bfloat16*)wreg;
        __hip_bfloat16* w2t = (__hip_bfloat16*)(wreg + 2*M1);
        __hip_bfloat16* y1  = (__hip_bfloat16*)(wreg + 4*M1);
        for (int e=0; e<E_; ++e) {
            transpose_bf16<<<dim3(I_/64, H_/64, 1), blk, 0, stream>>>(W1 + (size_t)e*H_*I_, w1t, H_, I_);
            moe_mfma<2,true><<<dim3(I_/128, 32), blk, 0, stream>>>(
                hs_b, w1t, y1, nullptr, slot_tok, slot_w, nullptr, cnt_pad+e, basep+e, I_, H_, 0);
            transpose_bf16<<<dim3(H_/64, I_/64, 1), blk, 0, stream>>>(W2 + (size_t)e*I_*H_, w2t, I_, H_);
            moe_mfma<3,true><<<dim3(H_/128, 32), blk, 0, stream>>>(
                y1, w2t, nullptr, moe_out, slot_tok, slot_w, nullptr, cnt_pad+e, basep+e, H_, I_, 0);
        }
    }

    ln_kernel<<<T_, blk, 0, stream>>>(moe_out, hs, ln2g, ln2b, out, nullptr);
}

// Round 13
// 767.336 us; speedup vs baseline: 1.0449x; 1.0449x over previous
//
#include <hip/hip_runtime.h>
#include <hip/hip_bf16.h>
#include <math.h>

#define H_ 1024
#define NH_ 16
#define HD_ 64
#define I_ 4096
#define E_ 8
#define B_ 2
#define S_ 2048
#define T_ 4096

#define MAXSLOTS 9216   // 2*T + 8*128 pad
#define MAXTILES 72     // MAXSLOTS/128

typedef __attribute__((ext_vector_type(8))) short short8v;
typedef __attribute__((ext_vector_type(4))) float f32x4;

#define GLOAD16(g, l) __builtin_amdgcn_global_load_lds((const __attribute__((address_space(1))) void*)(g), (__attribute__((address_space(3))) void*)(l), 16, 0, 0)

static __device__ inline unsigned short f2bf(float x) {
    __hip_bfloat16 h = __float2bfloat16(x);
    unsigned short u;
    __builtin_memcpy(&u, &h, 2);
    return u;
}
static __device__ inline float bf2f(unsigned short u) {
    __hip_bfloat16 h;
    __builtin_memcpy(&h, &u, 2);
    return __bfloat162float(h);
}

// exact-gelu via A&S 7.1.26 erf approximation (max abs err 1.5e-7 << bf16 rounding)
static __device__ inline float gelu_fast(float x) {
    float z  = x * 0.70710678118654752f;
    float az = fabsf(z);
    float t  = __builtin_amdgcn_rcpf(fmaf(0.3275911f, az, 1.f));
    float p  = fmaf(1.061405429f, t, -1.453152027f);
    p = fmaf(p, t, 1.421413741f);
    p = fmaf(p, t, -0.284496736f);
    p = fmaf(p, t, 0.254829592f);
    p = p * t;
    float e = __expf(-az*az);
    float er = 1.f - p*e;
    er = (z < 0.f) ? -er : er;
    return 0.5f * x * (1.f + er);
}

// ---------------- zero ----------------
__global__ void zero_kernel(float* __restrict__ p, int n) {
    int i = blockIdx.x * blockDim.x + threadIdx.x;
    if (i < n) p[i] = 0.f;
}

// ---------------- fp32 -> bf16 hi/lo split (elementwise) ----------------
__global__ __launch_bounds__(256) void split_bf16(
    const float* __restrict__ in, __hip_bfloat16* __restrict__ hi,
    __hip_bfloat16* __restrict__ lo, int n4)
{
    int i = blockIdx.x * blockDim.x + threadIdx.x;
    if (i >= n4) return;
    float4 v = ((const float4*)in)[i];
    unsigned short h0 = f2bf(v.x), h1 = f2bf(v.y), h2 = f2bf(v.z), h3 = f2bf(v.w);
    unsigned short l0 = f2bf(v.x - bf2f(h0)), l1 = f2bf(v.y - bf2f(h1));
    unsigned short l2 = f2bf(v.z - bf2f(h2)), l3 = f2bf(v.w - bf2f(h3));
    uint2 ph = make_uint2((unsigned)h0 | ((unsigned)h1 << 16), (unsigned)h2 | ((unsigned)h3 << 16));
    uint2 pl = make_uint2((unsigned)l0 | ((unsigned)l1 << 16), (unsigned)l2 | ((unsigned)l3 << 16));
    *(uint2*)((char*)hi + (size_t)i*8) = ph;
    *(uint2*)((char*)lo + (size_t)i*8) = pl;
}

// ---------------- merged transpose+split for the 4 projection weights ----------------
__global__ __launch_bounds__(256) void transpose_split_w4(
    const float* __restrict__ Wq, const float* __restrict__ Wk,
    const float* __restrict__ Wv, const float* __restrict__ Wd,
    __hip_bfloat16* __restrict__ wqkv_h, __hip_bfloat16* __restrict__ wqkv_l,
    __hip_bfloat16* __restrict__ wd_h, __hip_bfloat16* __restrict__ wd_l)
{
    __shared__ float t[64][65];
    const int z = blockIdx.z;
    const float* in = (z==0) ? Wq : (z==1) ? Wk : (z==2) ? Wv : Wd;
    __hip_bfloat16* oh = (z<3) ? (wqkv_h + (size_t)z*1024*1024) : wd_h;
    __hip_bfloat16* ol = (z<3) ? (wqkv_l + (size_t)z*1024*1024) : wd_l;
    int k0 = blockIdx.y*64, n0 = blockIdx.x*64;
    int tid = threadIdx.x;
    #pragma unroll
    for (int it=0; it<4; ++it) {
        int lin = it*256 + tid;
        int r = lin >> 4, c4 = (lin & 15) << 2;
        float4 v = *(const float4*)&in[(size_t)(k0+r)*1024 + n0 + c4];
        t[r][c4] = v.x; t[r][c4+1] = v.y; t[r][c4+2] = v.z; t[r][c4+3] = v.w;
    }
    __syncthreads();
    #pragma unroll
    for (int it=0; it<4; ++it) {
        int lin = it*256 + tid;
        int r = lin >> 4, c4 = (lin & 15) << 2;
        float v0 = t[c4][r], v1 = t[c4+1][r], v2 = t[c4+2][r], v3 = t[c4+3][r];
        ushort4 hh, ll;
        hh.x = f2bf(v0); hh.y = f2bf(v1); hh.z = f2bf(v2); hh.w = f2bf(v3);
        ll.x = f2bf(v0 - bf2f(hh.x)); ll.y = f2bf(v1 - bf2f(hh.y));
        ll.z = f2bf(v2 - bf2f(hh.z)); ll.w = f2bf(v3 - bf2f(hh.w));
        size_t o = (size_t)(n0+r)*1024 + k0 + c4;
        *(ushort4*)&oh[o] = hh;
        *(ushort4*)&ol[o] = ll;
    }
}

// ---------------- transpose + f32->bf16: in [K][N] -> out [N][K] (vectorized) ----------------
__global__ __launch_bounds__(256) void transpose_bf16(
    const float* __restrict__ in, __hip_bfloat16* __restrict__ outp, int K, int N)
{
    __shared__ float t[64][65];
    size_t eoff = (size_t)blockIdx.z * (size_t)K * (size_t)N;
    int k0 = blockIdx.y*64, n0 = blockIdx.x*64;
    int tid = threadIdx.x;
    #pragma unroll
    for (int it=0; it<4; ++it) {
        int lin = it*256 + tid;
        int r = lin >> 4, c4 = (lin & 15) << 2;
        float4 v = *(const float4*)&in[eoff + (size_t)(k0+r)*N + n0 + c4];
        t[r][c4] = v.x; t[r][c4+1] = v.y; t[r][c4+2] = v.z; t[r][c4+3] = v.w;
    }
    __syncthreads();
    #pragma unroll
    for (int it=0; it<4; ++it) {
        int lin = it*256 + tid;
        int r = lin >> 4, c4 = (lin & 15) << 2;
        ushort4 o;
        o.x = f2bf(t[c4][r]);   o.y = f2bf(t[c4+1][r]);
        o.z = f2bf(t[c4+2][r]); o.w = f2bf(t[c4+3][r]);
        *(ushort4*)&outp[eoff + (size_t)(n0+r)*K + k0 + c4] = o;
    }
}

// ---------------- bf16x3 GEMM: C = A@B (+bias), fp32-accurate, XCD-swizzled 1D grid ----------------
template<bool BIAS>
__global__ __launch_bounds__(256, 2) void gemm_bf16x3(
    const __hip_bfloat16* __restrict__ Ah, const __hip_bfloat16* __restrict__ Al,
    const __hip_bfloat16* __restrict__ Bh, const __hip_bfloat16* __restrict__ Bl,
    float* __restrict__ C, const float* __restrict__ bias, int N, int K, int nbx)
{
    const int tid = threadIdx.x;
    const int w = tid >> 6, lane = tid & 63;
    const int wg = blockIdx.x;
    const int xcd = wg & 7, ix = wg >> 3;
    const int byc = (int)(gridDim.x >> 3) / nbx;
    const int by = xcd*byc + ix / nbx;
    const int bx = ix % nbx;

    __shared__ __align__(16) char smem[65536];
    const int AH = 0, AL = 16384, BH = 32768, BL = 49152;

    const int laneg = lane >> 3;
    const int k2sw = ((lane & 7) ^ laneg) << 4;
    const int l15 = lane & 15, l4 = lane >> 4;
    const int wr = w >> 1, wc = w & 1;

    f32x4 acc[4][4];
    #pragma unroll
    for (int m=0;m<4;m++)
        #pragma unroll
        for (int n=0;n<4;n++) acc[m][n] = (f32x4){0.f,0.f,0.f,0.f};

    for (int k0 = 0; k0 < K; k0 += 64) {
        __syncthreads();
        #pragma unroll
        for (int qq=0;qq<4;qq++) {
            int arow = by*128 + (w*4+qq)*8 + laneg;
            int brow = bx*128 + (w*4+qq)*8 + laneg;
            size_t aoff = ((size_t)arow*K + k0)*2 + k2sw;
            size_t boff = ((size_t)brow*K + k0)*2 + k2sw;
            GLOAD16((const char*)Ah + aoff, smem + AH + (w*4+qq)*1024);
            GLOAD16((const char*)Al + aoff, smem + AL + (w*4+qq)*1024);
            GLOAD16((const char*)Bh + boff, smem + BH + (w*4+qq)*1024);
            GLOAD16((const char*)Bl + boff, smem + BL + (w*4+qq)*1024);
        }
        __syncthreads();

        short8v ahf[4][2], alf[4][2], bhf[4][2], blf[4][2];
        #pragma unroll
        for (int m=0;m<4;m++) {
            int row = wr*64 + m*16 + l15;
            int rb = row << 7, rsw = (row & 7) << 4;
            #pragma unroll
            for (int s=0;s<2;s++) {
                int off = rb + ((s*64 + (l4<<4)) ^ rsw);
                ahf[m][s] = *(const short8v*)(smem + AH + off);
                alf[m][s] = *(const short8v*)(smem + AL + off);
            }
        }
        #pragma unroll
        for (int n=0;n<4;n++) {
            int row = wc*64 + n*16 + l15;
            int rb = row << 7, rsw = (row & 7) << 4;
            #pragma unroll
            for (int s=0;s<2;s++) {
                int off = rb + ((s*64 + (l4<<4)) ^ rsw);
                bhf[n][s] = *(const short8v*)(smem + BH + off);
                blf[n][s] = *(const short8v*)(smem + BL + off);
            }
        }
        #pragma unroll
        for (int m=0;m<4;m++)
            #pragma unroll
            for (int n=0;n<4;n++)
                #pragma unroll
                for (int s=0;s<2;s++) {
                    acc[m][n] = __builtin_amdgcn_mfma_f32_16x16x32_bf16(ahf[m][s], bhf[n][s], acc[m][n], 0, 0, 0);
                    acc[m][n] = __builtin_amdgcn_mfma_f32_16x16x32_bf16(ahf[m][s], blf[n][s], acc[m][n], 0, 0, 0);
                    acc[m][n] = __builtin_amdgcn_mfma_f32_16x16x32_bf16(alf[m][s], bhf[n][s], acc[m][n], 0, 0, 0);
                }
    }

    #pragma unroll
    for (int m=0;m<4;m++)
        #pragma unroll
        for (int j=0;j<4;j++) {
            int orow = by*128 + wr*64 + m*16 + l4*4 + j;
            #pragma unroll
            for (int n=0;n<4;n++) {
                int ocol = bx*128 + wc*64 + n*16 + l15;
                float v = acc[m][n][j];
                if (BIAS) v += bias[ocol];
                C[(size_t)orow*N + ocol] = v;
            }
        }
}

// ---------------- MFMA MoE GEMM ----------------
// MODE 2: y1 = gelu(gather(hs_b) @ W1t^T) -> bf16 (LDS-coalesced store)
// MODE 3: moe_out[tok] += w * (y1 @ W2t^T) -> f32 atomic
// FULL (!PE): 1D grid, XCD-swizzled, bx-MAJOR within XCD (L2-resident W-slice + A-tiles).
template<int MODE, bool PE>
__global__ __launch_bounds__(256) void moe_mfma(
    const __hip_bfloat16* __restrict__ A,
    const __hip_bfloat16* __restrict__ Bt,
    __hip_bfloat16* __restrict__ y1,
    float* __restrict__ moe_out,
    const int* __restrict__ slot_token,
    const float* __restrict__ slot_w,
    const int* __restrict__ tile_expert,
    const int* __restrict__ cnt_ptr,
    const int* __restrict__ base_ptr,
    int N, int K, int nbx)
{
    const int tid = threadIdx.x;
    const int w = tid >> 6, lane = tid & 63;

    int bx, slot0, y1row0;
    const __hip_bfloat16* Bp;
    if (PE) {
        bx = blockIdx.x;
        int tloc = blockIdx.y;
        if ((tloc << 7) >= *cnt_ptr) return;
        slot0 = *base_ptr + (tloc << 7);
        y1row0 = tloc << 7;
        Bp = Bt;
    } else {
        const int wg = blockIdx.x;
        const int xcd = wg & 7, ix = wg >> 3;
        const int byc = (int)(gridDim.x >> 3) / nbx;
        int gt = xcd*byc + ix % byc;                   // bx-major: tile varies fastest
        bx = ix / byc;
        if (gt >= *cnt_ptr) return;
        int e = tile_expert[gt];
        Bp = Bt + (size_t)e * (size_t)K * (size_t)N;
        slot0 = gt << 7;
        y1row0 = gt << 7;
    }

    __shared__ __align__(16) char smem[32768];

    const int laneg = lane >> 3;
    const int k2sw = ((lane & 7) ^ laneg) << 4;

    int tokq[4];
    if (MODE == 2) {
        #pragma unroll
        for (int qq=0;qq<4;qq++) {
            int t0 = slot_token[slot0 + (w*4+qq)*8 + laneg];
            tokq[qq] = t0 < 0 ? 0 : t0;
        }
    }

    f32x4 acc[4][4];
    #pragma unroll
    for (int m=0;m<4;m++)
        #pragma unroll
        for (int n=0;n<4;n++) acc[m][n] = (f32x4){0.f,0.f,0.f,0.f};

    const int l15 = lane & 15;
    const int l4  = lane >> 4;
    const int wr = w >> 1, wc = w & 1;

    for (int k0 = 0; k0 < K; k0 += 64) {
        __syncthreads();
        #pragma unroll
        for (int qq=0;qq<4;qq++) {
            const char* ga;
            if (MODE == 2) {
                ga = (const char*)A + (((size_t)tokq[qq])*K + k0)*2 + k2sw;
            } else {
                int row = y1row0 + (w*4+qq)*8 + laneg;
                ga = (const char*)A + ((size_t)row*K + k0)*2 + k2sw;
            }
            GLOAD16(ga, smem + (w*4+qq)*1024);
        }
        #pragma unroll
        for (int qq=0;qq<4;qq++) {
            int row = bx*128 + (w*4+qq)*8 + laneg;
            const char* gb = (const char*)Bp + ((size_t)row*K + k0)*2 + k2sw;
            GLOAD16(gb, smem + 16384 + (w*4+qq)*1024);
        }
        __syncthreads();

        short8v a_frag[4][2], b_frag[4][2];
        #pragma unroll
        for (int m=0;m<4;m++) {
            int row = wr*64 + m*16 + l15;
            int rb = row << 7;
            #pragma unroll
            for (int s=0;s<2;s++) {
                int off = rb + ((s*64 + (l4<<4)) ^ ((row&7)<<4));
                a_frag[m][s] = *(const short8v*)(smem + off);
            }
        }
        #pragma unroll
        for (int n=0;n<4;n++) {
            int row = wc*64 + n*16 + l15;
            int rb = row << 7;
            #pragma unroll
            for (int s=0;s<2;s++) {
                int off = rb + ((s*64 + (l4<<4)) ^ ((row&7)<<4));
                b_frag[n][s] = *(const short8v*)(smem + 16384 + off);
            }
        }
        #pragma unroll
        for (int m=0;m<4;m++)
            #pragma unroll
            for (int n=0;n<4;n++) {
                acc[m][n] = __builtin_amdgcn_mfma_f32_16x16x32_bf16(a_frag[m][0], b_frag[n][0], acc[m][n], 0, 0, 0);
                acc[m][n] = __builtin_amdgcn_mfma_f32_16x16x32_bf16(a_frag[m][1], b_frag[n][1], acc[m][n], 0, 0, 0);
            }
    }

    if (MODE == 3) {
        #pragma unroll
        for (int m=0;m<4;m++) {
            #pragma unroll
            for (int j=0;j<4;j++) {
                int orow = wr*64 + m*16 + l4*4 + j;
                int slot = slot0 + orow;
                int tok = slot_token[slot];
                if (tok < 0) continue;
                float sw = slot_w[slot];
                #pragma unroll
                for (int n=0;n<4;n++) {
                    int ocol = bx*128 + wc*64 + n*16 + l15;
                    atomicAdd(&moe_out[(size_t)tok*H_ + ocol], sw * acc[m][n][j]);
                }
            }
        }
    } else {
        // gelu -> LDS [128 rows][128 bf16 cols, 256B pitch] -> coalesced b128 stores
        __syncthreads();   // all waves done reading smem from the main loop
        #pragma unroll
        for (int m=0;m<4;m++)
            #pragma unroll
            for (int j=0;j<4;j++) {
                int orow = wr*64 + m*16 + l4*4 + j;
                #pragma unroll
                for (int n=0;n<4;n++) {
                    int ocol = wc*64 + n*16 + l15;
                    unsigned short g = f2bf(gelu_fast(acc[m][n][j]));
                    *(unsigned short*)(smem + orow*256 + ocol*2) = g;
                }
            }
        __syncthreads();
        // lanes 0-15 cover one full 256B row segment-wise: fully coalesced
        #pragma unroll
        for (int s=0;s<8;s++) {
            int row = w*32 + s*4 + l4;
            short8v v = *(const short8v*)(smem + row*256 + l15*16);
            *(short8v*)((char*)y1 + ((size_t)(y1row0 + row)*N + bx*128 + l15*8)*2) = v;
        }
    }
}

// ---------------- RoPE + split: fp32 qkv[t][3072] -> rotated bf16 hi/lo, head-major ----------------
__global__ void rope_split_kernel(
    const float* __restrict__ qkv,
    __hip_bfloat16* __restrict__ qh, __hip_bfloat16* __restrict__ ql,
    __hip_bfloat16* __restrict__ kh, __hip_bfloat16* __restrict__ kl)
{
    int idx = blockIdx.x * blockDim.x + threadIdx.x;  // T*NH*32
    int i = idx & 31;
    int n = (idx >> 5) & (NH_-1);
    int t = idx >> 9;
    int b = t >> 11;
    int pos = t & (S_ - 1);
    float inv = exp2f((float)i * (-13.287712379549449f / 32.f));
    float ang = (float)pos * inv;
    float c = cosf(ang), s = sinf(ang);
    size_t base = (size_t)t*3072 + (size_t)n*64;
    size_t obase = ((size_t)(b*NH_ + n)*S_ + pos)*64;

    float q1 = qkv[base+i], q2 = qkv[base+i+32];
    float qo1 = (q1*c - q2*s)*0.125f;
    float qo2 = (q2*c + q1*s)*0.125f;
    unsigned short h1 = f2bf(qo1), h2 = f2bf(qo2);
    qh[obase+i]    = *(__hip_bfloat16*)&h1;
    qh[obase+i+32] = *(__hip_bfloat16*)&h2;
    unsigned short lo1 = f2bf(qo1 - bf2f(h1)), lo2 = f2bf(qo2 - bf2f(h2));
    ql[obase+i]    = *(__hip_bfloat16*)&lo1;
    ql[obase+i+32] = *(__hip_bfloat16*)&lo2;

    float k1 = qkv[base+1024+i], k2 = qkv[base+1024+i+32];
    float ko1 = k1*c - k2*s;
    float ko2 = k2*c + k1*s;
    unsigned short kh1 = f2bf(ko1), kh2 = f2bf(ko2);
    kh[obase+i]    = *(__hip_bfloat16*)&kh1;
    kh[obase+i+32] = *(__hip_bfloat16*)&kh2;
    unsigned short kl1 = f2bf(ko1 - bf2f(kh1)), kl2 = f2bf(ko2 - bf2f(kh2));
    kl[obase+i]    = *(__hip_bfloat16*)&kl1;
    kl[obase+i+32] = *(__hip_bfloat16*)&kl2;
}

// ---------------- V transpose + split ----------------
__global__ __launch_bounds__(256) void vsplit_t_kernel(
    const float* __restrict__ qkv,
    __hip_bfloat16* __restrict__ vth, __hip_bfloat16* __restrict__ vtl)
{
    __shared__ float t[64][65];
    const int s0 = blockIdx.x*64;
    const int hn = blockIdx.y;
    const int b  = blockIdx.z;
    const int tid = threadIdx.x;
    #pragma unroll
    for (int it=0; it<4; ++it) {
        int lin = it*256 + tid;
        int r = lin >> 4, c4 = (lin & 15) << 2;
        float4 vv = *(const float4*)&qkv[(size_t)(b*S_ + s0 + r)*3072 + 2048 + hn*64 + c4];
        t[r][c4] = vv.x; t[r][c4+1] = vv.y; t[r][c4+2] = vv.z; t[r][c4+3] = vv.w;
    }
    __syncthreads();
    size_t obase = (size_t)(b*NH_ + hn)*64*S_;
    #pragma unroll
    for (int it=0; it<4; ++it) {
        int lin = it*256 + tid;
        int d = lin >> 4, c4 = (lin & 15) << 2;
        float v0 = t[c4][d], v1 = t[c4+1][d], v2 = t[c4+2][d], v3 = t[c4+3][d];
        ushort4 hh, ll;
        hh.x = f2bf(v0); hh.y = f2bf(v1); hh.z = f2bf(v2); hh.w = f2bf(v3);
        ll.x = f2bf(v0 - bf2f(hh.x)); ll.y = f2bf(v1 - bf2f(hh.y));
        ll.z = f2bf(v2 - bf2f(hh.z)); ll.w = f2bf(v3 - bf2f(hh.w));
        size_t o = obase + (size_t)d*S_ + s0 + c4;
        *(ushort4*)&vth[o] = hh;
        *(ushort4*)&vtl[o] = ll;
    }
}

// ---------------- MFMA attention: bf16x3, XCD-swizzled, NO max-tracking softmax ----------------
__global__ __launch_bounds__(256, 3) void attn_mfma(
    const __hip_bfloat16* __restrict__ qh, const __hip_bfloat16* __restrict__ ql,
    const __hip_bfloat16* __restrict__ kh, const __hip_bfloat16* __restrict__ kl,
    const __hip_bfloat16* __restrict__ vth, const __hip_bfloat16* __restrict__ vtl,
    __hip_bfloat16* __restrict__ ctx_hi, __hip_bfloat16* __restrict__ ctx_lo)
{
    const int wg = blockIdx.x;
    const int xcd = wg & 7;
    const int ix = wg >> 3;
    const int head = xcd*4 + (ix >> 5);
    const int qt = ix & 31;
    const int b = head >> 4, hn = head & 15;

    const int tid = threadIdx.x;
    const int w = tid >> 6, lane = tid & 63;
    const int l15 = lane & 15, l4 = lane >> 4;
    const int laneg = lane >> 3;
    const int k2sw = ((lane & 7) ^ laneg) << 4;

    __shared__ __align__(16) char smem[49152];
    const int KHo = 0, KLo = 8192, VHo = 16384, VLo = 24576, PHo = 32768, PLo = 40960;

    const size_t kbase = (size_t)head*S_*64;
    const size_t vbase = (size_t)head*64*S_;

    #pragma unroll
    for (int qq=0;qq<2;qq++) {
        int c = w*2 + qq;
        int row = qt*64 + c*8 + laneg;
        size_t off = (kbase + (size_t)row*64)*2 + k2sw;
        GLOAD16((const char*)qh + off, smem + PHo + c*1024);
        GLOAD16((const char*)ql + off, smem + PLo + c*1024);
    }
    __syncthreads();
    short8v qhf[2], qlf[2];
    {
        int row = w*16 + l15;
        int rsw = (row & 7) << 4;
        #pragma unroll
        for (int s=0;s<2;s++) {
            int off = row*128 + ((s*64 + l4*16) ^ rsw);
            qhf[s] = *(const short8v*)(smem + PHo + off);
            qlf[s] = *(const short8v*)(smem + PLo + off);
        }
    }

    f32x4 acc[4];
    #pragma unroll
    for (int db=0;db<4;db++) acc[db] = (f32x4){0.f,0.f,0.f,0.f};
    float lrun[4] = {0.f, 0.f, 0.f, 0.f};

    for (int kt=0; kt<S_/64; ++kt) {
        __syncthreads();
        #pragma unroll
        for (int qq=0;qq<2;qq++) {
            int c = w*2 + qq;
            int r8 = c*8 + laneg;
            size_t koff = (kbase + (size_t)(kt*64 + r8)*64)*2 + k2sw;
            GLOAD16((const char*)kh + koff, smem + KHo + c*1024);
            GLOAD16((const char*)kl + koff, smem + KLo + c*1024);
            size_t voff = (vbase + (size_t)r8*S_ + kt*64)*2 + k2sw;
            GLOAD16((const char*)vth + voff, smem + VHo + c*1024);
            GLOAD16((const char*)vtl + voff, smem + VLo + c*1024);
        }
        __syncthreads();

        f32x4 s_acc[4];
        #pragma unroll
        for (int cb=0;cb<4;cb++) {
            s_acc[cb] = (f32x4){0.f,0.f,0.f,0.f};
            int row = cb*16 + l15;
            int rsw = (row & 7) << 4;
            #pragma unroll
            for (int s=0;s<2;s++) {
                int off = row*128 + ((s*64 + l4*16) ^ rsw);
                short8v khf = *(const short8v*)(smem + KHo + off);
                short8v klf = *(const short8v*)(smem + KLo + off);
                s_acc[cb] = __builtin_amdgcn_mfma_f32_16x16x32_bf16(qhf[s], khf, s_acc[cb], 0, 0, 0);
                s_acc[cb] = __builtin_amdgcn_mfma_f32_16x16x32_bf16(qhf[s], klf, s_acc[cb], 0, 0, 0);
                s_acc[cb] = __builtin_amdgcn_mfma_f32_16x16x32_bf16(qlf[s], khf, s_acc[cb], 0, 0, 0);
            }
        }

        #pragma unroll
        for (int cb=0;cb<4;cb++)
            #pragma unroll
            for (int j=0;j<4;j++) {
                float p = __expf(s_acc[cb][j]);
                lrun[j] += p;
                int prow = w*16 + l4*4 + j;
                unsigned short hh = f2bf(p);
                unsigned short ll = f2bf(p - bf2f(hh));
                int off = prow*128 + (((cb*16 + l15)*2) ^ ((prow&7)<<4));
                *(unsigned short*)(smem + PHo + off) = hh;
                *(unsigned short*)(smem + PLo + off) = ll;
            }
        asm volatile("s_waitcnt lgkmcnt(0)" ::: "memory");
        __builtin_amdgcn_sched_barrier(0);

        short8v pah[2], pal[2];
        {
            int row = w*16 + l15;
            int rsw = (row & 7) << 4;
            #pragma unroll
            for (int s=0;s<2;s++) {
                int off = row*128 + ((s*64 + l4*16) ^ rsw);
                pah[s] = *(const short8v*)(smem + PHo + off);
                pal[s] = *(const short8v*)(smem + PLo + off);
            }
        }
        #pragma unroll
        for (int db=0;db<4;db++) {
            int row = db*16 + l15;
            int rsw = (row & 7) << 4;
            #pragma unroll
            for (int s=0;s<2;s++) {
                int off = row*128 + ((s*64 + l4*16) ^ rsw);
                short8v vhf = *(const short8v*)(smem + VHo + off);
                short8v vlf = *(const short8v*)(smem + VLo + off);
                acc[db] = __builtin_amdgcn_mfma_f32_16x16x32_bf16(pah[s], vhf, acc[db], 0, 0, 0);
                acc[db] = __builtin_amdgcn_mfma_f32_16x16x32_bf16(pah[s], vlf, acc[db], 0, 0, 0);
                acc[db] = __builtin_amdgcn_mfma_f32_16x16x32_bf16(pal[s], vhf, acc[db], 0, 0, 0);
            }
        }
    }

    #pragma unroll
    for (int j=0;j<4;j++) {
        float s = lrun[j];
        #pragma unroll
        for (int m=8;m;m>>=1) s += __shfl_xor(s, m);
        lrun[j] = s;
    }

    #pragma unroll
    for (int db=0;db<4;db++)
        #pragma unroll
        for (int j=0;j<4;j++) {
            int qrow = qt*64 + w*16 + l4*4 + j;
            float o = acc[db][j] / lrun[j];
            unsigned short hh = f2bf(o);
            unsigned short ll = f2bf(o - bf2f(hh));
            size_t oidx = (size_t)(b*S_ + qrow)*H_ + hn*64 + db*16 + l15;
            ctx_hi[oidx] = *(__hip_bfloat16*)&hh;
            ctx_lo[oidx] = *(__hip_bfloat16*)&ll;
        }
}

// ---------------- layernorm (residual fused, optional bf16 out) ----------------
__global__ __launch_bounds__(256) void ln_kernel(
    const float* __restrict__ a, const float* __restrict__ res,
    const float* __restrict__ g, const float* __restrict__ beta,
    float* __restrict__ out, __hip_bfloat16* __restrict__ outb)
{
    int row = blockIdx.x, tid = threadIdx.x;
    const float4 va = ((const float4*)(a + (size_t)row*H_))[tid];
    const float4 vr = ((const float4*)(res + (size_t)row*H_))[tid];
    float x0=va.x+vr.x, x1=va.y+vr.y, x2=va.z+vr.z, x3=va.w+vr.w;
    float s  = x0+x1+x2+x3;
    float ss = x0*x0 + x1*x1 + x2*x2 + x3*x3;
    #pragma unroll
    for (int off=32; off; off>>=1) { s += __shfl_xor(s, off); ss += __shfl_xor(ss, off); }
    __shared__ float red[8];
    if ((tid&63)==0) { red[tid>>6]=s; red[4+(tid>>6)]=ss; }
    __syncthreads();
    if (tid==0) { red[0]=red[0]+red[1]+red[2]+red[3]; red[4]=red[4]+red[5]+red[6]+red[7]; }
    __syncthreads();
    float mu  = red[0] * (1.f/H_);
    float var = red[4] * (1.f/H_) - mu*mu;
    float rs = rsqrtf(fmaxf(var, 0.f) + 1e-12f);
    const float4 vg = ((const float4*)g)[tid];
    const float4 vb = ((const float4*)beta)[tid];
    float4 vo;
    vo.x = (x0-mu)*rs*vg.x + vb.x;
    vo.y = (x1-mu)*rs*vg.y + vb.y;
    vo.z = (x2-mu)*rs*vg.z + vb.z;
    vo.w = (x3-mu)*rs*vg.w + vb.w;
    ((float4*)(out + (size_t)row*H_))[tid] = vo;
    if (outb) {
        unsigned int p0 = (unsigned)f2bf(vo.x) | ((unsigned)f2bf(vo.y) << 16);
        unsigned int p1 = (unsigned)f2bf(vo.z) | ((unsigned)f2bf(vo.w) << 16);
        ((uint2*)(outb + (size_t)row*H_))[tid] = make_uint2(p0, p1);
    }
}

// ---------------- router: 64 blocks x 64 tokens, register-accumulated stats ----------------
__global__ __launch_bounds__(256) void router_kernel(
    const float* __restrict__ hs, const float* __restrict__ Wg,
    int* __restrict__ tok_e, float* __restrict__ tok_w,
    int* __restrict__ counts, float* __restrict__ P_sum)
{
    const int w = threadIdx.x >> 6, lane = threadIdx.x & 63;
    float psum[E_];
    int cnt[E_];
    #pragma unroll
    for (int e=0;e<E_;e++){ psum[e]=0.f; cnt[e]=0; }

    for (int it=0; it<16; ++it) {
        int t = blockIdx.x*64 + it*4 + w;
        const float* row = hs + (size_t)t * H_;
        float acc[E_];
        #pragma unroll
        for (int e=0;e<E_;e++) acc[e]=0.f;
        for (int i16=0; i16<16; ++i16) {
            int i = i16*64 + lane;
            float xv = row[i];
            const float* wg = Wg + (size_t)i*E_;
            #pragma unroll
            for (int e=0;e<E_;e++) acc[e] = fmaf(xv, wg[e], acc[e]);
        }
        #pragma unroll
        for (int e=0;e<E_;e++) {
            float vv = acc[e];
            #pragma unroll
            for (int off=32; off; off>>=1) vv += __shfl_xor(vv, off);
            acc[e] = vv;
        }
        float mx = acc[0];
        #pragma unroll
        for (int e=1;e<E_;e++) mx = fmaxf(mx, acc[e]);
        float p[E_], se=0.f;
        #pragma unroll
        for (int e=0;e<E_;e++){ p[e] = __expf(acc[e]-mx); se += p[e]; }
        float isv = 1.f/se;
        #pragma unroll
        for (int e=0;e<E_;e++){ p[e]*=isv; psum[e] += p[e]; }
        int e1=0;
        #pragma unroll
        for (int e=1;e<E_;e++) if (p[e] > p[e1]) e1=e;
        int e2 = (e1==0)?1:0;
        #pragma unroll
        for (int e=0;e<E_;e++) if (e!=e1 && p[e] > p[e2]) e2=e;
        #pragma unroll
        for (int e=0;e<E_;e++) cnt[e] += (e==e1?1:0) + (e==e2?1:0);
        if (lane==0) {
            float w1=p[e1], w2=p[e2], si=1.f/(w1+w2);
            tok_e[t*2]=e1; tok_e[t*2+1]=e2;
            tok_w[t*2]=w1*si; tok_w[t*2+1]=w2*si;
        }
    }
    if (lane==0) {
        #pragma unroll
        for (int e=0;e<E_;e++) {
            atomicAdd(&P_sum[e], psum[e]);
            atomicAdd(&counts[e], cnt[e]);
        }
    }
}

__global__ void router_finalize(
    const int* __restrict__ counts, const float* __restrict__ P_sum,
    int* __restrict__ base, int* __restrict__ cursor,
    int* __restrict__ cnt_pad, int* __restrict__ ntiles,
    int* __restrict__ slot_token, int* __restrict__ tile_expert,
    float* __restrict__ aux_out)
{
    __shared__ int sbase[E_+1];
    if (threadIdx.x == 0) {
        int bacc = 0;
        float aux = 0.f;
        for (int e=0;e<E_;e++) {
            sbase[e] = bacc; base[e] = bacc;
            int cp = (counts[e] + 127) & ~127;
            cnt_pad[e] = cp;
            bacc += cp;
            cursor[e] = 0;
            aux += ((float)counts[e]/(float)T_) * (P_sum[e]/(float)T_);
        }
        sbase[E_] = bacc;
        *ntiles = bacc >> 7;
        *aux_out = (float)E_ * aux;
    }
    __syncthreads();
    for (int sIdx = (int)threadIdx.x; sIdx < MAXSLOTS; sIdx += (int)blockDim.x)
        slot_token[sIdx] = -1;
    for (int tt = (int)threadIdx.x; tt < MAXTILES; tt += (int)blockDim.x) {
        int s = tt*128;
        int e = E_-1;
        for (int qe=0; qe<E_; ++qe) if (s < sbase[qe+1]) { e = qe; break; }
        tile_expert[tt] = e;
    }
}

__global__ void scatter_slots(
    const int* __restrict__ tok_e, const float* __restrict__ tok_w,
    const int* __restrict__ base, int* __restrict__ cursor,
    int* __restrict__ slot_token, float* __restrict__ slot_w)
{
    int t = blockIdx.x*blockDim.x + threadIdx.x;
    if (t >= T_) return;
    #pragma unroll
    for (int j=0;j<2;j++) {
        int e = tok_e[t*2+j];
        int pos = atomicAdd(&cursor[e], 1);
        int s = base[e] + pos;
        slot_token[s] = t;
        slot_w[s] = tok_w[t*2+j];
    }
}

extern "C" void kernel_launch(void* const* d_in, const int* in_sizes, int n_in,
                              void* d_out, int out_size, void* d_ws, size_t ws_size,
                              hipStream_t stream)
{
    const float* x    = (const float*)d_in[0];
    const float* Wq   = (const float*)d_in[1];
    const float* Wk   = (const float*)d_in[2];
    const float* Wv   = (const float*)d_in[3];
    const float* Wd   = (const float*)d_in[4];
    const float* bd   = (const float*)d_in[5];
    const float* ln1g = (const float*)d_in[6];
    const float* ln1b = (const float*)d_in[7];
    const float* Wg   = (const float*)d_in[8];
    const float* W1   = (const float*)d_in[9];
    const float* W2   = (const float*)d_in[10];
    const float* ln2g = (const float*)d_in[11];
    const float* ln2b = (const float*)d_in[12];
    float* out = (float*)d_out;

    float* f0 = (float*)d_ws;
    const size_t M1 = 1u << 20;
    float* qkv      = f0;
    float* attn_out = f0 + 12*M1;
    float* hs       = f0;
    float* moe_out  = f0 + 4*M1;
    __hip_bfloat16* hs_b = (__hip_bfloat16*)(f0 + 16*M1);

    float* misc = f0 + 18*M1;
    int*   misc_i = (int*)misc;
    int*   tok_e   = misc_i;
    float* tok_w   = misc + 8192;
    int*   slot_tok= misc_i + 16384;
    float* slot_w  = misc + 25600;
    int*   counts  = misc_i + 34816;
    float* P_sum   = misc + 34824;
    int*   cursor  = misc_i + 34832;
    int*   basep   = misc_i + 34840;
    int*   cnt_pad = misc_i + 34848;
    int*   ntiles  = misc_i + 34856;
    int*   tile_ex = misc_i + 34857;

    float* off_p = f0 + 18*M1 + 65536;
    __hip_bfloat16* xa_hi = (__hip_bfloat16*)(off_p);
    __hip_bfloat16* xa_lo = (__hip_bfloat16*)(off_p + 2*M1);
    __hip_bfloat16* at_qh = (__hip_bfloat16*)(off_p + 4*M1);
    __hip_bfloat16* at_ql = (__hip_bfloat16*)(off_p + 6*M1);
    __hip_bfloat16* at_kh = (__hip_bfloat16*)(off_p + 8*M1);
    __hip_bfloat16* at_kl = (__hip_bfloat16*)(off_p + 10*M1);
    __hip_bfloat16* at_vh = (__hip_bfloat16*)(off_p + 12*M1);
    __hip_bfloat16* at_vl = (__hip_bfloat16*)(off_p + 14*M1);
    __hip_bfloat16* wqkv_h = (__hip_bfloat16*)(off_p + 16*M1);
    __hip_bfloat16* wqkv_l = (__hip_bfloat16*)(off_p + 16*M1 + 3*(M1/2));
    __hip_bfloat16* wd_h = (__hip_bfloat16*)(off_p + 19*M1);
    __hip_bfloat16* wd_l = (__hip_bfloat16*)(off_p + 19*M1 + M1/2);

    float* wreg = off_p + 4*M1;
    const bool FULL = ws_size >= (size_t)300*1024*1024;

    dim3 blk(256);

    split_bf16<<<(T_*H_/4)/256, blk, 0, stream>>>(x, xa_hi, xa_lo, T_*H_/4);
    transpose_split_w4<<<dim3(16,16,4), blk, 0, stream>>>(Wq, Wk, Wv, Wd, wqkv_h, wqkv_l, wd_h, wd_l);

    gemm_bf16x3<false><<<dim3(768), blk, 0, stream>>>(xa_hi, xa_lo, wqkv_h, wqkv_l, qkv, nullptr, 3072, H_, 24);

    rope_split_kernel<<<(T_*NH_*32)/256, blk, 0, stream>>>(qkv, at_qh, at_ql, at_kh, at_kl);
    vsplit_t_kernel<<<dim3(S_/64, NH_, B_), blk, 0, stream>>>(qkv, at_vh, at_vl);

    attn_mfma<<<dim3(B_*NH_*(S_/64)), blk, 0, stream>>>(at_qh, at_ql, at_kh, at_kl, at_vh, at_vl, xa_hi, xa_lo);

    gemm_bf16x3<true><<<dim3(256), blk, 0, stream>>>(xa_hi, xa_lo, wd_h, wd_l, attn_out, bd, H_, H_, 8);

    zero_kernel<<<(T_*H_)/256, blk, 0, stream>>>(moe_out, T_*H_);
    zero_kernel<<<1, blk, 0, stream>>>(misc + 34816, 16);

    ln_kernel<<<T_, blk, 0, stream>>>(attn_out, x, ln1g, ln1b, hs, hs_b);

    router_kernel<<<T_/64, blk, 0, stream>>>(hs, Wg, tok_e, tok_w, counts, P_sum);
    router_finalize<<<1, blk, 0, stream>>>(counts, P_sum, basep, cursor, cnt_pad, ntiles,
                                           slot_tok, tile_ex, out + (size_t)T_*H_);
    scatter_slots<<<T_/256, blk, 0, stream>>>(tok_e, tok_w, basep, cursor, slot_tok, slot_w);

    if (FULL) {
        __hip_bfloat16* W1t = (__hip_bfloat16*)wreg;
        __hip_bfloat16* W2t = (__hip_bfloat16*)(wreg + 16*M1);
        __hip_bfloat16* y1  = (__hip_bfloat16*)(wreg + 32*M1);
        transpose_bf16<<<dim3(I_/64, H_/64, E_), blk, 0, stream>>>(W1, W1t, H_, I_);
        transpose_bf16<<<dim3(H_/64, I_/64, E_), blk, 0, stream>>>(W2, W2t, I_, H_);
        moe_mfma<2,false><<<dim3(MAXTILES*32), blk, 0, stream>>>(
            hs_b, W1t, y1, nullptr, slot_tok, slot_w, tile_ex, ntiles, nullptr, I_, H_, 32);
        moe_mfma<3,false><<<dim3(MAXTILES*8), blk, 0, stream>>>(
            y1, W2t, nullptr, moe_out, slot_tok, slot_w, tile_ex, ntiles, nullptr, H_, I_, 8);
    } else {
        __hip_bfloat16* w1t = (__hip_bfloat16*)wreg;
        __hip_bfloat16* w2t = (__hip_bfloat16*)(wreg + 2*M1);
        __hip_bfloat16* y1  = (__hip_bfloat16*)(wreg + 4*M1);
        for (int e=0; e<E_; ++e) {
            transpose_bf16<<<dim3(I_/64, H_/64, 1), blk, 0, stream>>>(W1 + (size_t)e*H_*I_, w1t, H_, I_);
            moe_mfma<2,true><<<dim3(I_/128, 32), blk, 0, stream>>>(
                hs_b, w1t, y1, nullptr, slot_tok, slot_w, nullptr, cnt_pad+e, basep+e, I_, H_, 0);
            transpose_bf16<<<dim3(H_/64, I_/64, 1), blk, 0, stream>>>(W2 + (size_t)e*I_*H_, w2t, I_, H_);
            moe_mfma<3,true><<<dim3(H_/128, 32), blk, 0, stream>>>(
                y1, w2t, nullptr, moe_out, slot_tok, slot_w, nullptr, cnt_pad+e, basep+e, H_, I_, 0);
        }
    }

    ln_kernel<<<T_, blk, 0, stream>>>(moe_out, hs, ln2g, ln2b, out, nullptr);
}

// Round 14
// 762.615 us; speedup vs baseline: 1.0514x; 1.0062x over previous
//
#include <hip/hip_runtime.h>
#include <hip/hip_bf16.h>
#include <math.h>

#define H_ 1024
#define NH_ 16
#define HD_ 64
#define I_ 4096
#define E_ 8
#define B_ 2
#define S_ 2048
#define T_ 4096

#define MAXSLOTS 9216   // 2*T + 8*128 pad
#define MAXTILES 72     // MAXSLOTS/128

typedef __attribute__((ext_vector_type(8))) short short8v;
typedef __attribute__((ext_vector_type(4))) float f32x4;

#define GLOAD16(g, l) __builtin_amdgcn_global_load_lds((const __attribute__((address_space(1))) void*)(g), (__attribute__((address_space(3))) void*)(l), 16, 0, 0)

static __device__ inline unsigned short f2bf(float x) {
    __hip_bfloat16 h = __float2bfloat16(x);
    unsigned short u;
    __builtin_memcpy(&u, &h, 2);
    return u;
}
static __device__ inline float bf2f(unsigned short u) {
    __hip_bfloat16 h;
    __builtin_memcpy(&h, &u, 2);
    return __bfloat162float(h);
}

// exact-gelu via A&S 7.1.26 erf approximation (max abs err 1.5e-7 << bf16 rounding)
static __device__ inline float gelu_fast(float x) {
    float z  = x * 0.70710678118654752f;
    float az = fabsf(z);
    float t  = __builtin_amdgcn_rcpf(fmaf(0.3275911f, az, 1.f));
    float p  = fmaf(1.061405429f, t, -1.453152027f);
    p = fmaf(p, t, 1.421413741f);
    p = fmaf(p, t, -0.284496736f);
    p = fmaf(p, t, 0.254829592f);
    p = p * t;
    float e = __expf(-az*az);
    float er = 1.f - p*e;
    er = (z < 0.f) ? -er : er;
    return 0.5f * x * (1.f + er);
}

// ---------------- zero ----------------
__global__ void zero_kernel(float* __restrict__ p, int n) {
    int i = blockIdx.x * blockDim.x + threadIdx.x;
    if (i < n) p[i] = 0.f;
}

// ---------------- fp32 -> bf16 hi/lo split (elementwise) ----------------
__global__ __launch_bounds__(256) void split_bf16(
    const float* __restrict__ in, __hip_bfloat16* __restrict__ hi,
    __hip_bfloat16* __restrict__ lo, int n4)
{
    int i = blockIdx.x * blockDim.x + threadIdx.x;
    if (i >= n4) return;
    float4 v = ((const float4*)in)[i];
    unsigned short h0 = f2bf(v.x), h1 = f2bf(v.y), h2 = f2bf(v.z), h3 = f2bf(v.w);
    unsigned short l0 = f2bf(v.x - bf2f(h0)), l1 = f2bf(v.y - bf2f(h1));
    unsigned short l2 = f2bf(v.z - bf2f(h2)), l3 = f2bf(v.w - bf2f(h3));
    uint2 ph = make_uint2((unsigned)h0 | ((unsigned)h1 << 16), (unsigned)h2 | ((unsigned)h3 << 16));
    uint2 pl = make_uint2((unsigned)l0 | ((unsigned)l1 << 16), (unsigned)l2 | ((unsigned)l3 << 16));
    *(uint2*)((char*)hi + (size_t)i*8) = ph;
    *(uint2*)((char*)lo + (size_t)i*8) = pl;
}

// ---------------- merged transpose+split for the 4 projection weights ----------------
__global__ __launch_bounds__(256) void transpose_split_w4(
    const float* __restrict__ Wq, const float* __restrict__ Wk,
    const float* __restrict__ Wv, const float* __restrict__ Wd,
    __hip_bfloat16* __restrict__ wqkv_h, __hip_bfloat16* __restrict__ wqkv_l,
    __hip_bfloat16* __restrict__ wd_h, __hip_bfloat16* __restrict__ wd_l)
{
    __shared__ float t[64][65];
    const int z = blockIdx.z;
    const float* in = (z==0) ? Wq : (z==1) ? Wk : (z==2) ? Wv : Wd;
    __hip_bfloat16* oh = (z<3) ? (wqkv_h + (size_t)z*1024*1024) : wd_h;
    __hip_bfloat16* ol = (z<3) ? (wqkv_l + (size_t)z*1024*1024) : wd_l;
    int k0 = blockIdx.y*64, n0 = blockIdx.x*64;
    int tid = threadIdx.x;
    #pragma unroll
    for (int it=0; it<4; ++it) {
        int lin = it*256 + tid;
        int r = lin >> 4, c4 = (lin & 15) << 2;
        float4 v = *(const float4*)&in[(size_t)(k0+r)*1024 + n0 + c4];
        t[r][c4] = v.x; t[r][c4+1] = v.y; t[r][c4+2] = v.z; t[r][c4+3] = v.w;
    }
    __syncthreads();
    #pragma unroll
    for (int it=0; it<4; ++it) {
        int lin = it*256 + tid;
        int r = lin >> 4, c4 = (lin & 15) << 2;
        float v0 = t[c4][r], v1 = t[c4+1][r], v2 = t[c4+2][r], v3 = t[c4+3][r];
        ushort4 hh, ll;
        hh.x = f2bf(v0); hh.y = f2bf(v1); hh.z = f2bf(v2); hh.w = f2bf(v3);
        ll.x = f2bf(v0 - bf2f(hh.x)); ll.y = f2bf(v1 - bf2f(hh.y));
        ll.z = f2bf(v2 - bf2f(hh.z)); ll.w = f2bf(v3 - bf2f(hh.w));
        size_t o = (size_t)(n0+r)*1024 + k0 + c4;
        *(ushort4*)&oh[o] = hh;
        *(ushort4*)&ol[o] = ll;
    }
}

// ---------------- transpose + f32->bf16: in [K][N] -> out [N][K] (vectorized) ----------------
__global__ __launch_bounds__(256) void transpose_bf16(
    const float* __restrict__ in, __hip_bfloat16* __restrict__ outp, int K, int N)
{
    __shared__ float t[64][65];
    size_t eoff = (size_t)blockIdx.z * (size_t)K * (size_t)N;
    int k0 = blockIdx.y*64, n0 = blockIdx.x*64;
    int tid = threadIdx.x;
    #pragma unroll
    for (int it=0; it<4; ++it) {
        int lin = it*256 + tid;
        int r = lin >> 4, c4 = (lin & 15) << 2;
        float4 v = *(const float4*)&in[eoff + (size_t)(k0+r)*N + n0 + c4];
        t[r][c4] = v.x; t[r][c4+1] = v.y; t[r][c4+2] = v.z; t[r][c4+3] = v.w;
    }
    __syncthreads();
    #pragma unroll
    for (int it=0; it<4; ++it) {
        int lin = it*256 + tid;
        int r = lin >> 4, c4 = (lin & 15) << 2;
        ushort4 o;
        o.x = f2bf(t[c4][r]);   o.y = f2bf(t[c4+1][r]);
        o.z = f2bf(t[c4+2][r]); o.w = f2bf(t[c4+3][r]);
        *(ushort4*)&outp[eoff + (size_t)(n0+r)*K + k0 + c4] = o;
    }
}

// ---------------- bf16x3 GEMM: C = A@B (+bias), fp32-accurate, XCD-swizzled 1D grid ----------------
template<bool BIAS>
__global__ __launch_bounds__(256, 2) void gemm_bf16x3(
    const __hip_bfloat16* __restrict__ Ah, const __hip_bfloat16* __restrict__ Al,
    const __hip_bfloat16* __restrict__ Bh, const __hip_bfloat16* __restrict__ Bl,
    float* __restrict__ C, const float* __restrict__ bias, int N, int K, int nbx)
{
    const int tid = threadIdx.x;
    const int w = tid >> 6, lane = tid & 63;
    const int wg = blockIdx.x;
    const int xcd = wg & 7, ix = wg >> 3;
    const int byc = (int)(gridDim.x >> 3) / nbx;
    const int by = xcd*byc + ix / nbx;
    const int bx = ix % nbx;

    __shared__ __align__(16) char smem[65536];
    const int AH = 0, AL = 16384, BH = 32768, BL = 49152;

    const int laneg = lane >> 3;
    const int k2sw = ((lane & 7) ^ laneg) << 4;
    const int l15 = lane & 15, l4 = lane >> 4;
    const int wr = w >> 1, wc = w & 1;

    f32x4 acc[4][4];
    #pragma unroll
    for (int m=0;m<4;m++)
        #pragma unroll
        for (int n=0;n<4;n++) acc[m][n] = (f32x4){0.f,0.f,0.f,0.f};

    for (int k0 = 0; k0 < K; k0 += 64) {
        __syncthreads();
        #pragma unroll
        for (int qq=0;qq<4;qq++) {
            int arow = by*128 + (w*4+qq)*8 + laneg;
            int brow = bx*128 + (w*4+qq)*8 + laneg;
            size_t aoff = ((size_t)arow*K + k0)*2 + k2sw;
            size_t boff = ((size_t)brow*K + k0)*2 + k2sw;
            GLOAD16((const char*)Ah + aoff, smem + AH + (w*4+qq)*1024);
            GLOAD16((const char*)Al + aoff, smem + AL + (w*4+qq)*1024);
            GLOAD16((const char*)Bh + boff, smem + BH + (w*4+qq)*1024);
            GLOAD16((const char*)Bl + boff, smem + BL + (w*4+qq)*1024);
        }
        __syncthreads();

        short8v ahf[4][2], alf[4][2], bhf[4][2], blf[4][2];
        #pragma unroll
        for (int m=0;m<4;m++) {
            int row = wr*64 + m*16 + l15;
            int rb = row << 7, rsw = (row & 7) << 4;
            #pragma unroll
            for (int s=0;s<2;s++) {
                int off = rb + ((s*64 + (l4<<4)) ^ rsw);
                ahf[m][s] = *(const short8v*)(smem + AH + off);
                alf[m][s] = *(const short8v*)(smem + AL + off);
            }
        }
        #pragma unroll
        for (int n=0;n<4;n++) {
            int row = wc*64 + n*16 + l15;
            int rb = row << 7, rsw = (row & 7) << 4;
            #pragma unroll
            for (int s=0;s<2;s++) {
                int off = rb + ((s*64 + (l4<<4)) ^ rsw);
                bhf[n][s] = *(const short8v*)(smem + BH + off);
                blf[n][s] = *(const short8v*)(smem + BL + off);
            }
        }
        #pragma unroll
        for (int m=0;m<4;m++)
            #pragma unroll
            for (int n=0;n<4;n++)
                #pragma unroll
                for (int s=0;s<2;s++) {
                    acc[m][n] = __builtin_amdgcn_mfma_f32_16x16x32_bf16(ahf[m][s], bhf[n][s], acc[m][n], 0, 0, 0);
                    acc[m][n] = __builtin_amdgcn_mfma_f32_16x16x32_bf16(ahf[m][s], blf[n][s], acc[m][n], 0, 0, 0);
                    acc[m][n] = __builtin_amdgcn_mfma_f32_16x16x32_bf16(alf[m][s], bhf[n][s], acc[m][n], 0, 0, 0);
                }
    }

    #pragma unroll
    for (int m=0;m<4;m++)
        #pragma unroll
        for (int j=0;j<4;j++) {
            int orow = by*128 + wr*64 + m*16 + l4*4 + j;
            #pragma unroll
            for (int n=0;n<4;n++) {
                int ocol = bx*128 + wc*64 + n*16 + l15;
                float v = acc[m][n][j];
                if (BIAS) v += bias[ocol];
                C[(size_t)orow*N + ocol] = v;
            }
        }
}

// ---------------- MFMA MoE GEMM ----------------
// MODE 2: y1 = gelu(gather(hs_b) @ W1t^T) -> bf16 (LDS-coalesced store)
// MODE 3: moe_out[tok] += w * (y1 @ W2t^T) -> f32 atomic
// FULL (!PE): 1D grid, XCD-swizzled, bx-MAJOR within XCD (L2-resident W-slice + A-tiles).
template<int MODE, bool PE>
__global__ __launch_bounds__(256) void moe_mfma(
    const __hip_bfloat16* __restrict__ A,
    const __hip_bfloat16* __restrict__ Bt,
    __hip_bfloat16* __restrict__ y1,
    float* __restrict__ moe_out,
    const int* __restrict__ slot_token,
    const float* __restrict__ slot_w,
    const int* __restrict__ tile_expert,
    const int* __restrict__ cnt_ptr,
    const int* __restrict__ base_ptr,
    int N, int K, int nbx)
{
    const int tid = threadIdx.x;
    const int w = tid >> 6, lane = tid & 63;

    int bx, slot0, y1row0;
    const __hip_bfloat16* Bp;
    if (PE) {
        bx = blockIdx.x;
        int tloc = blockIdx.y;
        if ((tloc << 7) >= *cnt_ptr) return;
        slot0 = *base_ptr + (tloc << 7);
        y1row0 = tloc << 7;
        Bp = Bt;
    } else {
        const int wg = blockIdx.x;
        const int xcd = wg & 7, ix = wg >> 3;
        const int byc = (int)(gridDim.x >> 3) / nbx;
        int gt = xcd*byc + ix % byc;                   // bx-major: tile varies fastest
        bx = ix / byc;
        if (gt >= *cnt_ptr) return;
        int e = tile_expert[gt];
        Bp = Bt + (size_t)e * (size_t)K * (size_t)N;
        slot0 = gt << 7;
        y1row0 = gt << 7;
    }

    __shared__ __align__(16) char smem[32768];

    const int laneg = lane >> 3;
    const int k2sw = ((lane & 7) ^ laneg) << 4;

    int tokq[4];
    if (MODE == 2) {
        #pragma unroll
        for (int qq=0;qq<4;qq++) {
            int t0 = slot_token[slot0 + (w*4+qq)*8 + laneg];
            tokq[qq] = t0 < 0 ? 0 : t0;
        }
    }

    f32x4 acc[4][4];
    #pragma unroll
    for (int m=0;m<4;m++)
        #pragma unroll
        for (int n=0;n<4;n++) acc[m][n] = (f32x4){0.f,0.f,0.f,0.f};

    const int l15 = lane & 15;
    const int l4  = lane >> 4;
    const int wr = w >> 1, wc = w & 1;

    for (int k0 = 0; k0 < K; k0 += 64) {
        __syncthreads();
        #pragma unroll
        for (int qq=0;qq<4;qq++) {
            const char* ga;
            if (MODE == 2) {
                ga = (const char*)A + (((size_t)tokq[qq])*K + k0)*2 + k2sw;
            } else {
                int row = y1row0 + (w*4+qq)*8 + laneg;
                ga = (const char*)A + ((size_t)row*K + k0)*2 + k2sw;
            }
            GLOAD16(ga, smem + (w*4+qq)*1024);
        }
        #pragma unroll
        for (int qq=0;qq<4;qq++) {
            int row = bx*128 + (w*4+qq)*8 + laneg;
            const char* gb = (const char*)Bp + ((size_t)row*K + k0)*2 + k2sw;
            GLOAD16(gb, smem + 16384 + (w*4+qq)*1024);
        }
        __syncthreads();

        short8v a_frag[4][2], b_frag[4][2];
        #pragma unroll
        for (int m=0;m<4;m++) {
            int row = wr*64 + m*16 + l15;
            int rb = row << 7;
            #pragma unroll
            for (int s=0;s<2;s++) {
                int off = rb + ((s*64 + (l4<<4)) ^ ((row&7)<<4));
                a_frag[m][s] = *(const short8v*)(smem + off);
            }
        }
        #pragma unroll
        for (int n=0;n<4;n++) {
            int row = wc*64 + n*16 + l15;
            int rb = row << 7;
            #pragma unroll
            for (int s=0;s<2;s++) {
                int off = rb + ((s*64 + (l4<<4)) ^ ((row&7)<<4));
                b_frag[n][s] = *(const short8v*)(smem + 16384 + off);
            }
        }
        #pragma unroll
        for (int m=0;m<4;m++)
            #pragma unroll
            for (int n=0;n<4;n++) {
                acc[m][n] = __builtin_amdgcn_mfma_f32_16x16x32_bf16(a_frag[m][0], b_frag[n][0], acc[m][n], 0, 0, 0);
                acc[m][n] = __builtin_amdgcn_mfma_f32_16x16x32_bf16(a_frag[m][1], b_frag[n][1], acc[m][n], 0, 0, 0);
            }
    }

    if (MODE == 3) {
        #pragma unroll
        for (int m=0;m<4;m++) {
            #pragma unroll
            for (int j=0;j<4;j++) {
                int orow = wr*64 + m*16 + l4*4 + j;
                int slot = slot0 + orow;
                int tok = slot_token[slot];
                if (tok < 0) continue;
                float sw = slot_w[slot];
                #pragma unroll
                for (int n=0;n<4;n++) {
                    int ocol = bx*128 + wc*64 + n*16 + l15;
                    atomicAdd(&moe_out[(size_t)tok*H_ + ocol], sw * acc[m][n][j]);
                }
            }
        }
    } else {
        // gelu -> LDS [128 rows][128 bf16 cols, 256B pitch] -> coalesced b128 stores
        __syncthreads();   // all waves done reading smem from the main loop
        #pragma unroll
        for (int m=0;m<4;m++)
            #pragma unroll
            for (int j=0;j<4;j++) {
                int orow = wr*64 + m*16 + l4*4 + j;
                #pragma unroll
                for (int n=0;n<4;n++) {
                    int ocol = wc*64 + n*16 + l15;
                    unsigned short g = f2bf(gelu_fast(acc[m][n][j]));
                    *(unsigned short*)(smem + orow*256 + ocol*2) = g;
                }
            }
        __syncthreads();
        #pragma unroll
        for (int s=0;s<8;s++) {
            int row = w*32 + s*4 + l4;
            short8v v = *(const short8v*)(smem + row*256 + l15*16);
            *(short8v*)((char*)y1 + ((size_t)(y1row0 + row)*N + bx*128 + l15*8)*2) = v;
        }
    }
}

// ---------------- RoPE + split: fp32 qkv[t][3072] -> rotated bf16 hi/lo, head-major ----------------
__global__ void rope_split_kernel(
    const float* __restrict__ qkv,
    __hip_bfloat16* __restrict__ qh, __hip_bfloat16* __restrict__ ql,
    __hip_bfloat16* __restrict__ kh, __hip_bfloat16* __restrict__ kl)
{
    int idx = blockIdx.x * blockDim.x + threadIdx.x;  // T*NH*32
    int i = idx & 31;
    int n = (idx >> 5) & (NH_-1);
    int t = idx >> 9;
    int b = t >> 11;
    int pos = t & (S_ - 1);
    float inv = exp2f((float)i * (-13.287712379549449f / 32.f));
    float ang = (float)pos * inv;
    float c = cosf(ang), s = sinf(ang);
    size_t base = (size_t)t*3072 + (size_t)n*64;
    size_t obase = ((size_t)(b*NH_ + n)*S_ + pos)*64;

    float q1 = qkv[base+i], q2 = qkv[base+i+32];
    float qo1 = (q1*c - q2*s)*0.125f;
    float qo2 = (q2*c + q1*s)*0.125f;
    unsigned short h1 = f2bf(qo1), h2 = f2bf(qo2);
    qh[obase+i]    = *(__hip_bfloat16*)&h1;
    qh[obase+i+32] = *(__hip_bfloat16*)&h2;
    unsigned short lo1 = f2bf(qo1 - bf2f(h1)), lo2 = f2bf(qo2 - bf2f(h2));
    ql[obase+i]    = *(__hip_bfloat16*)&lo1;
    ql[obase+i+32] = *(__hip_bfloat16*)&lo2;

    float k1 = qkv[base+1024+i], k2 = qkv[base+1024+i+32];
    float ko1 = k1*c - k2*s;
    float ko2 = k2*c + k1*s;
    unsigned short kh1 = f2bf(ko1), kh2 = f2bf(ko2);
    kh[obase+i]    = *(__hip_bfloat16*)&kh1;
    kh[obase+i+32] = *(__hip_bfloat16*)&kh2;
    unsigned short kl1 = f2bf(ko1 - bf2f(kh1)), kl2 = f2bf(ko2 - bf2f(kh2));
    kl[obase+i]    = *(__hip_bfloat16*)&kl1;
    kl[obase+i+32] = *(__hip_bfloat16*)&kl2;
}

// ---------------- V transpose + split ----------------
__global__ __launch_bounds__(256) void vsplit_t_kernel(
    const float* __restrict__ qkv,
    __hip_bfloat16* __restrict__ vth, __hip_bfloat16* __restrict__ vtl)
{
    __shared__ float t[64][65];
    const int s0 = blockIdx.x*64;
    const int hn = blockIdx.y;
    const int b  = blockIdx.z;
    const int tid = threadIdx.x;
    #pragma unroll
    for (int it=0; it<4; ++it) {
        int lin = it*256 + tid;
        int r = lin >> 4, c4 = (lin & 15) << 2;
        float4 vv = *(const float4*)&qkv[(size_t)(b*S_ + s0 + r)*3072 + 2048 + hn*64 + c4];
        t[r][c4] = vv.x; t[r][c4+1] = vv.y; t[r][c4+2] = vv.z; t[r][c4+3] = vv.w;
    }
    __syncthreads();
    size_t obase = (size_t)(b*NH_ + hn)*64*S_;
    #pragma unroll
    for (int it=0; it<4; ++it) {
        int lin = it*256 + tid;
        int d = lin >> 4, c4 = (lin & 15) << 2;
        float v0 = t[c4][d], v1 = t[c4+1][d], v2 = t[c4+2][d], v3 = t[c4+3][d];
        ushort4 hh, ll;
        hh.x = f2bf(v0); hh.y = f2bf(v1); hh.z = f2bf(v2); hh.w = f2bf(v3);
        ll.x = f2bf(v0 - bf2f(hh.x)); ll.y = f2bf(v1 - bf2f(hh.y));
        ll.z = f2bf(v2 - bf2f(hh.z)); ll.w = f2bf(v3 - bf2f(hh.w));
        size_t o = obase + (size_t)d*S_ + s0 + c4;
        *(ushort4*)&vth[o] = hh;
        *(ushort4*)&vtl[o] = ll;
    }
}

// ---------------- MFMA attention: bf16x3, XCD-swizzled, no-max softmax,
// 32KB LDS (P overlays K; extra barrier separates K-reads from P-writes) ----------------
__global__ __launch_bounds__(256) void attn_mfma(
    const __hip_bfloat16* __restrict__ qh, const __hip_bfloat16* __restrict__ ql,
    const __hip_bfloat16* __restrict__ kh, const __hip_bfloat16* __restrict__ kl,
    const __hip_bfloat16* __restrict__ vth, const __hip_bfloat16* __restrict__ vtl,
    __hip_bfloat16* __restrict__ ctx_hi, __hip_bfloat16* __restrict__ ctx_lo)
{
    const int wg = blockIdx.x;
    const int xcd = wg & 7;
    const int ix = wg >> 3;
    const int head = xcd*4 + (ix >> 5);
    const int qt = ix & 31;
    const int b = head >> 4, hn = head & 15;

    const int tid = threadIdx.x;
    const int w = tid >> 6, lane = tid & 63;
    const int l15 = lane & 15, l4 = lane >> 4;
    const int laneg = lane >> 3;
    const int k2sw = ((lane & 7) ^ laneg) << 4;

    // K hi@0 / K lo@8192 (P overlays after QK^T), V hi@16384 / V lo@24576
    __shared__ __align__(16) char smem[32768];
    const int KHo = 0, KLo = 8192, VHo = 16384, VLo = 24576;
    const int PHo = 0, PLo = 8192;

    const size_t kbase = (size_t)head*S_*64;
    const size_t vbase = (size_t)head*64*S_;

    // ---- prologue: stage Q tile into K region, read Q frags ----
    #pragma unroll
    for (int qq=0;qq<2;qq++) {
        int c = w*2 + qq;
        int row = qt*64 + c*8 + laneg;
        size_t off = (kbase + (size_t)row*64)*2 + k2sw;
        GLOAD16((const char*)qh + off, smem + KHo + c*1024);
        GLOAD16((const char*)ql + off, smem + KLo + c*1024);
    }
    __syncthreads();
    short8v qhf[2], qlf[2];
    {
        int row = w*16 + l15;
        int rsw = (row & 7) << 4;
        #pragma unroll
        for (int s=0;s<2;s++) {
            int off = row*128 + ((s*64 + l4*16) ^ rsw);
            qhf[s] = *(const short8v*)(smem + KHo + off);
            qlf[s] = *(const short8v*)(smem + KLo + off);
        }
    }

    f32x4 acc[4];
    #pragma unroll
    for (int db=0;db<4;db++) acc[db] = (f32x4){0.f,0.f,0.f,0.f};
    float lrun[4] = {0.f, 0.f, 0.f, 0.f};

    for (int kt=0; kt<S_/64; ++kt) {
        __syncthreads();   // prior tile's P/V reads (and Q-frag reads at kt=0) done
        #pragma unroll
        for (int qq=0;qq<2;qq++) {
            int c = w*2 + qq;
            int r8 = c*8 + laneg;
            size_t koff = (kbase + (size_t)(kt*64 + r8)*64)*2 + k2sw;
            GLOAD16((const char*)kh + koff, smem + KHo + c*1024);
            GLOAD16((const char*)kl + koff, smem + KLo + c*1024);
            size_t voff = (vbase + (size_t)r8*S_ + kt*64)*2 + k2sw;
            GLOAD16((const char*)vth + voff, smem + VHo + c*1024);
            GLOAD16((const char*)vtl + voff, smem + VLo + c*1024);
        }
        __syncthreads();   // staged tile visible

        // ---- QK^T (3-term split) ----
        f32x4 s_acc[4];
        #pragma unroll
        for (int cb=0;cb<4;cb++) {
            s_acc[cb] = (f32x4){0.f,0.f,0.f,0.f};
            int row = cb*16 + l15;
            int rsw = (row & 7) << 4;
            #pragma unroll
            for (int s=0;s<2;s++) {
                int off = row*128 + ((s*64 + l4*16) ^ rsw);
                short8v khf = *(const short8v*)(smem + KHo + off);
                short8v klf = *(const short8v*)(smem + KLo + off);
                s_acc[cb] = __builtin_amdgcn_mfma_f32_16x16x32_bf16(qhf[s], khf, s_acc[cb], 0, 0, 0);
                s_acc[cb] = __builtin_amdgcn_mfma_f32_16x16x32_bf16(qhf[s], klf, s_acc[cb], 0, 0, 0);
                s_acc[cb] = __builtin_amdgcn_mfma_f32_16x16x32_bf16(qlf[s], khf, s_acc[cb], 0, 0, 0);
            }
        }
        __syncthreads();   // ALL waves done reading K; P may overwrite it

        // ---- P = exp(s), split -> wave-private rows in K region ----
        #pragma unroll
        for (int cb=0;cb<4;cb++)
            #pragma unroll
            for (int j=0;j<4;j++) {
                float p = __expf(s_acc[cb][j]);
                lrun[j] += p;
                int prow = w*16 + l4*4 + j;
                unsigned short hh = f2bf(p);
                unsigned short ll = f2bf(p - bf2f(hh));
                int off = prow*128 + (((cb*16 + l15)*2) ^ ((prow&7)<<4));
                *(unsigned short*)(smem + PHo + off) = hh;
                *(unsigned short*)(smem + PLo + off) = ll;
            }
        asm volatile("s_waitcnt lgkmcnt(0)" ::: "memory");
        __builtin_amdgcn_sched_barrier(0);

        // ---- PV (3-term split) ----
        short8v pah[2], pal[2];
        {
            int row = w*16 + l15;
            int rsw = (row & 7) << 4;
            #pragma unroll
            for (int s=0;s<2;s++) {
                int off = row*128 + ((s*64 + l4*16) ^ rsw);
                pah[s] = *(const short8v*)(smem + PHo + off);
                pal[s] = *(const short8v*)(smem + PLo + off);
            }
        }
        #pragma unroll
        for (int db=0;db<4;db++) {
            int row = db*16 + l15;
            int rsw = (row & 7) << 4;
            #pragma unroll
            for (int s=0;s<2;s++) {
                int off = row*128 + ((s*64 + l4*16) ^ rsw);
                short8v vhf = *(const short8v*)(smem + VHo + off);
                short8v vlf = *(const short8v*)(smem + VLo + off);
                acc[db] = __builtin_amdgcn_mfma_f32_16x16x32_bf16(pah[s], vhf, acc[db], 0, 0, 0);
                acc[db] = __builtin_amdgcn_mfma_f32_16x16x32_bf16(pah[s], vlf, acc[db], 0, 0, 0);
                acc[db] = __builtin_amdgcn_mfma_f32_16x16x32_bf16(pal[s], vhf, acc[db], 0, 0, 0);
            }
        }
    }

    // ---- deferred row-sum reduce ----
    #pragma unroll
    for (int j=0;j<4;j++) {
        float s = lrun[j];
        #pragma unroll
        for (int m=8;m;m>>=1) s += __shfl_xor(s, m);
        lrun[j] = s;
    }

    // ---- epilogue: write ctx as hi/lo split directly ----
    #pragma unroll
    for (int db=0;db<4;db++)
        #pragma unroll
        for (int j=0;j<4;j++) {
            int qrow = qt*64 + w*16 + l4*4 + j;
            float o = acc[db][j] / lrun[j];
            unsigned short hh = f2bf(o);
            unsigned short ll = f2bf(o - bf2f(hh));
            size_t oidx = (size_t)(b*S_ + qrow)*H_ + hn*64 + db*16 + l15;
            ctx_hi[oidx] = *(__hip_bfloat16*)&hh;
            ctx_lo[oidx] = *(__hip_bfloat16*)&ll;
        }
}

// ---------------- layernorm (residual fused, optional bf16 out) ----------------
__global__ __launch_bounds__(256) void ln_kernel(
    const float* __restrict__ a, const float* __restrict__ res,
    const float* __restrict__ g, const float* __restrict__ beta,
    float* __restrict__ out, __hip_bfloat16* __restrict__ outb)
{
    int row = blockIdx.x, tid = threadIdx.x;
    const float4 va = ((const float4*)(a + (size_t)row*H_))[tid];
    const float4 vr = ((const float4*)(res + (size_t)row*H_))[tid];
    float x0=va.x+vr.x, x1=va.y+vr.y, x2=va.z+vr.z, x3=va.w+vr.w;
    float s  = x0+x1+x2+x3;
    float ss = x0*x0 + x1*x1 + x2*x2 + x3*x3;
    #pragma unroll
    for (int off=32; off; off>>=1) { s += __shfl_xor(s, off); ss += __shfl_xor(ss, off); }
    __shared__ float red[8];
    if ((tid&63)==0) { red[tid>>6]=s; red[4+(tid>>6)]=ss; }
    __syncthreads();
    if (tid==0) { red[0]=red[0]+red[1]+red[2]+red[3]; red[4]=red[4]+red[5]+red[6]+red[7]; }
    __syncthreads();
    float mu  = red[0] * (1.f/H_);
    float var = red[4] * (1.f/H_) - mu*mu;
    float rs = rsqrtf(fmaxf(var, 0.f) + 1e-12f);
    const float4 vg = ((const float4*)g)[tid];
    const float4 vb = ((const float4*)beta)[tid];
    float4 vo;
    vo.x = (x0-mu)*rs*vg.x + vb.x;
    vo.y = (x1-mu)*rs*vg.y + vb.y;
    vo.z = (x2-mu)*rs*vg.z + vb.z;
    vo.w = (x3-mu)*rs*vg.w + vb.w;
    ((float4*)(out + (size_t)row*H_))[tid] = vo;
    if (outb) {
        unsigned int p0 = (unsigned)f2bf(vo.x) | ((unsigned)f2bf(vo.y) << 16);
        unsigned int p1 = (unsigned)f2bf(vo.z) | ((unsigned)f2bf(vo.w) << 16);
        ((uint2*)(outb + (size_t)row*H_))[tid] = make_uint2(p0, p1);
    }
}

// ---------------- router: 64 blocks x 64 tokens, register-accumulated stats ----------------
__global__ __launch_bounds__(256) void router_kernel(
    const float* __restrict__ hs, const float* __restrict__ Wg,
    int* __restrict__ tok_e, float* __restrict__ tok_w,
    int* __restrict__ counts, float* __restrict__ P_sum)
{
    const int w = threadIdx.x >> 6, lane = threadIdx.x & 63;
    float psum[E_];
    int cnt[E_];
    #pragma unroll
    for (int e=0;e<E_;e++){ psum[e]=0.f; cnt[e]=0; }

    for (int it=0; it<16; ++it) {
        int t = blockIdx.x*64 + it*4 + w;
        const float* row = hs + (size_t)t * H_;
        float acc[E_];
        #pragma unroll
        for (int e=0;e<E_;e++) acc[e]=0.f;
        for (int i16=0; i16<16; ++i16) {
            int i = i16*64 + lane;
            float xv = row[i];
            const float* wg = Wg + (size_t)i*E_;
            #pragma unroll
            for (int e=0;e<E_;e++) acc[e] = fmaf(xv, wg[e], acc[e]);
        }
        #pragma unroll
        for (int e=0;e<E_;e++) {
            float vv = acc[e];
            #pragma unroll
            for (int off=32; off; off>>=1) vv += __shfl_xor(vv, off);
            acc[e] = vv;
        }
        float mx = acc[0];
        #pragma unroll
        for (int e=1;e<E_;e++) mx = fmaxf(mx, acc[e]);
        float p[E_], se=0.f;
        #pragma unroll
        for (int e=0;e<E_;e++){ p[e] = __expf(acc[e]-mx); se += p[e]; }
        float isv = 1.f/se;
        #pragma unroll
        for (int e=0;e<E_;e++){ p[e]*=isv; psum[e] += p[e]; }
        int e1=0;
        #pragma unroll
        for (int e=1;e<E_;e++) if (p[e] > p[e1]) e1=e;
        int e2 = (e1==0)?1:0;
        #pragma unroll
        for (int e=0;e<E_;e++) if (e!=e1 && p[e] > p[e2]) e2=e;
        #pragma unroll
        for (int e=0;e<E_;e++) cnt[e] += (e==e1?1:0) + (e==e2?1:0);
        if (lane==0) {
            float w1=p[e1], w2=p[e2], si=1.f/(w1+w2);
            tok_e[t*2]=e1; tok_e[t*2+1]=e2;
            tok_w[t*2]=w1*si; tok_w[t*2+1]=w2*si;
        }
    }
    if (lane==0) {
        #pragma unroll
        for (int e=0;e<E_;e++) {
            atomicAdd(&P_sum[e], psum[e]);
            atomicAdd(&counts[e], cnt[e]);
        }
    }
}

__global__ void router_finalize(
    const int* __restrict__ counts, const float* __restrict__ P_sum,
    int* __restrict__ base, int* __restrict__ cursor,
    int* __restrict__ cnt_pad, int* __restrict__ ntiles,
    int* __restrict__ slot_token, int* __restrict__ tile_expert,
    float* __restrict__ aux_out)
{
    __shared__ int sbase[E_+1];
    if (threadIdx.x == 0) {
        int bacc = 0;
        float aux = 0.f;
        for (int e=0;e<E_;e++) {
            sbase[e] = bacc; base[e] = bacc;
            int cp = (counts[e] + 127) & ~127;
            cnt_pad[e] = cp;
            bacc += cp;
            cursor[e] = 0;
            aux += ((float)counts[e]/(float)T_) * (P_sum[e]/(float)T_);
        }
        sbase[E_] = bacc;
        *ntiles = bacc >> 7;
        *aux_out = (float)E_ * aux;
    }
    __syncthreads();
    for (int sIdx = (int)threadIdx.x; sIdx < MAXSLOTS; sIdx += (int)blockDim.x)
        slot_token[sIdx] = -1;
    for (int tt = (int)threadIdx.x; tt < MAXTILES; tt += (int)blockDim.x) {
        int s = tt*128;
        int e = E_-1;
        for (int qe=0; qe<E_; ++qe) if (s < sbase[qe+1]) { e = qe; break; }
        tile_expert[tt] = e;
    }
}

__global__ void scatter_slots(
    const int* __restrict__ tok_e, const float* __restrict__ tok_w,
    const int* __restrict__ base, int* __restrict__ cursor,
    int* __restrict__ slot_token, float* __restrict__ slot_w)
{
    int t = blockIdx.x*blockDim.x + threadIdx.x;
    if (t >= T_) return;
    #pragma unroll
    for (int j=0;j<2;j++) {
        int e = tok_e[t*2+j];
        int pos = atomicAdd(&cursor[e], 1);
        int s = base[e] + pos;
        slot_token[s] = t;
        slot_w[s] = tok_w[t*2+j];
    }
}

extern "C" void kernel_launch(void* const* d_in, const int* in_sizes, int n_in,
                              void* d_out, int out_size, void* d_ws, size_t ws_size,
                              hipStream_t stream)
{
    const float* x    = (const float*)d_in[0];
    const float* Wq   = (const float*)d_in[1];
    const float* Wk   = (const float*)d_in[2];
    const float* Wv   = (const float*)d_in[3];
    const float* Wd   = (const float*)d_in[4];
    const float* bd   = (const float*)d_in[5];
    const float* ln1g = (const float*)d_in[6];
    const float* ln1b = (const float*)d_in[7];
    const float* Wg   = (const float*)d_in[8];
    const float* W1   = (const float*)d_in[9];
    const float* W2   = (const float*)d_in[10];
    const float* ln2g = (const float*)d_in[11];
    const float* ln2b = (const float*)d_in[12];
    float* out = (float*)d_out;

    float* f0 = (float*)d_ws;
    const size_t M1 = 1u << 20;
    float* qkv      = f0;
    float* attn_out = f0 + 12*M1;
    float* hs       = f0;
    float* moe_out  = f0 + 4*M1;
    __hip_bfloat16* hs_b = (__hip_bfloat16*)(f0 + 16*M1);

    float* misc = f0 + 18*M1;
    int*   misc_i = (int*)misc;
    int*   tok_e   = misc_i;
    float* tok_w   = misc + 8192;
    int*   slot_tok= misc_i + 16384;
    float* slot_w  = misc + 25600;
    int*   counts  = misc_i + 34816;
    float* P_sum   = misc + 34824;
    int*   cursor  = misc_i + 34832;
    int*   basep   = misc_i + 34840;
    int*   cnt_pad = misc_i + 34848;
    int*   ntiles  = misc_i + 34856;
    int*   tile_ex = misc_i + 34857;

    float* off_p = f0 + 18*M1 + 65536;
    __hip_bfloat16* xa_hi = (__hip_bfloat16*)(off_p);
    __hip_bfloat16* xa_lo = (__hip_bfloat16*)(off_p + 2*M1);
    __hip_bfloat16* at_qh = (__hip_bfloat16*)(off_p + 4*M1);
    __hip_bfloat16* at_ql = (__hip_bfloat16*)(off_p + 6*M1);
    __hip_bfloat16* at_kh = (__hip_bfloat16*)(off_p + 8*M1);
    __hip_bfloat16* at_kl = (__hip_bfloat16*)(off_p + 10*M1);
    __hip_bfloat16* at_vh = (__hip_bfloat16*)(off_p + 12*M1);
    __hip_bfloat16* at_vl = (__hip_bfloat16*)(off_p + 14*M1);
    __hip_bfloat16* wqkv_h = (__hip_bfloat16*)(off_p + 16*M1);
    __hip_bfloat16* wqkv_l = (__hip_bfloat16*)(off_p + 16*M1 + 3*(M1/2));
    __hip_bfloat16* wd_h = (__hip_bfloat16*)(off_p + 19*M1);
    __hip_bfloat16* wd_l = (__hip_bfloat16*)(off_p + 19*M1 + M1/2);

    float* wreg = off_p + 4*M1;
    const bool FULL = ws_size >= (size_t)300*1024*1024;

    dim3 blk(256);

    split_bf16<<<(T_*H_/4)/256, blk, 0, stream>>>(x, xa_hi, xa_lo, T_*H_/4);
    transpose_split_w4<<<dim3(16,16,4), blk, 0, stream>>>(Wq, Wk, Wv, Wd, wqkv_h, wqkv_l, wd_h, wd_l);

    gemm_bf16x3<false><<<dim3(768), blk, 0, stream>>>(xa_hi, xa_lo, wqkv_h, wqkv_l, qkv, nullptr, 3072, H_, 24);

    rope_split_kernel<<<(T_*NH_*32)/256, blk, 0, stream>>>(qkv, at_qh, at_ql, at_kh, at_kl);
    vsplit_t_kernel<<<dim3(S_/64, NH_, B_), blk, 0, stream>>>(qkv, at_vh, at_vl);

    attn_mfma<<<dim3(B_*NH_*(S_/64)), blk, 0, stream>>>(at_qh, at_ql, at_kh, at_kl, at_vh, at_vl, xa_hi, xa_lo);

    gemm_bf16x3<true><<<dim3(256), blk, 0, stream>>>(xa_hi, xa_lo, wd_h, wd_l, attn_out, bd, H_, H_, 8);

    zero_kernel<<<(T_*H_)/256, blk, 0, stream>>>(moe_out, T_*H_);
    zero_kernel<<<1, blk, 0, stream>>>(misc + 34816, 16);

    ln_kernel<<<T_, blk, 0, stream>>>(attn_out, x, ln1g, ln1b, hs, hs_b);

    router_kernel<<<T_/64, blk, 0, stream>>>(hs, Wg, tok_e, tok_w, counts, P_sum);
    router_finalize<<<1, blk, 0, stream>>>(counts, P_sum, basep, cursor, cnt_pad, ntiles,
                                           slot_tok, tile_ex, out + (size_t)T_*H_);
    scatter_slots<<<T_/256, blk, 0, stream>>>(tok_e, tok_w, basep, cursor, slot_tok, slot_w);

    if (FULL) {
        __hip_bfloat16* W1t = (__hip_bfloat16*)wreg;
        __hip_bfloat16* W2t = (__hip_bfloat16*)(wreg + 16*M1);
        __hip_bfloat16* y1  = (__hip_bfloat16*)(wreg + 32*M1);
        transpose_bf16<<<dim3(I_/64, H_/64, E_), blk, 0, stream>>>(W1, W1t, H_, I_);
        transpose_bf16<<<dim3(H_/64, I_/64, E_), blk, 0, stream>>>(W2, W2t, I_, H_);
        moe_mfma<2,false><<<dim3(MAXTILES*32), blk, 0, stream>>>(
            hs_b, W1t, y1, nullptr, slot_tok, slot_w, tile_ex, ntiles, nullptr, I_, H_, 32);
        moe_mfma<3,false><<<dim3(MAXTILES*8), blk, 0, stream>>>(
            y1, W2t, nullptr, moe_out, slot_tok, slot_w, tile_ex, ntiles, nullptr, H_, I_, 8);
    } else {
        __hip_bfloat16* w1t = (__hip_bfloat16*)wreg;
        __hip_bfloat16* w2t = (__hip_bfloat16*)(wreg + 2*M1);
        __hip_bfloat16* y1  = (__hip_bfloat16*)(wreg + 4*M1);
        for (int e=0; e<E_; ++e) {
            transpose_bf16<<<dim3(I_/64, H_/64, 1), blk, 0, stream>>>(W1 + (size_t)e*H_*I_, w1t, H_, I_);
            moe_mfma<2,true><<<dim3(I_/128, 32), blk, 0, stream>>>(
                hs_b, w1t, y1, nullptr, slot_tok, slot_w, nullptr, cnt_pad+e, basep+e, I_, H_, 0);
            transpose_bf16<<<dim3(H_/64, I_/64, 1), blk, 0, stream>>>(W2 + (size_t)e*I_*H_, w2t, I_, H_);
            moe_mfma<3,true><<<dim3(H_/128, 32), blk, 0, stream>>>(
                y1, w2t, nullptr, moe_out, slot_tok, slot_w, nullptr, cnt_pad+e, basep+e, H_, I_, 0);
        }
    }

    ln_kernel<<<T_, blk, 0, stream>>>(moe_out, hs, ln2g, ln2b, out, nullptr);
}

// Round 16
// 756.498 us; speedup vs baseline: 1.0599x; 1.0081x over previous
//
#include <hip/hip_runtime.h>
#include <hip/hip_bf16.h>
#include <math.h>

#define H_ 1024
#define NH_ 16
#define HD_ 64
#define I_ 4096
#define E_ 8
#define B_ 2
#define S_ 2048
#define T_ 4096

#define MAXSLOTS 9216   // 2*T + 8*128 pad
#define MAXTILES 72     // MAXSLOTS/128

typedef __attribute__((ext_vector_type(8))) short short8v;
typedef __attribute__((ext_vector_type(4))) float f32x4;

#define GLOAD16(g, l) __builtin_amdgcn_global_load_lds((const __attribute__((address_space(1))) void*)(g), (__attribute__((address_space(3))) void*)(l), 16, 0, 0)

static __device__ inline unsigned short f2bf(float x) {
    __hip_bfloat16 h = __float2bfloat16(x);
    unsigned short u;
    __builtin_memcpy(&u, &h, 2);
    return u;
}
static __device__ inline float bf2f(unsigned short u) {
    __hip_bfloat16 h;
    __builtin_memcpy(&h, &u, 2);
    return __bfloat162float(h);
}

// exact-gelu via A&S 7.1.26 erf approximation (max abs err 1.5e-7 << bf16 rounding)
static __device__ inline float gelu_fast(float x) {
    float z  = x * 0.70710678118654752f;
    float az = fabsf(z);
    float t  = __builtin_amdgcn_rcpf(fmaf(0.3275911f, az, 1.f));
    float p  = fmaf(1.061405429f, t, -1.453152027f);
    p = fmaf(p, t, 1.421413741f);
    p = fmaf(p, t, -0.284496736f);
    p = fmaf(p, t, 0.254829592f);
    p = p * t;
    float e = __expf(-az*az);
    float er = 1.f - p*e;
    er = (z < 0.f) ? -er : er;
    return 0.5f * x * (1.f + er);
}

// ---------------- zero (moe_out + misc accumulators) ----------------
__global__ void zero_all(float* __restrict__ p, int n, float* __restrict__ misc16) {
    int i = blockIdx.x * blockDim.x + threadIdx.x;
    if (i < n) p[i] = 0.f;
    if (blockIdx.x == 0 && threadIdx.x < 16) misc16[threadIdx.x] = 0.f;
}

// ---------------- prep: split x (blocks <4096) + transpose+split Wq/Wk/Wv/Wd ----------------
__global__ __launch_bounds__(256) void prep_inputs(
    const float* __restrict__ x,
    const float* __restrict__ Wq, const float* __restrict__ Wk,
    const float* __restrict__ Wv, const float* __restrict__ Wd,
    __hip_bfloat16* __restrict__ xa_hi, __hip_bfloat16* __restrict__ xa_lo,
    __hip_bfloat16* __restrict__ wqkv_h, __hip_bfloat16* __restrict__ wqkv_l,
    __hip_bfloat16* __restrict__ wd_h, __hip_bfloat16* __restrict__ wd_l)
{
    __shared__ float t[64][65];
    const int bid = blockIdx.x;
    const int tid = threadIdx.x;
    if (bid < 4096) {
        int i = bid * 256 + tid;
        float4 v = ((const float4*)x)[i];
        unsigned short h0 = f2bf(v.x), h1 = f2bf(v.y), h2 = f2bf(v.z), h3 = f2bf(v.w);
        unsigned short l0 = f2bf(v.x - bf2f(h0)), l1 = f2bf(v.y - bf2f(h1));
        unsigned short l2 = f2bf(v.z - bf2f(h2)), l3 = f2bf(v.w - bf2f(h3));
        uint2 ph = make_uint2((unsigned)h0 | ((unsigned)h1 << 16), (unsigned)h2 | ((unsigned)h3 << 16));
        uint2 pl = make_uint2((unsigned)l0 | ((unsigned)l1 << 16), (unsigned)l2 | ((unsigned)l3 << 16));
        *(uint2*)((char*)xa_hi + (size_t)i*8) = ph;
        *(uint2*)((char*)xa_lo + (size_t)i*8) = pl;
        return;
    }
    int tt = bid - 4096;                 // 1024 blocks: 16 x 16 x 4
    int bx = tt & 15, by = (tt >> 4) & 15, z = tt >> 8;
    const float* in = (z==0) ? Wq : (z==1) ? Wk : (z==2) ? Wv : Wd;
    __hip_bfloat16* oh = (z<3) ? (wqkv_h + (size_t)z*1024*1024) : wd_h;
    __hip_bfloat16* ol = (z<3) ? (wqkv_l + (size_t)z*1024*1024) : wd_l;
    int k0 = by*64, n0 = bx*64;
    #pragma unroll
    for (int it=0; it<4; ++it) {
        int lin = it*256 + tid;
        int r = lin >> 4, c4 = (lin & 15) << 2;
        float4 v = *(const float4*)&in[(size_t)(k0+r)*1024 + n0 + c4];
        t[r][c4] = v.x; t[r][c4+1] = v.y; t[r][c4+2] = v.z; t[r][c4+3] = v.w;
    }
    __syncthreads();
    #pragma unroll
    for (int it=0; it<4; ++it) {
        int lin = it*256 + tid;
        int r = lin >> 4, c4 = (lin & 15) << 2;
        float v0 = t[c4][r], v1 = t[c4+1][r], v2 = t[c4+2][r], v3 = t[c4+3][r];
        ushort4 hh, ll;
        hh.x = f2bf(v0); hh.y = f2bf(v1); hh.z = f2bf(v2); hh.w = f2bf(v3);
        ll.x = f2bf(v0 - bf2f(hh.x)); ll.y = f2bf(v1 - bf2f(hh.y));
        ll.z = f2bf(v2 - bf2f(hh.z)); ll.w = f2bf(v3 - bf2f(hh.w));
        size_t o = (size_t)(n0+r)*1024 + k0 + c4;
        *(ushort4*)&oh[o] = hh;
        *(ushort4*)&ol[o] = ll;
    }
}

// ---------------- transpose + f32->bf16 (standalone, PE path only) ----------------
__global__ __launch_bounds__(256) void transpose_bf16(
    const float* __restrict__ in, __hip_bfloat16* __restrict__ outp, int K, int N)
{
    __shared__ float t[64][65];
    size_t eoff = (size_t)blockIdx.z * (size_t)K * (size_t)N;
    int k0 = blockIdx.y*64, n0 = blockIdx.x*64;
    int tid = threadIdx.x;
    #pragma unroll
    for (int it=0; it<4; ++it) {
        int lin = it*256 + tid;
        int r = lin >> 4, c4 = (lin & 15) << 2;
        float4 v = *(const float4*)&in[eoff + (size_t)(k0+r)*N + n0 + c4];
        t[r][c4] = v.x; t[r][c4+1] = v.y; t[r][c4+2] = v.z; t[r][c4+3] = v.w;
    }
    __syncthreads();
    #pragma unroll
    for (int it=0; it<4; ++it) {
        int lin = it*256 + tid;
        int r = lin >> 4, c4 = (lin & 15) << 2;
        ushort4 o;
        o.x = f2bf(t[c4][r]);   o.y = f2bf(t[c4+1][r]);
        o.z = f2bf(t[c4+2][r]); o.w = f2bf(t[c4+3][r]);
        *(ushort4*)&outp[eoff + (size_t)(n0+r)*K + k0 + c4] = o;
    }
}

// ---------------- bf16x3 GEMM: C = A@B (+bias), fp32-accurate, XCD-swizzled 1D grid ----------------
template<bool BIAS>
__global__ __launch_bounds__(256, 2) void gemm_bf16x3(
    const __hip_bfloat16* __restrict__ Ah, const __hip_bfloat16* __restrict__ Al,
    const __hip_bfloat16* __restrict__ Bh, const __hip_bfloat16* __restrict__ Bl,
    float* __restrict__ C, const float* __restrict__ bias, int N, int K, int nbx)
{
    const int tid = threadIdx.x;
    const int w = tid >> 6, lane = tid & 63;
    const int wg = blockIdx.x;
    const int xcd = wg & 7, ix = wg >> 3;
    const int byc = (int)(gridDim.x >> 3) / nbx;
    const int by = xcd*byc + ix / nbx;
    const int bx = ix % nbx;

    __shared__ __align__(16) char smem[65536];
    const int AH = 0, AL = 16384, BH = 32768, BL = 49152;

    const int laneg = lane >> 3;
    const int k2sw = ((lane & 7) ^ laneg) << 4;
    const int l15 = lane & 15, l4 = lane >> 4;
    const int wr = w >> 1, wc = w & 1;

    f32x4 acc[4][4];
    #pragma unroll
    for (int m=0;m<4;m++)
        #pragma unroll
        for (int n=0;n<4;n++) acc[m][n] = (f32x4){0.f,0.f,0.f,0.f};

    for (int k0 = 0; k0 < K; k0 += 64) {
        __syncthreads();
        #pragma unroll
        for (int qq=0;qq<4;qq++) {
            int arow = by*128 + (w*4+qq)*8 + laneg;
            int brow = bx*128 + (w*4+qq)*8 + laneg;
            size_t aoff = ((size_t)arow*K + k0)*2 + k2sw;
            size_t boff = ((size_t)brow*K + k0)*2 + k2sw;
            GLOAD16((const char*)Ah + aoff, smem + AH + (w*4+qq)*1024);
            GLOAD16((const char*)Al + aoff, smem + AL + (w*4+qq)*1024);
            GLOAD16((const char*)Bh + boff, smem + BH + (w*4+qq)*1024);
            GLOAD16((const char*)Bl + boff, smem + BL + (w*4+qq)*1024);
        }
        __syncthreads();

        short8v ahf[4][2], alf[4][2], bhf[4][2], blf[4][2];
        #pragma unroll
        for (int m=0;m<4;m++) {
            int row = wr*64 + m*16 + l15;
            int rb = row << 7, rsw = (row & 7) << 4;
            #pragma unroll
            for (int s=0;s<2;s++) {
                int off = rb + ((s*64 + (l4<<4)) ^ rsw);
                ahf[m][s] = *(const short8v*)(smem + AH + off);
                alf[m][s] = *(const short8v*)(smem + AL + off);
            }
        }
        #pragma unroll
        for (int n=0;n<4;n++) {
            int row = wc*64 + n*16 + l15;
            int rb = row << 7, rsw = (row & 7) << 4;
            #pragma unroll
            for (int s=0;s<2;s++) {
                int off = rb + ((s*64 + (l4<<4)) ^ rsw);
                bhf[n][s] = *(const short8v*)(smem + BH + off);
                blf[n][s] = *(const short8v*)(smem + BL + off);
            }
        }
        #pragma unroll
        for (int m=0;m<4;m++)
            #pragma unroll
            for (int n=0;n<4;n++)
                #pragma unroll
                for (int s=0;s<2;s++) {
                    acc[m][n] = __builtin_amdgcn_mfma_f32_16x16x32_bf16(ahf[m][s], bhf[n][s], acc[m][n], 0, 0, 0);
                    acc[m][n] = __builtin_amdgcn_mfma_f32_16x16x32_bf16(ahf[m][s], blf[n][s], acc[m][n], 0, 0, 0);
                    acc[m][n] = __builtin_amdgcn_mfma_f32_16x16x32_bf16(alf[m][s], bhf[n][s], acc[m][n], 0, 0, 0);
                }
    }

    #pragma unroll
    for (int m=0;m<4;m++)
        #pragma unroll
        for (int j=0;j<4;j++) {
            int orow = by*128 + wr*64 + m*16 + l4*4 + j;
            #pragma unroll
            for (int n=0;n<4;n++) {
                int ocol = bx*128 + wc*64 + n*16 + l15;
                float v = acc[m][n][j];
                if (BIAS) v += bias[ocol];
                C[(size_t)orow*N + ocol] = v;
            }
        }
}

// ---------------- FUSED: QKV bf16x3 GEMM (blocks <768) + W1/W2 transpose (rest) ----------------
__global__ __launch_bounds__(256, 2) void fused_qkv_w12(
    const __hip_bfloat16* __restrict__ Ah, const __hip_bfloat16* __restrict__ Al,
    const __hip_bfloat16* __restrict__ Bh, const __hip_bfloat16* __restrict__ Bl,
    float* __restrict__ C,
    const float* __restrict__ W1, const float* __restrict__ W2,
    __hip_bfloat16* __restrict__ W1t, __hip_bfloat16* __restrict__ W2t)
{
    __shared__ __align__(16) char smem[65536];
    const int tid = threadIdx.x;
    const int bid = blockIdx.x;

    if (bid < 768) {
        const int N = 3072, K = 1024;
        const int w = tid >> 6, lane = tid & 63;
        const int xcd = bid & 7, ix = bid >> 3;
        const int by = xcd*4 + ix / 24;
        const int bx = ix % 24;
        const int AH = 0, AL = 16384, BH = 32768, BL = 49152;
        const int laneg = lane >> 3;
        const int k2sw = ((lane & 7) ^ laneg) << 4;
        const int l15 = lane & 15, l4 = lane >> 4;
        const int wr = w >> 1, wc = w & 1;

        f32x4 acc[4][4];
        #pragma unroll
        for (int m=0;m<4;m++)
            #pragma unroll
            for (int n=0;n<4;n++) acc[m][n] = (f32x4){0.f,0.f,0.f,0.f};

        for (int k0 = 0; k0 < K; k0 += 64) {
            __syncthreads();
            #pragma unroll
            for (int qq=0;qq<4;qq++) {
                int arow = by*128 + (w*4+qq)*8 + laneg;
                int brow = bx*128 + (w*4+qq)*8 + laneg;
                size_t aoff = ((size_t)arow*K + k0)*2 + k2sw;
                size_t boff = ((size_t)brow*K + k0)*2 + k2sw;
                GLOAD16((const char*)Ah + aoff, smem + AH + (w*4+qq)*1024);
                GLOAD16((const char*)Al + aoff, smem + AL + (w*4+qq)*1024);
                GLOAD16((const char*)Bh + boff, smem + BH + (w*4+qq)*1024);
                GLOAD16((const char*)Bl + boff, smem + BL + (w*4+qq)*1024);
            }
            __syncthreads();

            short8v ahf[4][2], alf[4][2], bhf[4][2], blf[4][2];
            #pragma unroll
            for (int m=0;m<4;m++) {
                int row = wr*64 + m*16 + l15;
                int rb = row << 7, rsw = (row & 7) << 4;
                #pragma unroll
                for (int s=0;s<2;s++) {
                    int off = rb + ((s*64 + (l4<<4)) ^ rsw);
                    ahf[m][s] = *(const short8v*)(smem + AH + off);
                    alf[m][s] = *(const short8v*)(smem + AL + off);
                }
            }
            #pragma unroll
            for (int n=0;n<4;n++) {
                int row = wc*64 + n*16 + l15;
                int rb = row << 7, rsw = (row & 7) << 4;
                #pragma unroll
                for (int s=0;s<2;s++) {
                    int off = rb + ((s*64 + (l4<<4)) ^ rsw);
                    bhf[n][s] = *(const short8v*)(smem + BH + off);
                    blf[n][s] = *(const short8v*)(smem + BL + off);
                }
            }
            #pragma unroll
            for (int m=0;m<4;m++)
                #pragma unroll
                for (int n=0;n<4;n++)
                    #pragma unroll
                    for (int s=0;s<2;s++) {
                        acc[m][n] = __builtin_amdgcn_mfma_f32_16x16x32_bf16(ahf[m][s], bhf[n][s], acc[m][n], 0, 0, 0);
                        acc[m][n] = __builtin_amdgcn_mfma_f32_16x16x32_bf16(ahf[m][s], blf[n][s], acc[m][n], 0, 0, 0);
                        acc[m][n] = __builtin_amdgcn_mfma_f32_16x16x32_bf16(alf[m][s], bhf[n][s], acc[m][n], 0, 0, 0);
                    }
        }

        #pragma unroll
        for (int m=0;m<4;m++)
            #pragma unroll
            for (int j=0;j<4;j++) {
                int orow = by*128 + wr*64 + m*16 + l4*4 + j;
                #pragma unroll
                for (int n=0;n<4;n++) {
                    int ocol = bx*128 + wc*64 + n*16 + l15;
                    C[(size_t)orow*N + ocol] = acc[m][n][j];
                }
            }
        return;
    }

    // ---- transpose path ----
    int t = bid - 768;
    const float* src;
    __hip_bfloat16* dst;
    int K, N;
    if (t < 8192) { src = W1; dst = W1t; K = 1024; N = 4096; }
    else          { t -= 8192; src = W2; dst = W2t; K = 4096; N = 1024; }
    const int nb_n = N >> 6;
    int bx = t % nb_n;
    int rest = t / nb_n;
    int by = rest % (K >> 6);
    int bz = rest / (K >> 6);
    size_t eoff = (size_t)bz * (size_t)K * (size_t)N;
    int k0 = by*64, n0 = bx*64;
    float (*tt)[65] = (float(*)[65])smem;
    #pragma unroll
    for (int it=0; it<4; ++it) {
        int lin = it*256 + tid;
        int r = lin >> 4, c4 = (lin & 15) << 2;
        float4 v = *(const float4*)&src[eoff + (size_t)(k0+r)*N + n0 + c4];
        tt[r][c4] = v.x; tt[r][c4+1] = v.y; tt[r][c4+2] = v.z; tt[r][c4+3] = v.w;
    }
    __syncthreads();
    #pragma unroll
    for (int it=0; it<4; ++it) {
        int lin = it*256 + tid;
        int r = lin >> 4, c4 = (lin & 15) << 2;
        ushort4 o;
        o.x = f2bf(tt[c4][r]);   o.y = f2bf(tt[c4+1][r]);
        o.z = f2bf(tt[c4+2][r]); o.w = f2bf(tt[c4+3][r]);
        *(ushort4*)&dst[eoff + (size_t)(n0+r)*K + k0 + c4] = o;
    }
}

// ---------------- MFMA MoE GEMM ----------------
template<int MODE, bool PE>
__global__ __launch_bounds__(256) void moe_mfma(
    const __hip_bfloat16* __restrict__ A,
    const __hip_bfloat16* __restrict__ Bt,
    __hip_bfloat16* __restrict__ y1,
    float* __restrict__ moe_out,
    const int* __restrict__ slot_token,
    const float* __restrict__ slot_w,
    const int* __restrict__ tile_expert,
    const int* __restrict__ cnt_ptr,
    const int* __restrict__ base_ptr,
    int N, int K, int nbx)
{
    const int tid = threadIdx.x;
    const int w = tid >> 6, lane = tid & 63;

    int bx, slot0, y1row0;
    const __hip_bfloat16* Bp;
    if (PE) {
        bx = blockIdx.x;
        int tloc = blockIdx.y;
        if ((tloc << 7) >= *cnt_ptr) return;
        slot0 = *base_ptr + (tloc << 7);
        y1row0 = tloc << 7;
        Bp = Bt;
    } else {
        const int wg = blockIdx.x;
        const int xcd = wg & 7, ix = wg >> 3;
        const int byc = (int)(gridDim.x >> 3) / nbx;
        int gt = xcd*byc + ix % byc;                   // bx-major: tile varies fastest
        bx = ix / byc;
        if (gt >= *cnt_ptr) return;
        int e = tile_expert[gt];
        Bp = Bt + (size_t)e * (size_t)K * (size_t)N;
        slot0 = gt << 7;
        y1row0 = gt << 7;
    }

    __shared__ __align__(16) char smem[32768];

    const int laneg = lane >> 3;
    const int k2sw = ((lane & 7) ^ laneg) << 4;

    int tokq[4];
    if (MODE == 2) {
        #pragma unroll
        for (int qq=0;qq<4;qq++) {
            int t0 = slot_token[slot0 + (w*4+qq)*8 + laneg];
            tokq[qq] = t0 < 0 ? 0 : t0;
        }
    }

    f32x4 acc[4][4];
    #pragma unroll
    for (int m=0;m<4;m++)
        #pragma unroll
        for (int n=0;n<4;n++) acc[m][n] = (f32x4){0.f,0.f,0.f,0.f};

    const int l15 = lane & 15;
    const int l4  = lane >> 4;
    const int wr = w >> 1, wc = w & 1;

    for (int k0 = 0; k0 < K; k0 += 64) {
        __syncthreads();
        #pragma unroll
        for (int qq=0;qq<4;qq++) {
            const char* ga;
            if (MODE == 2) {
                ga = (const char*)A + (((size_t)tokq[qq])*K + k0)*2 + k2sw;
            } else {
                int row = y1row0 + (w*4+qq)*8 + laneg;
                ga = (const char*)A + ((size_t)row*K + k0)*2 + k2sw;
            }
            GLOAD16(ga, smem + (w*4+qq)*1024);
        }
        #pragma unroll
        for (int qq=0;qq<4;qq++) {
            int row = bx*128 + (w*4+qq)*8 + laneg;
            const char* gb = (const char*)Bp + ((size_t)row*K + k0)*2 + k2sw;
            GLOAD16(gb, smem + 16384 + (w*4+qq)*1024);
        }
        __syncthreads();

        short8v a_frag[4][2], b_frag[4][2];
        #pragma unroll
        for (int m=0;m<4;m++) {
            int row = wr*64 + m*16 + l15;
            int rb = row << 7;
            #pragma unroll
            for (int s=0;s<2;s++) {
                int off = rb + ((s*64 + (l4<<4)) ^ ((row&7)<<4));
                a_frag[m][s] = *(const short8v*)(smem + off);
            }
        }
        #pragma unroll
        for (int n=0;n<4;n++) {
            int row = wc*64 + n*16 + l15;
            int rb = row << 7;
            #pragma unroll
            for (int s=0;s<2;s++) {
                int off = rb + ((s*64 + (l4<<4)) ^ ((row&7)<<4));
                b_frag[n][s] = *(const short8v*)(smem + 16384 + off);
            }
        }
        #pragma unroll
        for (int m=0;m<4;m++)
            #pragma unroll
            for (int n=0;n<4;n++) {
                acc[m][n] = __builtin_amdgcn_mfma_f32_16x16x32_bf16(a_frag[m][0], b_frag[n][0], acc[m][n], 0, 0, 0);
                acc[m][n] = __builtin_amdgcn_mfma_f32_16x16x32_bf16(a_frag[m][1], b_frag[n][1], acc[m][n], 0, 0, 0);
            }
    }

    if (MODE == 3) {
        #pragma unroll
        for (int m=0;m<4;m++) {
            #pragma unroll
            for (int j=0;j<4;j++) {
                int orow = wr*64 + m*16 + l4*4 + j;
                int slot = slot0 + orow;
                int tok = slot_token[slot];
                if (tok < 0) continue;
                float sw = slot_w[slot];
                #pragma unroll
                for (int n=0;n<4;n++) {
                    int ocol = bx*128 + wc*64 + n*16 + l15;
                    atomicAdd(&moe_out[(size_t)tok*H_ + ocol], sw * acc[m][n][j]);
                }
            }
        }
    } else {
        __syncthreads();
        #pragma unroll
        for (int m=0;m<4;m++)
            #pragma unroll
            for (int j=0;j<4;j++) {
                int orow = wr*64 + m*16 + l4*4 + j;
                #pragma unroll
                for (int n=0;n<4;n++) {
                    int ocol = wc*64 + n*16 + l15;
                    unsigned short g = f2bf(gelu_fast(acc[m][n][j]));
                    *(unsigned short*)(smem + orow*256 + ocol*2) = g;
                }
            }
        __syncthreads();
        #pragma unroll
        for (int s=0;s<8;s++) {
            int row = w*32 + s*4 + l4;
            short8v v = *(const short8v*)(smem + row*256 + l15*16);
            *(short8v*)((char*)y1 + ((size_t)(y1row0 + row)*N + bx*128 + l15*8)*2) = v;
        }
    }
}

// ---------------- FUSED RoPE+split (blocks <8192) + V transpose+split ----------------
__global__ __launch_bounds__(256) void rope_vsplit(
    const float* __restrict__ qkv,
    __hip_bfloat16* __restrict__ qh, __hip_bfloat16* __restrict__ ql,
    __hip_bfloat16* __restrict__ kh, __hip_bfloat16* __restrict__ kl,
    __hip_bfloat16* __restrict__ vth, __hip_bfloat16* __restrict__ vtl)
{
    __shared__ float t[64][65];
    const int bid = blockIdx.x;
    const int tid = threadIdx.x;
    if (bid < 8192) {
        int idx = bid * 256 + tid;
        int i = idx & 31;
        int n = (idx >> 5) & (NH_-1);
        int tk = idx >> 9;
        int b = tk >> 11;
        int pos = tk & (S_ - 1);
        float inv = exp2f((float)i * (-13.287712379549449f / 32.f));
        float ang = (float)pos * inv;
        float c = cosf(ang), s = sinf(ang);
        size_t base = (size_t)tk*3072 + (size_t)n*64;
        size_t obase = ((size_t)(b*NH_ + n)*S_ + pos)*64;

        float q1 = qkv[base+i], q2 = qkv[base+i+32];
        float qo1 = (q1*c - q2*s)*0.125f;
        float qo2 = (q2*c + q1*s)*0.125f;
        unsigned short h1 = f2bf(qo1), h2 = f2bf(qo2);
        qh[obase+i]    = *(__hip_bfloat16*)&h1;
        qh[obase+i+32] = *(__hip_bfloat16*)&h2;
        unsigned short lo1 = f2bf(qo1 - bf2f(h1)), lo2 = f2bf(qo2 - bf2f(h2));
        ql[obase+i]    = *(__hip_bfloat16*)&lo1;
        ql[obase+i+32] = *(__hip_bfloat16*)&lo2;

        float k1 = qkv[base+1024+i], k2 = qkv[base+1024+i+32];
        float ko1 = k1*c - k2*s;
        float ko2 = k2*c + k1*s;
        unsigned short kh1 = f2bf(ko1), kh2 = f2bf(ko2);
        kh[obase+i]    = *(__hip_bfloat16*)&kh1;
        kh[obase+i+32] = *(__hip_bfloat16*)&kh2;
        unsigned short kl1 = f2bf(ko1 - bf2f(kh1)), kl2 = f2bf(ko2 - bf2f(kh2));
        kl[obase+i]    = *(__hip_bfloat16*)&kl1;
        kl[obase+i+32] = *(__hip_bfloat16*)&kl2;
        return;
    }
    int tt = bid - 8192;           // 1024 blocks: 32 x 16 x 2
    const int s0 = (tt & 31)*64;
    const int hn = (tt >> 5) & 15;
    const int b  = tt >> 9;
    #pragma unroll
    for (int it=0; it<4; ++it) {
        int lin = it*256 + tid;
        int r = lin >> 4, c4 = (lin & 15) << 2;
        float4 vv = *(const float4*)&qkv[(size_t)(b*S_ + s0 + r)*3072 + 2048 + hn*64 + c4];
        t[r][c4] = vv.x; t[r][c4+1] = vv.y; t[r][c4+2] = vv.z; t[r][c4+3] = vv.w;
    }
    __syncthreads();
    size_t obase = (size_t)(b*NH_ + hn)*64*S_;
    #pragma unroll
    for (int it=0; it<4; ++it) {
        int lin = it*256 + tid;
        int d = lin >> 4, c4 = (lin & 15) << 2;
        float v0 = t[c4][d], v1 = t[c4+1][d], v2 = t[c4+2][d], v3 = t[c4+3][d];
        ushort4 hh, ll;
        hh.x = f2bf(v0); hh.y = f2bf(v1); hh.z = f2bf(v2); hh.w = f2bf(v3);
        ll.x = f2bf(v0 - bf2f(hh.x)); ll.y = f2bf(v1 - bf2f(hh.y));
        ll.z = f2bf(v2 - bf2f(hh.z)); ll.w = f2bf(v3 - bf2f(hh.w));
        size_t o = obase + (size_t)d*S_ + s0 + c4;
        *(ushort4*)&vth[o] = hh;
        *(ushort4*)&vtl[o] = ll;
    }
}

// ---------------- MFMA attention: bf16x3, XCD-swizzled, no-max softmax, 32KB LDS ----------------
__global__ __launch_bounds__(256) void attn_mfma(
    const __hip_bfloat16* __restrict__ qh, const __hip_bfloat16* __restrict__ ql,
    const __hip_bfloat16* __restrict__ kh, const __hip_bfloat16* __restrict__ kl,
    const __hip_bfloat16* __restrict__ vth, const __hip_bfloat16* __restrict__ vtl,
    __hip_bfloat16* __restrict__ ctx_hi, __hip_bfloat16* __restrict__ ctx_lo)
{
    const int wg = blockIdx.x;
    const int xcd = wg & 7;
    const int ix = wg >> 3;
    const int head = xcd*4 + (ix >> 5);
    const int qt = ix & 31;
    const int b = head >> 4, hn = head & 15;

    const int tid = threadIdx.x;
    const int w = tid >> 6, lane = tid & 63;
    const int l15 = lane & 15, l4 = lane >> 4;
    const int laneg = lane >> 3;
    const int k2sw = ((lane & 7) ^ laneg) << 4;

    __shared__ __align__(16) char smem[32768];
    const int KHo = 0, KLo = 8192, VHo = 16384, VLo = 24576;
    const int PHo = 0, PLo = 8192;

    const size_t kbase = (size_t)head*S_*64;
    const size_t vbase = (size_t)head*64*S_;

    #pragma unroll
    for (int qq=0;qq<2;qq++) {
        int c = w*2 + qq;
        int row = qt*64 + c*8 + laneg;
        size_t off = (kbase + (size_t)row*64)*2 + k2sw;
        GLOAD16((const char*)qh + off, smem + KHo + c*1024);
        GLOAD16((const char*)ql + off, smem + KLo + c*1024);
    }
    __syncthreads();
    short8v qhf[2], qlf[2];
    {
        int row = w*16 + l15;
        int rsw = (row & 7) << 4;
        #pragma unroll
        for (int s=0;s<2;s++) {
            int off = row*128 + ((s*64 + l4*16) ^ rsw);
            qhf[s] = *(const short8v*)(smem + KHo + off);
            qlf[s] = *(const short8v*)(smem + KLo + off);
        }
    }

    f32x4 acc[4];
    #pragma unroll
    for (int db=0;db<4;db++) acc[db] = (f32x4){0.f,0.f,0.f,0.f};
    float lrun[4] = {0.f, 0.f, 0.f, 0.f};

    for (int kt=0; kt<S_/64; ++kt) {
        __syncthreads();
        #pragma unroll
        for (int qq=0;qq<2;qq++) {
            int c = w*2 + qq;
            int r8 = c*8 + laneg;
            size_t koff = (kbase + (size_t)(kt*64 + r8)*64)*2 + k2sw;
            GLOAD16((const char*)kh + koff, smem + KHo + c*1024);
            GLOAD16((const char*)kl + koff, smem + KLo + c*1024);
            size_t voff = (vbase + (size_t)r8*S_ + kt*64)*2 + k2sw;
            GLOAD16((const char*)vth + voff, smem + VHo + c*1024);
            GLOAD16((const char*)vtl + voff, smem + VLo + c*1024);
        }
        __syncthreads();

        f32x4 s_acc[4];
        #pragma unroll
        for (int cb=0;cb<4;cb++) {
            s_acc[cb] = (f32x4){0.f,0.f,0.f,0.f};
            int row = cb*16 + l15;
            int rsw = (row & 7) << 4;
            #pragma unroll
            for (int s=0;s<2;s++) {
                int off = row*128 + ((s*64 + l4*16) ^ rsw);
                short8v khf = *(const short8v*)(smem + KHo + off);
                short8v klf = *(const short8v*)(smem + KLo + off);
                s_acc[cb] = __builtin_amdgcn_mfma_f32_16x16x32_bf16(qhf[s], khf, s_acc[cb], 0, 0, 0);
                s_acc[cb] = __builtin_amdgcn_mfma_f32_16x16x32_bf16(qhf[s], klf, s_acc[cb], 0, 0, 0);
                s_acc[cb] = __builtin_amdgcn_mfma_f32_16x16x32_bf16(qlf[s], khf, s_acc[cb], 0, 0, 0);
            }
        }
        __syncthreads();   // ALL waves done reading K; P may overwrite it

        #pragma unroll
        for (int cb=0;cb<4;cb++)
            #pragma unroll
            for (int j=0;j<4;j++) {
                float p = __expf(s_acc[cb][j]);
                lrun[j] += p;
                int prow = w*16 + l4*4 + j;
                unsigned short hh = f2bf(p);
                unsigned short ll = f2bf(p - bf2f(hh));
                int off = prow*128 + (((cb*16 + l15)*2) ^ ((prow&7)<<4));
                *(unsigned short*)(smem + PHo + off) = hh;
                *(unsigned short*)(smem + PLo + off) = ll;
            }
        asm volatile("s_waitcnt lgkmcnt(0)" ::: "memory");
        __builtin_amdgcn_sched_barrier(0);

        short8v pah[2], pal[2];
        {
            int row = w*16 + l15;
            int rsw = (row & 7) << 4;
            #pragma unroll
            for (int s=0;s<2;s++) {
                int off = row*128 + ((s*64 + l4*16) ^ rsw);
                pah[s] = *(const short8v*)(smem + PHo + off);
                pal[s] = *(const short8v*)(smem + PLo + off);
            }
        }
        #pragma unroll
        for (int db=0;db<4;db++) {
            int row = db*16 + l15;
            int rsw = (row & 7) << 4;
            #pragma unroll
            for (int s=0;s<2;s++) {
                int off = row*128 + ((s*64 + l4*16) ^ rsw);
                short8v vhf = *(const short8v*)(smem + VHo + off);
                short8v vlf = *(const short8v*)(smem + VLo + off);
                acc[db] = __builtin_amdgcn_mfma_f32_16x16x32_bf16(pah[s], vhf, acc[db], 0, 0, 0);
                acc[db] = __builtin_amdgcn_mfma_f32_16x16x32_bf16(pah[s], vlf, acc[db], 0, 0, 0);
                acc[db] = __builtin_amdgcn_mfma_f32_16x16x32_bf16(pal[s], vhf, acc[db], 0, 0, 0);
            }
        }
    }

    #pragma unroll
    for (int j=0;j<4;j++) {
        float s = lrun[j];
        #pragma unroll
        for (int m=8;m;m>>=1) s += __shfl_xor(s, m);
        lrun[j] = s;
    }

    #pragma unroll
    for (int db=0;db<4;db++)
        #pragma unroll
        for (int j=0;j<4;j++) {
            int qrow = qt*64 + w*16 + l4*4 + j;
            float o = acc[db][j] / lrun[j];
            unsigned short hh = f2bf(o);
            unsigned short ll = f2bf(o - bf2f(hh));
            size_t oidx = (size_t)(b*S_ + qrow)*H_ + hn*64 + db*16 + l15;
            ctx_hi[oidx] = *(__hip_bfloat16*)&hh;
            ctx_lo[oidx] = *(__hip_bfloat16*)&ll;
        }
}

// ---------------- layernorm (residual fused, optional bf16 out) ----------------
__global__ __launch_bounds__(256) void ln_kernel(
    const float* __restrict__ a, const float* __restrict__ res,
    const float* __restrict__ g, const float* __restrict__ beta,
    float* __restrict__ out, __hip_bfloat16* __restrict__ outb)
{
    int row = blockIdx.x, tid = threadIdx.x;
    const float4 va = ((const float4*)(a + (size_t)row*H_))[tid];
    const float4 vr = ((const float4*)(res + (size_t)row*H_))[tid];
    float x0=va.x+vr.x, x1=va.y+vr.y, x2=va.z+vr.z, x3=va.w+vr.w;
    float s  = x0+x1+x2+x3;
    float ss = x0*x0 + x1*x1 + x2*x2 + x3*x3;
    #pragma unroll
    for (int off=32; off; off>>=1) { s += __shfl_xor(s, off); ss += __shfl_xor(ss, off); }
    __shared__ float red[8];
    if ((tid&63)==0) { red[tid>>6]=s; red[4+(tid>>6)]=ss; }
    __syncthreads();
    if (tid==0) { red[0]=red[0]+red[1]+red[2]+red[3]; red[4]=red[4]+red[5]+red[6]+red[7]; }
    __syncthreads();
    float mu  = red[0] * (1.f/H_);
    float var = red[4] * (1.f/H_) - mu*mu;
    float rs = rsqrtf(fmaxf(var, 0.f) + 1e-12f);
    const float4 vg = ((const float4*)g)[tid];
    const float4 vb = ((const float4*)beta)[tid];
    float4 vo;
    vo.x = (x0-mu)*rs*vg.x + vb.x;
    vo.y = (x1-mu)*rs*vg.y + vb.y;
    vo.z = (x2-mu)*rs*vg.z + vb.z;
    vo.w = (x3-mu)*rs*vg.w + vb.w;
    ((float4*)(out + (size_t)row*H_))[tid] = vo;
    if (outb) {
        unsigned int p0 = (unsigned)f2bf(vo.x) | ((unsigned)f2bf(vo.y) << 16);
        unsigned int p1 = (unsigned)f2bf(vo.z) | ((unsigned)f2bf(vo.w) << 16);
        ((uint2*)(outb + (size_t)row*H_))[tid] = make_uint2(p0, p1);
    }
}

// ---------------- router: 64 blocks x 64 tokens, register-accumulated stats ----------------
__global__ __launch_bounds__(256) void router_kernel(
    const float* __restrict__ hs, const float* __restrict__ Wg,
    int* __restrict__ tok_e, float* __restrict__ tok_w,
    int* __restrict__ counts, float* __restrict__ P_sum)
{
    const int w = threadIdx.x >> 6, lane = threadIdx.x & 63;
    float psum[E_];
    int cnt[E_];
    #pragma unroll
    for (int e=0;e<E_;e++){ psum[e]=0.f; cnt[e]=0; }

    for (int it=0; it<16; ++it) {
        int t = blockIdx.x*64 + it*4 + w;
        const float* row = hs + (size_t)t * H_;
        float acc[E_];
        #pragma unroll
        for (int e=0;e<E_;e++) acc[e]=0.f;
        for (int i16=0; i16<16; ++i16) {
            int i = i16*64 + lane;
            float xv = row[i];
            const float* wg = Wg + (size_t)i*E_;
            #pragma unroll
            for (int e=0;e<E_;e++) acc[e] = fmaf(xv, wg[e], acc[e]);
        }
        #pragma unroll
        for (int e=0;e<E_;e++) {
            float vv = acc[e];
            #pragma unroll
            for (int off=32; off; off>>=1) vv += __shfl_xor(vv, off);
            acc[e] = vv;
        }
        float mx = acc[0];
        #pragma unroll
        for (int e=1;e<E_;e++) mx = fmaxf(mx, acc[e]);
        float p[E_], se=0.f;
        #pragma unroll
        for (int e=0;e<E_;e++){ p[e] = __expf(acc[e]-mx); se += p[e]; }
        float isv = 1.f/se;
        #pragma unroll
        for (int e=0;e<E_;e++){ p[e]*=isv; psum[e] += p[e]; }
        int e1=0;
        #pragma unroll
        for (int e=1;e<E_;e++) if (p[e] > p[e1]) e1=e;
        int e2 = (e1==0)?1:0;
        #pragma unroll
        for (int e=0;e<E_;e++) if (e!=e1 && p[e] > p[e2]) e2=e;
        #pragma unroll
        for (int e=0;e<E_;e++) cnt[e] += (e==e1?1:0) + (e==e2?1:0);
        if (lane==0) {
            float w1=p[e1], w2=p[e2], si=1.f/(w1+w2);
            tok_e[t*2]=e1; tok_e[t*2+1]=e2;
            tok_w[t*2]=w1*si; tok_w[t*2+1]=w2*si;
        }
    }
    if (lane==0) {
        #pragma unroll
        for (int e=0;e<E_;e++) {
            atomicAdd(&P_sum[e], psum[e]);
            atomicAdd(&counts[e], cnt[e]);
        }
    }
}

__global__ void router_finalize(
    const int* __restrict__ counts, const float* __restrict__ P_sum,
    int* __restrict__ base, int* __restrict__ cursor,
    int* __restrict__ cnt_pad, int* __restrict__ ntiles,
    int* __restrict__ slot_token, int* __restrict__ tile_expert,
    float* __restrict__ aux_out)
{
    __shared__ int sbase[E_+1];
    if (threadIdx.x == 0) {
        int bacc = 0;
        float aux = 0.f;
        for (int e=0;e<E_;e++) {
            sbase[e] = bacc; base[e] = bacc;
            int cp = (counts[e] + 127) & ~127;
            cnt_pad[e] = cp;
            bacc += cp;
            cursor[e] = 0;
            aux += ((float)counts[e]/(float)T_) * (P_sum[e]/(float)T_);
        }
        sbase[E_] = bacc;
        *ntiles = bacc >> 7;
        *aux_out = (float)E_ * aux;
    }
    __syncthreads();
    for (int sIdx = (int)threadIdx.x; sIdx < MAXSLOTS; sIdx += (int)blockDim.x)
        slot_token[sIdx] = -1;
    for (int tt = (int)threadIdx.x; tt < MAXTILES; tt += (int)blockDim.x) {
        int s = tt*128;
        int e = E_-1;
        for (int qe=0; qe<E_; ++qe) if (s < sbase[qe+1]) { e = qe; break; }
        tile_expert[tt] = e;
    }
}

__global__ void scatter_slots(
    const int* __restrict__ tok_e, const float* __restrict__ tok_w,
    const int* __restrict__ base, int* __restrict__ cursor,
    int* __restrict__ slot_token, float* __restrict__ slot_w)
{
    int t = blockIdx.x*blockDim.x + threadIdx.x;
    if (t >= T_) return;
    #pragma unroll
    for (int j=0;j<2;j++) {
        int e = tok_e[t*2+j];
        int pos = atomicAdd(&cursor[e], 1);
        int s = base[e] + pos;
        slot_token[s] = t;
        slot_w[s] = tok_w[t*2+j];
    }
}

extern "C" void kernel_launch(void* const* d_in, const int* in_sizes, int n_in,
                              void* d_out, int out_size, void* d_ws, size_t ws_size,
                              hipStream_t stream)
{
    const float* x    = (const float*)d_in[0];
    const float* Wq   = (const float*)d_in[1];
    const float* Wk   = (const float*)d_in[2];
    const float* Wv   = (const float*)d_in[3];
    const float* Wd   = (const float*)d_in[4];
    const float* bd   = (const float*)d_in[5];
    const float* ln1g = (const float*)d_in[6];
    const float* ln1b = (const float*)d_in[7];
    const float* Wg   = (const float*)d_in[8];
    const float* W1   = (const float*)d_in[9];
    const float* W2   = (const float*)d_in[10];
    const float* ln2g = (const float*)d_in[11];
    const float* ln2b = (const float*)d_in[12];
    float* out = (float*)d_out;

    float* f0 = (float*)d_ws;
    const size_t M1 = 1u << 20;
    float* qkv      = f0;
    float* attn_out = f0 + 12*M1;
    float* hs       = f0;
    float* moe_out  = f0 + 4*M1;
    __hip_bfloat16* hs_b = (__hip_bfloat16*)(f0 + 16*M1);

    float* misc = f0 + 18*M1;
    int*   misc_i = (int*)misc;
    int*   tok_e   = misc_i;
    float* tok_w   = misc + 8192;
    int*   slot_tok= misc_i + 16384;
    float* slot_w  = misc + 25600;
    int*   counts  = misc_i + 34816;
    float* P_sum   = misc + 34824;
    int*   cursor  = misc_i + 34832;
    int*   basep   = misc_i + 34840;
    int*   cnt_pad = misc_i + 34848;
    int*   ntiles  = misc_i + 34856;
    int*   tile_ex = misc_i + 34857;

    float* off_p = f0 + 18*M1 + 65536;
    __hip_bfloat16* xa_hi = (__hip_bfloat16*)(off_p);
    __hip_bfloat16* xa_lo = (__hip_bfloat16*)(off_p + 2*M1);
    __hip_bfloat16* at_qh = (__hip_bfloat16*)(off_p + 4*M1);
    __hip_bfloat16* at_ql = (__hip_bfloat16*)(off_p + 6*M1);
    __hip_bfloat16* at_kh = (__hip_bfloat16*)(off_p + 8*M1);
    __hip_bfloat16* at_kl = (__hip_bfloat16*)(off_p + 10*M1);
    __hip_bfloat16* at_vh = (__hip_bfloat16*)(off_p + 12*M1);
    __hip_bfloat16* at_vl = (__hip_bfloat16*)(off_p + 14*M1);
    __hip_bfloat16* wqkv_h = (__hip_bfloat16*)(off_p + 16*M1);
    __hip_bfloat16* wqkv_l = (__hip_bfloat16*)(off_p + 16*M1 + 3*(M1/2));
    __hip_bfloat16* wd_h = (__hip_bfloat16*)(off_p + 19*M1);
    __hip_bfloat16* wd_l = (__hip_bfloat16*)(off_p + 19*M1 + M1/2);

    const bool FULL = ws_size >= (size_t)300*1024*1024;
    // FULL layout: W1t @ +20M1 (16M1 span), W2t @ +36M1 (16M1 span).
    // y1F overlays off_p+0 .. +18.875M1 (xa + at_* + wqkv region — ALL dead by MoE time).
    // No overlap with W1t/W2t (start at +20M1). Total footprint ~280 MB.
    __hip_bfloat16* W1t = (__hip_bfloat16*)(off_p + 20*M1);
    __hip_bfloat16* W2t = (__hip_bfloat16*)(off_p + 36*M1);
    __hip_bfloat16* y1F = (__hip_bfloat16*)(off_p);
    float* wreg = off_p + 4*M1;   // PE path scratch

    dim3 blk(256);

    prep_inputs<<<dim3(5120), blk, 0, stream>>>(x, Wq, Wk, Wv, Wd, xa_hi, xa_lo, wqkv_h, wqkv_l, wd_h, wd_l);

    if (FULL) {
        fused_qkv_w12<<<dim3(768 + 8192 + 8192), blk, 0, stream>>>(
            xa_hi, xa_lo, wqkv_h, wqkv_l, qkv, W1, W2, W1t, W2t);
    } else {
        gemm_bf16x3<false><<<dim3(768), blk, 0, stream>>>(xa_hi, xa_lo, wqkv_h, wqkv_l, qkv, nullptr, 3072, H_, 24);
    }

    rope_vsplit<<<dim3(8192 + 1024), blk, 0, stream>>>(qkv, at_qh, at_ql, at_kh, at_kl, at_vh, at_vl);

    attn_mfma<<<dim3(B_*NH_*(S_/64)), blk, 0, stream>>>(at_qh, at_ql, at_kh, at_kl, at_vh, at_vl, xa_hi, xa_lo);

    gemm_bf16x3<true><<<dim3(256), blk, 0, stream>>>(xa_hi, xa_lo, wd_h, wd_l, attn_out, bd, H_, H_, 8);

    zero_all<<<dim3((T_*H_)/256), blk, 0, stream>>>(moe_out, T_*H_, misc + 34816);

    ln_kernel<<<T_, blk, 0, stream>>>(attn_out, x, ln1g, ln1b, hs, hs_b);

    router_kernel<<<T_/64, blk, 0, stream>>>(hs, Wg, tok_e, tok_w, counts, P_sum);
    router_finalize<<<1, blk, 0, stream>>>(counts, P_sum, basep, cursor, cnt_pad, ntiles,
                                           slot_tok, tile_ex, out + (size_t)T_*H_);
    scatter_slots<<<T_/256, blk, 0, stream>>>(tok_e, tok_w, basep, cursor, slot_tok, slot_w);

    if (FULL) {
        moe_mfma<2,false><<<dim3(MAXTILES*32), blk, 0, stream>>>(
            hs_b, W1t, y1F, nullptr, slot_tok, slot_w, tile_ex, ntiles, nullptr, I_, H_, 32);
        moe_mfma<3,false><<<dim3(MAXTILES*8), blk, 0, stream>>>(
            y1F, W2t, nullptr, moe_out, slot_tok, slot_w, tile_ex, ntiles, nullptr, H_, I_, 8);
    } else {
        __hip_bfloat16* w1t = (__hip_bfloat16*)wreg;
        __hip_bfloat16* w2t = (__hip_bfloat16*)(wreg + 2*M1);
        __hip_bfloat16* y1  = (__hip_bfloat16*)(wreg + 4*M1);
        for (int e=0; e<E_; ++e) {
            transpose_bf16<<<dim3(I_/64, H_/64, 1), blk, 0, stream>>>(W1 + (size_t)e*H_*I_, w1t, H_, I_);
            moe_mfma<2,true><<<dim3(I_/128, 32), blk, 0, stream>>>(
                hs_b, w1t, y1, nullptr, slot_tok, slot_w, nullptr, cnt_pad+e, basep+e, I_, H_, 0);
            transpose_bf16<<<dim3(H_/64, I_/64, 1), blk, 0, stream>>>(W2 + (size_t)e*I_*H_, w2t, I_, H_);
            moe_mfma<3,true><<<dim3(H_/128, 32), blk, 0, stream>>>(
                y1, w2t, nullptr, moe_out, slot_tok, slot_w, nullptr, cnt_pad+e, basep+e, H_, I_, 0);
        }
    }

    ln_kernel<<<T_, blk, 0, stream>>>(moe_out, hs, ln2g, ln2b, out, nullptr);
}

// Round 17
// 750.850 us; speedup vs baseline: 1.0679x; 1.0075x over previous
//
#include <hip/hip_runtime.h>
#include <hip/hip_bf16.h>
#include <math.h>

#define H_ 1024
#define NH_ 16
#define HD_ 64
#define I_ 4096
#define E_ 8
#define B_ 2
#define S_ 2048
#define T_ 4096

#define MAXSLOTS 9216   // 2*T + 8*128 pad
#define MAXTILES 72     // MAXSLOTS/128

typedef __attribute__((ext_vector_type(8))) short short8v;
typedef __attribute__((ext_vector_type(4))) float f32x4;

#define GLOAD16(g, l) __builtin_amdgcn_global_load_lds((const __attribute__((address_space(1))) void*)(g), (__attribute__((address_space(3))) void*)(l), 16, 0, 0)

static __device__ inline unsigned short f2bf(float x) {
    __hip_bfloat16 h = __float2bfloat16(x);
    unsigned short u;
    __builtin_memcpy(&u, &h, 2);
    return u;
}
static __device__ inline float bf2f(unsigned short u) {
    __hip_bfloat16 h;
    __builtin_memcpy(&h, &u, 2);
    return __bfloat162float(h);
}

// exact-gelu via A&S 7.1.26 erf approximation (max abs err 1.5e-7 << bf16 rounding)
static __device__ inline float gelu_fast(float x) {
    float z  = x * 0.70710678118654752f;
    float az = fabsf(z);
    float t  = __builtin_amdgcn_rcpf(fmaf(0.3275911f, az, 1.f));
    float p  = fmaf(1.061405429f, t, -1.453152027f);
    p = fmaf(p, t, 1.421413741f);
    p = fmaf(p, t, -0.284496736f);
    p = fmaf(p, t, 0.254829592f);
    p = p * t;
    float e = __expf(-az*az);
    float er = 1.f - p*e;
    er = (z < 0.f) ? -er : er;
    return 0.5f * x * (1.f + er);
}

// ---------------- prep: split x (blocks <4096) + transpose+split Wq/Wk/Wv/Wd ----------------
__global__ __launch_bounds__(256) void prep_inputs(
    const float* __restrict__ x,
    const float* __restrict__ Wq, const float* __restrict__ Wk,
    const float* __restrict__ Wv, const float* __restrict__ Wd,
    __hip_bfloat16* __restrict__ xa_hi, __hip_bfloat16* __restrict__ xa_lo,
    __hip_bfloat16* __restrict__ wqkv_h, __hip_bfloat16* __restrict__ wqkv_l,
    __hip_bfloat16* __restrict__ wd_h, __hip_bfloat16* __restrict__ wd_l)
{
    __shared__ float t[64][65];
    const int bid = blockIdx.x;
    const int tid = threadIdx.x;
    if (bid < 4096) {
        int i = bid * 256 + tid;
        float4 v = ((const float4*)x)[i];
        unsigned short h0 = f2bf(v.x), h1 = f2bf(v.y), h2 = f2bf(v.z), h3 = f2bf(v.w);
        unsigned short l0 = f2bf(v.x - bf2f(h0)), l1 = f2bf(v.y - bf2f(h1));
        unsigned short l2 = f2bf(v.z - bf2f(h2)), l3 = f2bf(v.w - bf2f(h3));
        uint2 ph = make_uint2((unsigned)h0 | ((unsigned)h1 << 16), (unsigned)h2 | ((unsigned)h3 << 16));
        uint2 pl = make_uint2((unsigned)l0 | ((unsigned)l1 << 16), (unsigned)l2 | ((unsigned)l3 << 16));
        *(uint2*)((char*)xa_hi + (size_t)i*8) = ph;
        *(uint2*)((char*)xa_lo + (size_t)i*8) = pl;
        return;
    }
    int tt = bid - 4096;                 // 1024 blocks: 16 x 16 x 4
    int bx = tt & 15, by = (tt >> 4) & 15, z = tt >> 8;
    const float* in = (z==0) ? Wq : (z==1) ? Wk : (z==2) ? Wv : Wd;
    __hip_bfloat16* oh = (z<3) ? (wqkv_h + (size_t)z*1024*1024) : wd_h;
    __hip_bfloat16* ol = (z<3) ? (wqkv_l + (size_t)z*1024*1024) : wd_l;
    int k0 = by*64, n0 = bx*64;
    #pragma unroll
    for (int it=0; it<4; ++it) {
        int lin = it*256 + tid;
        int r = lin >> 4, c4 = (lin & 15) << 2;
        float4 v = *(const float4*)&in[(size_t)(k0+r)*1024 + n0 + c4];
        t[r][c4] = v.x; t[r][c4+1] = v.y; t[r][c4+2] = v.z; t[r][c4+3] = v.w;
    }
    __syncthreads();
    #pragma unroll
    for (int it=0; it<4; ++it) {
        int lin = it*256 + tid;
        int r = lin >> 4, c4 = (lin & 15) << 2;
        float v0 = t[c4][r], v1 = t[c4+1][r], v2 = t[c4+2][r], v3 = t[c4+3][r];
        ushort4 hh, ll;
        hh.x = f2bf(v0); hh.y = f2bf(v1); hh.z = f2bf(v2); hh.w = f2bf(v3);
        ll.x = f2bf(v0 - bf2f(hh.x)); ll.y = f2bf(v1 - bf2f(hh.y));
        ll.z = f2bf(v2 - bf2f(hh.z)); ll.w = f2bf(v3 - bf2f(hh.w));
        size_t o = (size_t)(n0+r)*1024 + k0 + c4;
        *(ushort4*)&oh[o] = hh;
        *(ushort4*)&ol[o] = ll;
    }
}

// ---------------- transpose + f32->bf16 (standalone, PE path only) ----------------
__global__ __launch_bounds__(256) void transpose_bf16(
    const float* __restrict__ in, __hip_bfloat16* __restrict__ outp, int K, int N)
{
    __shared__ float t[64][65];
    size_t eoff = (size_t)blockIdx.z * (size_t)K * (size_t)N;
    int k0 = blockIdx.y*64, n0 = blockIdx.x*64;
    int tid = threadIdx.x;
    #pragma unroll
    for (int it=0; it<4; ++it) {
        int lin = it*256 + tid;
        int r = lin >> 4, c4 = (lin & 15) << 2;
        float4 v = *(const float4*)&in[eoff + (size_t)(k0+r)*N + n0 + c4];
        t[r][c4] = v.x; t[r][c4+1] = v.y; t[r][c4+2] = v.z; t[r][c4+3] = v.w;
    }
    __syncthreads();
    #pragma unroll
    for (int it=0; it<4; ++it) {
        int lin = it*256 + tid;
        int r = lin >> 4, c4 = (lin & 15) << 2;
        ushort4 o;
        o.x = f2bf(t[c4][r]);   o.y = f2bf(t[c4+1][r]);
        o.z = f2bf(t[c4+2][r]); o.w = f2bf(t[c4+3][r]);
        *(ushort4*)&outp[eoff + (size_t)(n0+r)*K + k0 + c4] = o;
    }
}

// ---------------- bf16x3 GEMM: C = A@B (+bias), fp32-accurate, XCD-swizzled 1D grid ----------------
template<bool BIAS>
__global__ __launch_bounds__(256, 2) void gemm_bf16x3(
    const __hip_bfloat16* __restrict__ Ah, const __hip_bfloat16* __restrict__ Al,
    const __hip_bfloat16* __restrict__ Bh, const __hip_bfloat16* __restrict__ Bl,
    float* __restrict__ C, const float* __restrict__ bias, int N, int K, int nbx)
{
    const int tid = threadIdx.x;
    const int w = tid >> 6, lane = tid & 63;
    const int wg = blockIdx.x;
    const int xcd = wg & 7, ix = wg >> 3;
    const int byc = (int)(gridDim.x >> 3) / nbx;
    const int by = xcd*byc + ix / nbx;
    const int bx = ix % nbx;

    __shared__ __align__(16) char smem[65536];
    const int AH = 0, AL = 16384, BH = 32768, BL = 49152;

    const int laneg = lane >> 3;
    const int k2sw = ((lane & 7) ^ laneg) << 4;
    const int l15 = lane & 15, l4 = lane >> 4;
    const int wr = w >> 1, wc = w & 1;

    f32x4 acc[4][4];
    #pragma unroll
    for (int m=0;m<4;m++)
        #pragma unroll
        for (int n=0;n<4;n++) acc[m][n] = (f32x4){0.f,0.f,0.f,0.f};

    for (int k0 = 0; k0 < K; k0 += 64) {
        __syncthreads();
        #pragma unroll
        for (int qq=0;qq<4;qq++) {
            int arow = by*128 + (w*4+qq)*8 + laneg;
            int brow = bx*128 + (w*4+qq)*8 + laneg;
            size_t aoff = ((size_t)arow*K + k0)*2 + k2sw;
            size_t boff = ((size_t)brow*K + k0)*2 + k2sw;
            GLOAD16((const char*)Ah + aoff, smem + AH + (w*4+qq)*1024);
            GLOAD16((const char*)Al + aoff, smem + AL + (w*4+qq)*1024);
            GLOAD16((const char*)Bh + boff, smem + BH + (w*4+qq)*1024);
            GLOAD16((const char*)Bl + boff, smem + BL + (w*4+qq)*1024);
        }
        __syncthreads();

        short8v ahf[4][2], alf[4][2], bhf[4][2], blf[4][2];
        #pragma unroll
        for (int m=0;m<4;m++) {
            int row = wr*64 + m*16 + l15;
            int rb = row << 7, rsw = (row & 7) << 4;
            #pragma unroll
            for (int s=0;s<2;s++) {
                int off = rb + ((s*64 + (l4<<4)) ^ rsw);
                ahf[m][s] = *(const short8v*)(smem + AH + off);
                alf[m][s] = *(const short8v*)(smem + AL + off);
            }
        }
        #pragma unroll
        for (int n=0;n<4;n++) {
            int row = wc*64 + n*16 + l15;
            int rb = row << 7, rsw = (row & 7) << 4;
            #pragma unroll
            for (int s=0;s<2;s++) {
                int off = rb + ((s*64 + (l4<<4)) ^ rsw);
                bhf[n][s] = *(const short8v*)(smem + BH + off);
                blf[n][s] = *(const short8v*)(smem + BL + off);
            }
        }
        #pragma unroll
        for (int m=0;m<4;m++)
            #pragma unroll
            for (int n=0;n<4;n++)
                #pragma unroll
                for (int s=0;s<2;s++) {
                    acc[m][n] = __builtin_amdgcn_mfma_f32_16x16x32_bf16(ahf[m][s], bhf[n][s], acc[m][n], 0, 0, 0);
                    acc[m][n] = __builtin_amdgcn_mfma_f32_16x16x32_bf16(ahf[m][s], blf[n][s], acc[m][n], 0, 0, 0);
                    acc[m][n] = __builtin_amdgcn_mfma_f32_16x16x32_bf16(alf[m][s], bhf[n][s], acc[m][n], 0, 0, 0);
                }
    }

    #pragma unroll
    for (int m=0;m<4;m++)
        #pragma unroll
        for (int j=0;j<4;j++) {
            int orow = by*128 + wr*64 + m*16 + l4*4 + j;
            #pragma unroll
            for (int n=0;n<4;n++) {
                int ocol = bx*128 + wc*64 + n*16 + l15;
                float v = acc[m][n][j];
                if (BIAS) v += bias[ocol];
                C[(size_t)orow*N + ocol] = v;
            }
        }
}

// ---------------- FUSED: Wd bf16x3 GEMM (blocks <256) + moe_out/misc zero (rest) ----------------
__global__ __launch_bounds__(256, 2) void wd_gemm_zero(
    const __hip_bfloat16* __restrict__ Ah, const __hip_bfloat16* __restrict__ Al,
    const __hip_bfloat16* __restrict__ Bh, const __hip_bfloat16* __restrict__ Bl,
    float* __restrict__ C, const float* __restrict__ bias,
    float* __restrict__ moe_out, float* __restrict__ misc16)
{
    const int bid = blockIdx.x;
    const int tid = threadIdx.x;
    if (bid >= 256) {
        int z = bid - 256;              // 4096 blocks
        ((float4*)moe_out)[z*256 + tid] = (float4){0.f,0.f,0.f,0.f};
        if (z == 0 && tid < 16) misc16[tid] = 0.f;
        return;
    }
    const int N = 1024, K = 1024;
    const int w = tid >> 6, lane = tid & 63;
    const int xcd = bid & 7, ix = bid >> 3;
    const int by = xcd*4 + ix / 8;
    const int bx = ix % 8;

    __shared__ __align__(16) char smem[65536];
    const int AH = 0, AL = 16384, BH = 32768, BL = 49152;

    const int laneg = lane >> 3;
    const int k2sw = ((lane & 7) ^ laneg) << 4;
    const int l15 = lane & 15, l4 = lane >> 4;
    const int wr = w >> 1, wc = w & 1;

    f32x4 acc[4][4];
    #pragma unroll
    for (int m=0;m<4;m++)
        #pragma unroll
        for (int n=0;n<4;n++) acc[m][n] = (f32x4){0.f,0.f,0.f,0.f};

    for (int k0 = 0; k0 < K; k0 += 64) {
        __syncthreads();
        #pragma unroll
        for (int qq=0;qq<4;qq++) {
            int arow = by*128 + (w*4+qq)*8 + laneg;
            int brow = bx*128 + (w*4+qq)*8 + laneg;
            size_t aoff = ((size_t)arow*K + k0)*2 + k2sw;
            size_t boff = ((size_t)brow*K + k0)*2 + k2sw;
            GLOAD16((const char*)Ah + aoff, smem + AH + (w*4+qq)*1024);
            GLOAD16((const char*)Al + aoff, smem + AL + (w*4+qq)*1024);
            GLOAD16((const char*)Bh + boff, smem + BH + (w*4+qq)*1024);
            GLOAD16((const char*)Bl + boff, smem + BL + (w*4+qq)*1024);
        }
        __syncthreads();

        short8v ahf[4][2], alf[4][2], bhf[4][2], blf[4][2];
        #pragma unroll
        for (int m=0;m<4;m++) {
            int row = wr*64 + m*16 + l15;
            int rb = row << 7, rsw = (row & 7) << 4;
            #pragma unroll
            for (int s=0;s<2;s++) {
                int off = rb + ((s*64 + (l4<<4)) ^ rsw);
                ahf[m][s] = *(const short8v*)(smem + AH + off);
                alf[m][s] = *(const short8v*)(smem + AL + off);
            }
        }
        #pragma unroll
        for (int n=0;n<4;n++) {
            int row = wc*64 + n*16 + l15;
            int rb = row << 7, rsw = (row & 7) << 4;
            #pragma unroll
            for (int s=0;s<2;s++) {
                int off = rb + ((s*64 + (l4<<4)) ^ rsw);
                bhf[n][s] = *(const short8v*)(smem + BH + off);
                blf[n][s] = *(const short8v*)(smem + BL + off);
            }
        }
        #pragma unroll
        for (int m=0;m<4;m++)
            #pragma unroll
            for (int n=0;n<4;n++)
                #pragma unroll
                for (int s=0;s<2;s++) {
                    acc[m][n] = __builtin_amdgcn_mfma_f32_16x16x32_bf16(ahf[m][s], bhf[n][s], acc[m][n], 0, 0, 0);
                    acc[m][n] = __builtin_amdgcn_mfma_f32_16x16x32_bf16(ahf[m][s], blf[n][s], acc[m][n], 0, 0, 0);
                    acc[m][n] = __builtin_amdgcn_mfma_f32_16x16x32_bf16(alf[m][s], bhf[n][s], acc[m][n], 0, 0, 0);
                }
    }

    #pragma unroll
    for (int m=0;m<4;m++)
        #pragma unroll
        for (int j=0;j<4;j++) {
            int orow = by*128 + wr*64 + m*16 + l4*4 + j;
            #pragma unroll
            for (int n=0;n<4;n++) {
                int ocol = bx*128 + wc*64 + n*16 + l15;
                C[(size_t)orow*N + ocol] = acc[m][n][j] + bias[ocol];
            }
        }
}

// ---------------- FUSED: QKV bf16x3 GEMM (blocks <768) + W1/W2 transpose (rest) ----------------
__global__ __launch_bounds__(256, 2) void fused_qkv_w12(
    const __hip_bfloat16* __restrict__ Ah, const __hip_bfloat16* __restrict__ Al,
    const __hip_bfloat16* __restrict__ Bh, const __hip_bfloat16* __restrict__ Bl,
    float* __restrict__ C,
    const float* __restrict__ W1, const float* __restrict__ W2,
    __hip_bfloat16* __restrict__ W1t, __hip_bfloat16* __restrict__ W2t)
{
    __shared__ __align__(16) char smem[65536];
    const int tid = threadIdx.x;
    const int bid = blockIdx.x;

    if (bid < 768) {
        const int N = 3072, K = 1024;
        const int w = tid >> 6, lane = tid & 63;
        const int xcd = bid & 7, ix = bid >> 3;
        const int by = xcd*4 + ix / 24;
        const int bx = ix % 24;
        const int AH = 0, AL = 16384, BH = 32768, BL = 49152;
        const int laneg = lane >> 3;
        const int k2sw = ((lane & 7) ^ laneg) << 4;
        const int l15 = lane & 15, l4 = lane >> 4;
        const int wr = w >> 1, wc = w & 1;

        f32x4 acc[4][4];
        #pragma unroll
        for (int m=0;m<4;m++)
            #pragma unroll
            for (int n=0;n<4;n++) acc[m][n] = (f32x4){0.f,0.f,0.f,0.f};

        for (int k0 = 0; k0 < K; k0 += 64) {
            __syncthreads();
            #pragma unroll
            for (int qq=0;qq<4;qq++) {
                int arow = by*128 + (w*4+qq)*8 + laneg;
                int brow = bx*128 + (w*4+qq)*8 + laneg;
                size_t aoff = ((size_t)arow*K + k0)*2 + k2sw;
                size_t boff = ((size_t)brow*K + k0)*2 + k2sw;
                GLOAD16((const char*)Ah + aoff, smem + AH + (w*4+qq)*1024);
                GLOAD16((const char*)Al + aoff, smem + AL + (w*4+qq)*1024);
                GLOAD16((const char*)Bh + boff, smem + BH + (w*4+qq)*1024);
                GLOAD16((const char*)Bl + boff, smem + BL + (w*4+qq)*1024);
            }
            __syncthreads();

            short8v ahf[4][2], alf[4][2], bhf[4][2], blf[4][2];
            #pragma unroll
            for (int m=0;m<4;m++) {
                int row = wr*64 + m*16 + l15;
                int rb = row << 7, rsw = (row & 7) << 4;
                #pragma unroll
                for (int s=0;s<2;s++) {
                    int off = rb + ((s*64 + (l4<<4)) ^ rsw);
                    ahf[m][s] = *(const short8v*)(smem + AH + off);
                    alf[m][s] = *(const short8v*)(smem + AL + off);
                }
            }
            #pragma unroll
            for (int n=0;n<4;n++) {
                int row = wc*64 + n*16 + l15;
                int rb = row << 7, rsw = (row & 7) << 4;
                #pragma unroll
                for (int s=0;s<2;s++) {
                    int off = rb + ((s*64 + (l4<<4)) ^ rsw);
                    bhf[n][s] = *(const short8v*)(smem + BH + off);
                    blf[n][s] = *(const short8v*)(smem + BL + off);
                }
            }
            #pragma unroll
            for (int m=0;m<4;m++)
                #pragma unroll
                for (int n=0;n<4;n++)
                    #pragma unroll
                    for (int s=0;s<2;s++) {
                        acc[m][n] = __builtin_amdgcn_mfma_f32_16x16x32_bf16(ahf[m][s], bhf[n][s], acc[m][n], 0, 0, 0);
                        acc[m][n] = __builtin_amdgcn_mfma_f32_16x16x32_bf16(ahf[m][s], blf[n][s], acc[m][n], 0, 0, 0);
                        acc[m][n] = __builtin_amdgcn_mfma_f32_16x16x32_bf16(alf[m][s], bhf[n][s], acc[m][n], 0, 0, 0);
                    }
        }

        #pragma unroll
        for (int m=0;m<4;m++)
            #pragma unroll
            for (int j=0;j<4;j++) {
                int orow = by*128 + wr*64 + m*16 + l4*4 + j;
                #pragma unroll
                for (int n=0;n<4;n++) {
                    int ocol = bx*128 + wc*64 + n*16 + l15;
                    C[(size_t)orow*N + ocol] = acc[m][n][j];
                }
            }
        return;
    }

    // ---- transpose path ----
    int t = bid - 768;
    const float* src;
    __hip_bfloat16* dst;
    int K, N;
    if (t < 8192) { src = W1; dst = W1t; K = 1024; N = 4096; }
    else          { t -= 8192; src = W2; dst = W2t; K = 4096; N = 1024; }
    const int nb_n = N >> 6;
    int bx = t % nb_n;
    int rest = t / nb_n;
    int by = rest % (K >> 6);
    int bz = rest / (K >> 6);
    size_t eoff = (size_t)bz * (size_t)K * (size_t)N;
    int k0 = by*64, n0 = bx*64;
    float (*tt)[65] = (float(*)[65])smem;
    #pragma unroll
    for (int it=0; it<4; ++it) {
        int lin = it*256 + tid;
        int r = lin >> 4, c4 = (lin & 15) << 2;
        float4 v = *(const float4*)&src[eoff + (size_t)(k0+r)*N + n0 + c4];
        tt[r][c4] = v.x; tt[r][c4+1] = v.y; tt[r][c4+2] = v.z; tt[r][c4+3] = v.w;
    }
    __syncthreads();
    #pragma unroll
    for (int it=0; it<4; ++it) {
        int lin = it*256 + tid;
        int r = lin >> 4, c4 = (lin & 15) << 2;
        ushort4 o;
        o.x = f2bf(tt[c4][r]);   o.y = f2bf(tt[c4+1][r]);
        o.z = f2bf(tt[c4+2][r]); o.w = f2bf(tt[c4+3][r]);
        *(ushort4*)&dst[eoff + (size_t)(n0+r)*K + k0 + c4] = o;
    }
}

// ---------------- MFMA MoE GEMM ----------------
template<int MODE, bool PE>
__global__ __launch_bounds__(256) void moe_mfma(
    const __hip_bfloat16* __restrict__ A,
    const __hip_bfloat16* __restrict__ Bt,
    __hip_bfloat16* __restrict__ y1,
    float* __restrict__ moe_out,
    const int* __restrict__ slot_token,
    const float* __restrict__ slot_w,
    const int* __restrict__ tile_expert,
    const int* __restrict__ cnt_ptr,
    const int* __restrict__ base_ptr,
    int N, int K, int nbx)
{
    const int tid = threadIdx.x;
    const int w = tid >> 6, lane = tid & 63;

    int bx, slot0, y1row0;
    const __hip_bfloat16* Bp;
    if (PE) {
        bx = blockIdx.x;
        int tloc = blockIdx.y;
        if ((tloc << 7) >= *cnt_ptr) return;
        slot0 = *base_ptr + (tloc << 7);
        y1row0 = tloc << 7;
        Bp = Bt;
    } else {
        const int wg = blockIdx.x;
        const int xcd = wg & 7, ix = wg >> 3;
        const int byc = (int)(gridDim.x >> 3) / nbx;
        int gt = xcd*byc + ix % byc;                   // bx-major: tile varies fastest
        bx = ix / byc;
        if (gt >= *cnt_ptr) return;
        int e = tile_expert[gt];
        Bp = Bt + (size_t)e * (size_t)K * (size_t)N;
        slot0 = gt << 7;
        y1row0 = gt << 7;
    }

    __shared__ __align__(16) char smem[32768];

    const int laneg = lane >> 3;
    const int k2sw = ((lane & 7) ^ laneg) << 4;

    int tokq[4];
    if (MODE == 2) {
        #pragma unroll
        for (int qq=0;qq<4;qq++) {
            int t0 = slot_token[slot0 + (w*4+qq)*8 + laneg];
            tokq[qq] = t0 < 0 ? 0 : t0;
        }
    }

    f32x4 acc[4][4];
    #pragma unroll
    for (int m=0;m<4;m++)
        #pragma unroll
        for (int n=0;n<4;n++) acc[m][n] = (f32x4){0.f,0.f,0.f,0.f};

    const int l15 = lane & 15;
    const int l4  = lane >> 4;
    const int wr = w >> 1, wc = w & 1;

    for (int k0 = 0; k0 < K; k0 += 64) {
        __syncthreads();
        #pragma unroll
        for (int qq=0;qq<4;qq++) {
            const char* ga;
            if (MODE == 2) {
                ga = (const char*)A + (((size_t)tokq[qq])*K + k0)*2 + k2sw;
            } else {
                int row = y1row0 + (w*4+qq)*8 + laneg;
                ga = (const char*)A + ((size_t)row*K + k0)*2 + k2sw;
            }
            GLOAD16(ga, smem + (w*4+qq)*1024);
        }
        #pragma unroll
        for (int qq=0;qq<4;qq++) {
            int row = bx*128 + (w*4+qq)*8 + laneg;
            const char* gb = (const char*)Bp + ((size_t)row*K + k0)*2 + k2sw;
            GLOAD16(gb, smem + 16384 + (w*4+qq)*1024);
        }
        __syncthreads();

        short8v a_frag[4][2], b_frag[4][2];
        #pragma unroll
        for (int m=0;m<4;m++) {
            int row = wr*64 + m*16 + l15;
            int rb = row << 7;
            #pragma unroll
            for (int s=0;s<2;s++) {
                int off = rb + ((s*64 + (l4<<4)) ^ ((row&7)<<4));
                a_frag[m][s] = *(const short8v*)(smem + off);
            }
        }
        #pragma unroll
        for (int n=0;n<4;n++) {
            int row = wc*64 + n*16 + l15;
            int rb = row << 7;
            #pragma unroll
            for (int s=0;s<2;s++) {
                int off = rb + ((s*64 + (l4<<4)) ^ ((row&7)<<4));
                b_frag[n][s] = *(const short8v*)(smem + 16384 + off);
            }
        }
        #pragma unroll
        for (int m=0;m<4;m++)
            #pragma unroll
            for (int n=0;n<4;n++) {
                acc[m][n] = __builtin_amdgcn_mfma_f32_16x16x32_bf16(a_frag[m][0], b_frag[n][0], acc[m][n], 0, 0, 0);
                acc[m][n] = __builtin_amdgcn_mfma_f32_16x16x32_bf16(a_frag[m][1], b_frag[n][1], acc[m][n], 0, 0, 0);
            }
    }

    if (MODE == 3) {
        #pragma unroll
        for (int m=0;m<4;m++) {
            #pragma unroll
            for (int j=0;j<4;j++) {
                int orow = wr*64 + m*16 + l4*4 + j;
                int slot = slot0 + orow;
                int tok = slot_token[slot];
                if (tok < 0) continue;
                float sw = slot_w[slot];
                #pragma unroll
                for (int n=0;n<4;n++) {
                    int ocol = bx*128 + wc*64 + n*16 + l15;
                    atomicAdd(&moe_out[(size_t)tok*H_ + ocol], sw * acc[m][n][j]);
                }
            }
        }
    } else {
        __syncthreads();
        #pragma unroll
        for (int m=0;m<4;m++)
            #pragma unroll
            for (int j=0;j<4;j++) {
                int orow = wr*64 + m*16 + l4*4 + j;
                #pragma unroll
                for (int n=0;n<4;n++) {
                    int ocol = wc*64 + n*16 + l15;
                    unsigned short g = f2bf(gelu_fast(acc[m][n][j]));
                    *(unsigned short*)(smem + orow*256 + ocol*2) = g;
                }
            }
        __syncthreads();
        #pragma unroll
        for (int s=0;s<8;s++) {
            int row = w*32 + s*4 + l4;
            short8v v = *(const short8v*)(smem + row*256 + l15*16);
            *(short8v*)((char*)y1 + ((size_t)(y1row0 + row)*N + bx*128 + l15*8)*2) = v;
        }
    }
}

// ---------------- FUSED RoPE+split (blocks <8192) + V transpose+split ----------------
__global__ __launch_bounds__(256) void rope_vsplit(
    const float* __restrict__ qkv,
    __hip_bfloat16* __restrict__ qh, __hip_bfloat16* __restrict__ ql,
    __hip_bfloat16* __restrict__ kh, __hip_bfloat16* __restrict__ kl,
    __hip_bfloat16* __restrict__ vth, __hip_bfloat16* __restrict__ vtl)
{
    __shared__ float t[64][65];
    const int bid = blockIdx.x;
    const int tid = threadIdx.x;
    if (bid < 8192) {
        int idx = bid * 256 + tid;
        int i = idx & 31;
        int n = (idx >> 5) & (NH_-1);
        int tk = idx >> 9;
        int b = tk >> 11;
        int pos = tk & (S_ - 1);
        float inv = exp2f((float)i * (-13.287712379549449f / 32.f));
        float ang = (float)pos * inv;
        float c = cosf(ang), s = sinf(ang);
        size_t base = (size_t)tk*3072 + (size_t)n*64;
        size_t obase = ((size_t)(b*NH_ + n)*S_ + pos)*64;

        float q1 = qkv[base+i], q2 = qkv[base+i+32];
        float qo1 = (q1*c - q2*s)*0.125f;
        float qo2 = (q2*c + q1*s)*0.125f;
        unsigned short h1 = f2bf(qo1), h2 = f2bf(qo2);
        qh[obase+i]    = *(__hip_bfloat16*)&h1;
        qh[obase+i+32] = *(__hip_bfloat16*)&h2;
        unsigned short lo1 = f2bf(qo1 - bf2f(h1)), lo2 = f2bf(qo2 - bf2f(h2));
        ql[obase+i]    = *(__hip_bfloat16*)&lo1;
        ql[obase+i+32] = *(__hip_bfloat16*)&lo2;

        float k1 = qkv[base+1024+i], k2 = qkv[base+1024+i+32];
        float ko1 = k1*c - k2*s;
        float ko2 = k2*c + k1*s;
        unsigned short kh1 = f2bf(ko1), kh2 = f2bf(ko2);
        kh[obase+i]    = *(__hip_bfloat16*)&kh1;
        kh[obase+i+32] = *(__hip_bfloat16*)&kh2;
        unsigned short kl1 = f2bf(ko1 - bf2f(kh1)), kl2 = f2bf(ko2 - bf2f(kh2));
        kl[obase+i]    = *(__hip_bfloat16*)&kl1;
        kl[obase+i+32] = *(__hip_bfloat16*)&kl2;
        return;
    }
    int tt = bid - 8192;           // 1024 blocks: 32 x 16 x 2
    const int s0 = (tt & 31)*64;
    const int hn = (tt >> 5) & 15;
    const int b  = tt >> 9;
    #pragma unroll
    for (int it=0; it<4; ++it) {
        int lin = it*256 + tid;
        int r = lin >> 4, c4 = (lin & 15) << 2;
        float4 vv = *(const float4*)&qkv[(size_t)(b*S_ + s0 + r)*3072 + 2048 + hn*64 + c4];
        t[r][c4] = vv.x; t[r][c4+1] = vv.y; t[r][c4+2] = vv.z; t[r][c4+3] = vv.w;
    }
    __syncthreads();
    size_t obase = (size_t)(b*NH_ + hn)*64*S_;
    #pragma unroll
    for (int it=0; it<4; ++it) {
        int lin = it*256 + tid;
        int d = lin >> 4, c4 = (lin & 15) << 2;
        float v0 = t[c4][d], v1 = t[c4+1][d], v2 = t[c4+2][d], v3 = t[c4+3][d];
        ushort4 hh, ll;
        hh.x = f2bf(v0); hh.y = f2bf(v1); hh.z = f2bf(v2); hh.w = f2bf(v3);
        ll.x = f2bf(v0 - bf2f(hh.x)); ll.y = f2bf(v1 - bf2f(hh.y));
        ll.z = f2bf(v2 - bf2f(hh.z)); ll.w = f2bf(v3 - bf2f(hh.w));
        size_t o = obase + (size_t)d*S_ + s0 + c4;
        *(ushort4*)&vth[o] = hh;
        *(ushort4*)&vtl[o] = ll;
    }
}

// ---------------- MFMA attention: bf16x3, XCD-swizzled, no-max softmax, 32KB LDS,
// 128 q-rows/block (K/V staging amortized over 2x MFMA; P region wave-private per half) ----------------
__global__ __launch_bounds__(256) void attn_mfma(
    const __hip_bfloat16* __restrict__ qh, const __hip_bfloat16* __restrict__ ql,
    const __hip_bfloat16* __restrict__ kh, const __hip_bfloat16* __restrict__ kl,
    const __hip_bfloat16* __restrict__ vth, const __hip_bfloat16* __restrict__ vtl,
    __hip_bfloat16* __restrict__ ctx_hi, __hip_bfloat16* __restrict__ ctx_lo)
{
    const int wg = blockIdx.x;          // 512 blocks
    const int xcd = wg & 7;
    const int ix = wg >> 3;             // 0..63
    const int head = xcd*4 + (ix >> 4); // 4 heads per XCD
    const int qt = ix & 15;             // 16 tiles of 128 q-rows
    const int b = head >> 4, hn = head & 15;

    const int tid = threadIdx.x;
    const int w = tid >> 6, lane = tid & 63;
    const int l15 = lane & 15, l4 = lane >> 4;
    const int laneg = lane >> 3;
    const int k2sw = ((lane & 7) ^ laneg) << 4;

    __shared__ __align__(16) char smem[32768];
    const int KHo = 0, KLo = 8192, VHo = 16384, VLo = 24576;
    const int PHo = 0, PLo = 8192;

    const size_t kbase = (size_t)head*S_*64;
    const size_t vbase = (size_t)head*64*S_;

    // ---- Q prologue: two 64-row halves staged through the K region ----
    short8v qhf[2][2], qlf[2][2];
    #pragma unroll
    for (int m=0;m<2;m++) {
        #pragma unroll
        for (int qq=0;qq<2;qq++) {
            int c = w*2 + qq;
            int row = qt*128 + m*64 + c*8 + laneg;
            size_t off = (kbase + (size_t)row*64)*2 + k2sw;
            GLOAD16((const char*)qh + off, smem + KHo + c*1024);
            GLOAD16((const char*)ql + off, smem + KLo + c*1024);
        }
        __syncthreads();   // staged visible (drains vmcnt)
        {
            int row = w*16 + l15;
            int rsw = (row & 7) << 4;
            #pragma unroll
            for (int s=0;s<2;s++) {
                int off = row*128 + ((s*64 + l4*16) ^ rsw);
                qhf[m][s] = *(const short8v*)(smem + KHo + off);
                qlf[m][s] = *(const short8v*)(smem + KLo + off);
            }
        }
        __syncthreads();   // all waves read frags before region reused
    }

    f32x4 acc[2][4];
    #pragma unroll
    for (int m=0;m<2;m++)
        #pragma unroll
        for (int db=0;db<4;db++) acc[m][db] = (f32x4){0.f,0.f,0.f,0.f};
    float lrun[2][4] = {{0.f,0.f,0.f,0.f},{0.f,0.f,0.f,0.f}};

    for (int kt=0; kt<S_/64; ++kt) {
        // ---- stage K rows + V^T rows ----
        #pragma unroll
        for (int qq=0;qq<2;qq++) {
            int c = w*2 + qq;
            int r8 = c*8 + laneg;
            size_t koff = (kbase + (size_t)(kt*64 + r8)*64)*2 + k2sw;
            GLOAD16((const char*)kh + koff, smem + KHo + c*1024);
            GLOAD16((const char*)kl + koff, smem + KLo + c*1024);
            size_t voff = (vbase + (size_t)r8*S_ + kt*64)*2 + k2sw;
            GLOAD16((const char*)vth + voff, smem + VHo + c*1024);
            GLOAD16((const char*)vtl + voff, smem + VLo + c*1024);
        }
        __syncthreads();   // staged tile visible

        // ---- QK^T for BOTH q-halves (shared K ds_reads) ----
        f32x4 s_acc[2][4];
        #pragma unroll
        for (int cb=0;cb<4;cb++) {
            s_acc[0][cb] = (f32x4){0.f,0.f,0.f,0.f};
            s_acc[1][cb] = (f32x4){0.f,0.f,0.f,0.f};
            int row = cb*16 + l15;
            int rsw = (row & 7) << 4;
            #pragma unroll
            for (int s=0;s<2;s++) {
                int off = row*128 + ((s*64 + l4*16) ^ rsw);
                short8v khf = *(const short8v*)(smem + KHo + off);
                short8v klf = *(const short8v*)(smem + KLo + off);
                s_acc[0][cb] = __builtin_amdgcn_mfma_f32_16x16x32_bf16(qhf[0][s], khf, s_acc[0][cb], 0, 0, 0);
                s_acc[0][cb] = __builtin_amdgcn_mfma_f32_16x16x32_bf16(qhf[0][s], klf, s_acc[0][cb], 0, 0, 0);
                s_acc[0][cb] = __builtin_amdgcn_mfma_f32_16x16x32_bf16(qlf[0][s], khf, s_acc[0][cb], 0, 0, 0);
                s_acc[1][cb] = __builtin_amdgcn_mfma_f32_16x16x32_bf16(qhf[1][s], khf, s_acc[1][cb], 0, 0, 0);
                s_acc[1][cb] = __builtin_amdgcn_mfma_f32_16x16x32_bf16(qhf[1][s], klf, s_acc[1][cb], 0, 0, 0);
                s_acc[1][cb] = __builtin_amdgcn_mfma_f32_16x16x32_bf16(qlf[1][s], khf, s_acc[1][cb], 0, 0, 0);
            }
        }
        __syncthreads();   // ALL waves done reading K; P may overwrite it

        // ---- per-half: P=exp(s) -> wave-private LDS rows -> PV ----
        #pragma unroll
        for (int m=0;m<2;m++) {
            #pragma unroll
            for (int cb=0;cb<4;cb++)
                #pragma unroll
                for (int j=0;j<4;j++) {
                    float p = __expf(s_acc[m][cb][j]);
                    lrun[m][j] += p;
                    int prow = w*16 + l4*4 + j;
                    unsigned short hh = f2bf(p);
                    unsigned short ll = f2bf(p - bf2f(hh));
                    int off = prow*128 + (((cb*16 + l15)*2) ^ ((prow&7)<<4));
                    *(unsigned short*)(smem + PHo + off) = hh;
                    *(unsigned short*)(smem + PLo + off) = ll;
                }
            asm volatile("s_waitcnt lgkmcnt(0)" ::: "memory");
            __builtin_amdgcn_sched_barrier(0);

            short8v pah[2], pal[2];
            {
                int row = w*16 + l15;
                int rsw = (row & 7) << 4;
                #pragma unroll
                for (int s=0;s<2;s++) {
                    int off = row*128 + ((s*64 + l4*16) ^ rsw);
                    pah[s] = *(const short8v*)(smem + PHo + off);
                    pal[s] = *(const short8v*)(smem + PLo + off);
                }
            }
            #pragma unroll
            for (int db=0;db<4;db++) {
                int row = db*16 + l15;
                int rsw = (row & 7) << 4;
                #pragma unroll
                for (int s=0;s<2;s++) {
                    int off = row*128 + ((s*64 + l4*16) ^ rsw);
                    short8v vhf = *(const short8v*)(smem + VHo + off);
                    short8v vlf = *(const short8v*)(smem + VLo + off);
                    acc[m][db] = __builtin_amdgcn_mfma_f32_16x16x32_bf16(pah[s], vhf, acc[m][db], 0, 0, 0);
                    acc[m][db] = __builtin_amdgcn_mfma_f32_16x16x32_bf16(pah[s], vlf, acc[m][db], 0, 0, 0);
                    acc[m][db] = __builtin_amdgcn_mfma_f32_16x16x32_bf16(pal[s], vhf, acc[m][db], 0, 0, 0);
                }
            }
            __builtin_amdgcn_sched_barrier(0);   // pin m=0 P-reads before m=1 P-writes
        }
        __syncthreads();   // all P/V reads done before next tile staging
    }

    // ---- deferred row-sum reduce + epilogue ----
    #pragma unroll
    for (int m=0;m<2;m++) {
        #pragma unroll
        for (int j=0;j<4;j++) {
            float s = lrun[m][j];
            #pragma unroll
            for (int mk=8;mk;mk>>=1) s += __shfl_xor(s, mk);
            lrun[m][j] = s;
        }
        #pragma unroll
        for (int db=0;db<4;db++)
            #pragma unroll
            for (int j=0;j<4;j++) {
                int qrow = qt*128 + m*64 + w*16 + l4*4 + j;
                float o = acc[m][db][j] / lrun[m][j];
                unsigned short hh = f2bf(o);
                unsigned short ll = f2bf(o - bf2f(hh));
                size_t oidx = (size_t)(b*S_ + qrow)*H_ + hn*64 + db*16 + l15;
                ctx_hi[oidx] = *(__hip_bfloat16*)&hh;
                ctx_lo[oidx] = *(__hip_bfloat16*)&ll;
            }
    }
}

// ---------------- layernorm (residual fused, optional bf16 out) ----------------
__global__ __launch_bounds__(256) void ln_kernel(
    const float* __restrict__ a, const float* __restrict__ res,
    const float* __restrict__ g, const float* __restrict__ beta,
    float* __restrict__ out, __hip_bfloat16* __restrict__ outb)
{
    int row = blockIdx.x, tid = threadIdx.x;
    const float4 va = ((const float4*)(a + (size_t)row*H_))[tid];
    const float4 vr = ((const float4*)(res + (size_t)row*H_))[tid];
    float x0=va.x+vr.x, x1=va.y+vr.y, x2=va.z+vr.z, x3=va.w+vr.w;
    float s  = x0+x1+x2+x3;
    float ss = x0*x0 + x1*x1 + x2*x2 + x3*x3;
    #pragma unroll
    for (int off=32; off; off>>=1) { s += __shfl_xor(s, off); ss += __shfl_xor(ss, off); }
    __shared__ float red[8];
    if ((tid&63)==0) { red[tid>>6]=s; red[4+(tid>>6)]=ss; }
    __syncthreads();
    if (tid==0) { red[0]=red[0]+red[1]+red[2]+red[3]; red[4]=red[4]+red[5]+red[6]+red[7]; }
    __syncthreads();
    float mu  = red[0] * (1.f/H_);
    float var = red[4] * (1.f/H_) - mu*mu;
    float rs = rsqrtf(fmaxf(var, 0.f) + 1e-12f);
    const float4 vg = ((const float4*)g)[tid];
    const float4 vb = ((const float4*)beta)[tid];
    float4 vo;
    vo.x = (x0-mu)*rs*vg.x + vb.x;
    vo.y = (x1-mu)*rs*vg.y + vb.y;
    vo.z = (x2-mu)*rs*vg.z + vb.z;
    vo.w = (x3-mu)*rs*vg.w + vb.w;
    ((float4*)(out + (size_t)row*H_))[tid] = vo;
    if (outb) {
        unsigned int p0 = (unsigned)f2bf(vo.x) | ((unsigned)f2bf(vo.y) << 16);
        unsigned int p1 = (unsigned)f2bf(vo.z) | ((unsigned)f2bf(vo.w) << 16);
        ((uint2*)(outb + (size_t)row*H_))[tid] = make_uint2(p0, p1);
    }
}

// ---------------- router: 64 blocks x 64 tokens, register-accumulated stats ----------------
__global__ __launch_bounds__(256) void router_kernel(
    const float* __restrict__ hs, const float* __restrict__ Wg,
    int* __restrict__ tok_e, float* __restrict__ tok_w,
    int* __restrict__ counts, float* __restrict__ P_sum)
{
    const int w = threadIdx.x >> 6, lane = threadIdx.x & 63;
    float psum[E_];
    int cnt[E_];
    #pragma unroll
    for (int e=0;e<E_;e++){ psum[e]=0.f; cnt[e]=0; }

    for (int it=0; it<16; ++it) {
        int t = blockIdx.x*64 + it*4 + w;
        const float* row = hs + (size_t)t * H_;
        float acc[E_];
        #pragma unroll
        for (int e=0;e<E_;e++) acc[e]=0.f;
        for (int i16=0; i16<16; ++i16) {
            int i = i16*64 + lane;
            float xv = row[i];
            const float* wg = Wg + (size_t)i*E_;
            #pragma unroll
            for (int e=0;e<E_;e++) acc[e] = fmaf(xv, wg[e], acc[e]);
        }
        #pragma unroll
        for (int e=0;e<E_;e++) {
            float vv = acc[e];
            #pragma unroll
            for (int off=32; off; off>>=1) vv += __shfl_xor(vv, off);
            acc[e] = vv;
        }
        float mx = acc[0];
        #pragma unroll
        for (int e=1;e<E_;e++) mx = fmaxf(mx, acc[e]);
        float p[E_], se=0.f;
        #pragma unroll
        for (int e=0;e<E_;e++){ p[e] = __expf(acc[e]-mx); se += p[e]; }
        float isv = 1.f/se;
        #pragma unroll
        for (int e=0;e<E_;e++){ p[e]*=isv; psum[e] += p[e]; }
        int e1=0;
        #pragma unroll
        for (int e=1;e<E_;e++) if (p[e] > p[e1]) e1=e;
        int e2 = (e1==0)?1:0;
        #pragma unroll
        for (int e=0;e<E_;e++) if (e!=e1 && p[e] > p[e2]) e2=e;
        #pragma unroll
        for (int e=0;e<E_;e++) cnt[e] += (e==e1?1:0) + (e==e2?1:0);
        if (lane==0) {
            float w1=p[e1], w2=p[e2], si=1.f/(w1+w2);
            tok_e[t*2]=e1; tok_e[t*2+1]=e2;
            tok_w[t*2]=w1*si; tok_w[t*2+1]=w2*si;
        }
    }
    if (lane==0) {
        #pragma unroll
        for (int e=0;e<E_;e++) {
            atomicAdd(&P_sum[e], psum[e]);
            atomicAdd(&counts[e], cnt[e]);
        }
    }
}

__global__ void router_finalize(
    const int* __restrict__ counts, const float* __restrict__ P_sum,
    int* __restrict__ base, int* __restrict__ cursor,
    int* __restrict__ cnt_pad, int* __restrict__ ntiles,
    int* __restrict__ slot_token, int* __restrict__ tile_expert,
    float* __restrict__ aux_out)
{
    __shared__ int sbase[E_+1];
    if (threadIdx.x == 0) {
        int bacc = 0;
        float aux = 0.f;
        for (int e=0;e<E_;e++) {
            sbase[e] = bacc; base[e] = bacc;
            int cp = (counts[e] + 127) & ~127;
            cnt_pad[e] = cp;
            bacc += cp;
            cursor[e] = 0;
            aux += ((float)counts[e]/(float)T_) * (P_sum[e]/(float)T_);
        }
        sbase[E_] = bacc;
        *ntiles = bacc >> 7;
        *aux_out = (float)E_ * aux;
    }
    __syncthreads();
    for (int sIdx = (int)threadIdx.x; sIdx < MAXSLOTS; sIdx += (int)blockDim.x)
        slot_token[sIdx] = -1;
    for (int tt = (int)threadIdx.x; tt < MAXTILES; tt += (int)blockDim.x) {
        int s = tt*128;
        int e = E_-1;
        for (int qe=0; qe<E_; ++qe) if (s < sbase[qe+1]) { e = qe; break; }
        tile_expert[tt] = e;
    }
}

__global__ void scatter_slots(
    const int* __restrict__ tok_e, const float* __restrict__ tok_w,
    const int* __restrict__ base, int* __restrict__ cursor,
    int* __restrict__ slot_token, float* __restrict__ slot_w)
{
    int t = blockIdx.x*blockDim.x + threadIdx.x;
    if (t >= T_) return;
    #pragma unroll
    for (int j=0;j<2;j++) {
        int e = tok_e[t*2+j];
        int pos = atomicAdd(&cursor[e], 1);
        int s = base[e] + pos;
        slot_token[s] = t;
        slot_w[s] = tok_w[t*2+j];
    }
}

extern "C" void kernel_launch(void* const* d_in, const int* in_sizes, int n_in,
                              void* d_out, int out_size, void* d_ws, size_t ws_size,
                              hipStream_t stream)
{
    const float* x    = (const float*)d_in[0];
    const float* Wq   = (const float*)d_in[1];
    const float* Wk   = (const float*)d_in[2];
    const float* Wv   = (const float*)d_in[3];
    const float* Wd   = (const float*)d_in[4];
    const float* bd   = (const float*)d_in[5];
    const float* ln1g = (const float*)d_in[6];
    const float* ln1b = (const float*)d_in[7];
    const float* Wg   = (const float*)d_in[8];
    const float* W1   = (const float*)d_in[9];
    const float* W2   = (const float*)d_in[10];
    const float* ln2g = (const float*)d_in[11];
    const float* ln2b = (const float*)d_in[12];
    float* out = (float*)d_out;

    float* f0 = (float*)d_ws;
    const size_t M1 = 1u << 20;
    float* qkv      = f0;
    float* attn_out = f0 + 12*M1;
    float* hs       = f0;
    float* moe_out  = f0 + 4*M1;
    __hip_bfloat16* hs_b = (__hip_bfloat16*)(f0 + 16*M1);

    float* misc = f0 + 18*M1;
    int*   misc_i = (int*)misc;
    int*   tok_e   = misc_i;
    float* tok_w   = misc + 8192;
    int*   slot_tok= misc_i + 16384;
    float* slot_w  = misc + 25600;
    int*   counts  = misc_i + 34816;
    float* P_sum   = misc + 34824;
    int*   cursor  = misc_i + 34832;
    int*   basep   = misc_i + 34840;
    int*   cnt_pad = misc_i + 34848;
    int*   ntiles  = misc_i + 34856;
    int*   tile_ex = misc_i + 34857;

    float* off_p = f0 + 18*M1 + 65536;
    __hip_bfloat16* xa_hi = (__hip_bfloat16*)(off_p);
    __hip_bfloat16* xa_lo = (__hip_bfloat16*)(off_p + 2*M1);
    __hip_bfloat16* at_qh = (__hip_bfloat16*)(off_p + 4*M1);
    __hip_bfloat16* at_ql = (__hip_bfloat16*)(off_p + 6*M1);
    __hip_bfloat16* at_kh = (__hip_bfloat16*)(off_p + 8*M1);
    __hip_bfloat16* at_kl = (__hip_bfloat16*)(off_p + 10*M1);
    __hip_bfloat16* at_vh = (__hip_bfloat16*)(off_p + 12*M1);
    __hip_bfloat16* at_vl = (__hip_bfloat16*)(off_p + 14*M1);
    __hip_bfloat16* wqkv_h = (__hip_bfloat16*)(off_p + 16*M1);
    __hip_bfloat16* wqkv_l = (__hip_bfloat16*)(off_p + 16*M1 + 3*(M1/2));
    __hip_bfloat16* wd_h = (__hip_bfloat16*)(off_p + 19*M1);
    __hip_bfloat16* wd_l = (__hip_bfloat16*)(off_p + 19*M1 + M1/2);

    const bool FULL = ws_size >= (size_t)300*1024*1024;
    // FULL layout: W1t @ +20M1 (16M1 span), W2t @ +36M1 (16M1 span).
    // y1F overlays off_p+0 .. +18.875M1 (xa + at_* + wqkv — all dead by MoE time).
    __hip_bfloat16* W1t = (__hip_bfloat16*)(off_p + 20*M1);
    __hip_bfloat16* W2t = (__hip_bfloat16*)(off_p + 36*M1);
    __hip_bfloat16* y1F = (__hip_bfloat16*)(off_p);
    float* wreg = off_p + 4*M1;   // PE path scratch

    dim3 blk(256);

    prep_inputs<<<dim3(5120), blk, 0, stream>>>(x, Wq, Wk, Wv, Wd, xa_hi, xa_lo, wqkv_h, wqkv_l, wd_h, wd_l);

    if (FULL) {
        fused_qkv_w12<<<dim3(768 + 8192 + 8192), blk, 0, stream>>>(
            xa_hi, xa_lo, wqkv_h, wqkv_l, qkv, W1, W2, W1t, W2t);
    } else {
        gemm_bf16x3<false><<<dim3(768), blk, 0, stream>>>(xa_hi, xa_lo, wqkv_h, wqkv_l, qkv, nullptr, 3072, H_, 24);
    }

    rope_vsplit<<<dim3(8192 + 1024), blk, 0, stream>>>(qkv, at_qh, at_ql, at_kh, at_kl, at_vh, at_vl);

    attn_mfma<<<dim3(B_*NH_*(S_/128)), blk, 0, stream>>>(at_qh, at_ql, at_kh, at_kl, at_vh, at_vl, xa_hi, xa_lo);

    // attn_out = ctx@Wd + bd, fused with moe_out/misc zeroing
    wd_gemm_zero<<<dim3(256 + 4096), blk, 0, stream>>>(xa_hi, xa_lo, wd_h, wd_l, attn_out, bd, moe_out, misc + 34816);

    ln_kernel<<<T_, blk, 0, stream>>>(attn_out, x, ln1g, ln1b, hs, hs_b);

    router_kernel<<<T_/64, blk, 0, stream>>>(hs, Wg, tok_e, tok_w, counts, P_sum);
    router_finalize<<<1, blk, 0, stream>>>(counts, P_sum, basep, cursor, cnt_pad, ntiles,
                                           slot_tok, tile_ex, out + (size_t)T_*H_);
    scatter_slots<<<T_/256, blk, 0, stream>>>(tok_e, tok_w, basep, cursor, slot_tok, slot_w);

    if (FULL) {
        moe_mfma<2,false><<<dim3(MAXTILES*32), blk, 0, stream>>>(
            hs_b, W1t, y1F, nullptr, slot_tok, slot_w, tile_ex, ntiles, nullptr, I_, H_, 32);
        moe_mfma<3,false><<<dim3(MAXTILES*8), blk, 0, stream>>>(
            y1F, W2t, nullptr, moe_out, slot_tok, slot_w, tile_ex, ntiles, nullptr, H_, I_, 8);
    } else {
        __hip_bfloat16* w1t = (__hip_bfloat16*)wreg;
        __hip_bfloat16* w2t = (__hip_bfloat16*)(wreg + 2*M1);
        __hip_bfloat16* y1  = (__hip_bfloat16*)(wreg + 4*M1);
        for (int e=0; e<E_; ++e) {
            transpose_bf16<<<dim3(I_/64, H_/64, 1), blk, 0, stream>>>(W1 + (size_t)e*H_*I_, w1t, H_, I_);
            moe_mfma<2,true><<<dim3(I_/128, 32), blk, 0, stream>>>(
                hs_b, w1t, y1, nullptr, slot_tok, slot_w, nullptr, cnt_pad+e, basep+e, I_, H_, 0);
            transpose_bf16<<<dim3(H_/64, I_/64, 1), blk, 0, stream>>>(W2 + (size_t)e*I_*H_, w2t, I_, H_);
            moe_mfma<3,true><<<dim3(H_/128, 32), blk, 0, stream>>>(
                y1, w2t, nullptr, moe_out, slot_tok, slot_w, nullptr, cnt_pad+e, basep+e, H_, I_, 0);
        }
    }

    ln_kernel<<<T_, blk, 0, stream>>>(moe_out, hs, ln2g, ln2b, out, nullptr);
}